// Round 1
// 1366.884 us; speedup vs baseline: 1.1240x; 1.1240x over previous
//
#include <hip/hip_runtime.h>
#include <hip/hip_bf16.h>
#include <stdint.h>

typedef __hip_bfloat16 bf16;

#define N_   4096
#define NP   32768   // B*N
#define KNN  20

// ---- workspace layout (units: float) ----
#define OFF_H2   0L         // 32768*64 ; later reused as hsn output
#define OFF_XYZ  2097152L   // 3 planes of 32768 (SoA)
#define OFF_X    2097152L
#define OFF_Y    2129920L
#define OFF_Z    2162688L
#define OFF_XX   2195456L   // 32768  (|h2|^2)
#define OFF_XXC  2228224L   // 32768  (|x|^2)
#define OFF_IDX1 2260992L   // 32768*20 int
#define OFF_IDX2 2916352L   // 32768*20 int
#define OFF_WF   3571712L   // 104768 fp32 weights
#define OFF_FLAG 3676480L   // dtype flag (int), 64-float slot
#define OFF_PAIR 3676544L   // pair chunk lives here during kNN phase
// post-kNN reuse of the pair region:
#define OFF_U    3676544L   // 32768*64 ; u=(Wa-Wb)h2 ; later w = Wsn1*hdg
#define OFF_V    5773696L   // 32768*64 ; v = Wb*h2
#define OFF_HDG  7870848L   // 32768*64
#define OFF_H4   5773696L   // 128*32768 k-major; overlaps V+HDG (both dead by then)

// ---- fp32 weight bank offsets ----
#define WF_W1 0
#define WF_G1 192
#define WF_B1 256
#define WF_W2 320
#define WF_G2 4416
#define WF_B2 4480
#define WF_WDG1 4544
#define WF_GDG1 12736
#define WF_BDG1 12800
#define WF_WDG2 12864
#define WF_GDG2 16960
#define WF_BDG2 17024
#define WF_WSN1 17088
#define WF_GSN1 21184
#define WF_BSN1 21248
#define WF_WSN2 21312
#define WF_GSN2 25408
#define WF_BSN2 25472
#define WF_W3 25536
#define WF_G3 29632
#define WF_B3 29696
#define WF_W4 29760
#define WF_G4 37952
#define WF_B4 38080
#define WF_W5 38208
#define WF_G5 103744
#define WF_B5 104256
#define WF_END 104768

__device__ __forceinline__ float lrelu(float x){ return x >= 0.f ? x : 0.01f*x; }

// sortable-uint mapping: preserves float order as unsigned order
__device__ __forceinline__ uint32_t fsort(float v){
  uint32_t b = __float_as_uint(v);
  return b ^ ((uint32_t)((int32_t)b >> 31) | 0x80000000u);
}

// butterfly max over 64 lanes of a u64 key (packed compare: v_cmp_lt_u64 + 2 cndmask)
#define BSTEP_DPP(CTRL) { \
    uint32_t olo = (uint32_t)__builtin_amdgcn_update_dpp(0,(int)(uint32_t)k, CTRL, 0xF, 0xF, true); \
    uint32_t ohi = (uint32_t)__builtin_amdgcn_update_dpp(0,(int)(uint32_t)(k>>32), CTRL, 0xF, 0xF, true); \
    uint64_t o = ((uint64_t)ohi << 32) | olo; \
    if (o > k) k = o; }
#define BSTEP_SHFL(MASK) { \
    uint32_t olo = (uint32_t)__shfl_xor((int)(uint32_t)k, MASK, 64); \
    uint32_t ohi = (uint32_t)__shfl_xor((int)(uint32_t)(k>>32), MASK, 64); \
    uint64_t o = ((uint64_t)ohi << 32) | olo; \
    if (o > k) k = o; }

__device__ __forceinline__ uint64_t bfly_max_u64(uint64_t k){
  BSTEP_DPP(0xB1)   // quad_perm xor1
  BSTEP_DPP(0x4E)   // quad_perm xor2
  BSTEP_DPP(0x124)  // row_ror:4
  BSTEP_DPP(0x128)  // row_ror:8
  BSTEP_SHFL(16)
  BSTEP_SHFL(32)
  return k;
}

// Iterative exact top-20. row = padded LDS (elem m at (m>>6)*65 + (m&63)).
// K = per-lane segment-max key. MODE 0: owner lane = m&63. MODE 1: owner = (m>>2)&63.
template<int MODE>
__device__ __forceinline__ void topk_iter(const float* __restrict__ row, uint64_t K,
                                          int lane, int* __restrict__ outp){
  uint32_t mlo = 0, mhi = 0;
  int keep = 0;
  #pragma unroll 1
  for (int tt = 0; tt < KNN; tt++){
    uint64_t g = bfly_max_u64(K);
    uint32_t m = ~(uint32_t)g;
    keep = (lane == tt) ? (int)m : keep;
    uint32_t js, mre;
    if (MODE == 0){
      js  = m & 63u;
      mre = ((uint32_t)lane << 6) + js;
    } else {
      js  = (m >> 2) & 63u;
      mre = (((uint32_t)lane >> 2) << 8) + (js << 2) + ((uint32_t)lane & 3u);
    }
    uint32_t ord = (MODE == 0) ? (m >> 6) : (((m >> 8) << 2) | (m & 3u));
    if ((uint32_t)lane == js){
      if (ord < 32u) mlo |= 1u << ord; else mhi |= 1u << (ord - 32u);
    }
    int sjs = __builtin_amdgcn_readfirstlane((int)js);
    uint32_t bl = (uint32_t)__builtin_amdgcn_readlane((int)mlo, sjs);
    uint32_t bh = (uint32_t)__builtin_amdgcn_readlane((int)mhi, sjs);
    uint64_t bm = ((uint64_t)bh << 32) | bl;
    uint32_t excl = (uint32_t)((bm >> lane) & 1ull);
    float v = row[(mre >> 6) * 65 + (mre & 63u)];
    uint64_t k2 = ((uint64_t)fsort(v) << 32) | (uint32_t)(~mre);
    if (excl) k2 = 0;
    uint64_t g2 = bfly_max_u64(k2);
    if ((uint32_t)lane == js) K = g2;
  }
  if (lane < KNN) outp[lane] = keep;
}

// ---------------- K-1: dtype detect (1 = fp32 inputs, 0 = bf16) -------------
__global__ void k_detect(const void* __restrict__ x, int* __restrict__ flag){
  int lane = threadIdx.x;
  const bf16* xb = (const bf16*)x;
  int cnt = 0;
  #pragma unroll 1
  for (int i = lane; i < 256; i += 64){
    float v = __bfloat162float(xb[2*i]);
    float a = fabsf(v);
    if (a > 1e-3f && a < 100.f) cnt++;
  }
  #pragma unroll
  for (int off = 32; off; off >>= 1) cnt += __shfl_down(cnt, off, 64);
  if (lane == 0) *flag = (cnt >= 128) ? 0 : 1;
}

// ---------------- K0: convert all weights -> fp32 bank ----------------------
struct WPack {
  const void* p[27];
  int off[28];
};

__global__ void k_wcvt(WPack pk, float* __restrict__ dst, const int* __restrict__ flagp){
  int i = blockIdx.x*256 + threadIdx.x;
  if (i >= WF_END) return;
  int f = *flagp;
  #pragma unroll 1
  for (int s = 0; s < 27; s++){
    if (i < pk.off[s+1]){
      int j = i - pk.off[s];
      dst[i] = f ? ((const float*)pk.p[s])[j]
                 : __bfloat162float(((const bf16*)pk.p[s])[j]);
      return;
    }
  }
}

// ---------------- K1: per-point MLP1+MLP2, norms, coords (SoA) --------------
__global__ void k_point(const void* __restrict__ x, float* __restrict__ ws){
  const float* wf = ws + OFF_WF;
  int f = ((const int*)(ws + OFF_FLAG))[0];
  int n = blockIdx.x*256 + threadIdx.x;
  float x0, x1, x2;
  if (f){
    const float* xf = (const float*)x;
    x0 = xf[n*3+0]; x1 = xf[n*3+1]; x2 = xf[n*3+2];
  } else {
    const bf16* xb = (const bf16*)x;
    x0 = __bfloat162float(xb[n*3+0]);
    x1 = __bfloat162float(xb[n*3+1]);
    x2 = __bfloat162float(xb[n*3+2]);
  }

  float h1[64];
  #pragma unroll
  for (int o=0;o<64;o++){
    float a = wf[WF_W1+o*3+0]*x0 + wf[WF_W1+o*3+1]*x1 + wf[WF_W1+o*3+2]*x2;
    h1[o] = lrelu(wf[WF_G1+o]*a + wf[WF_B1+o]);
  }
  float xx = 0.f;
  #pragma unroll 1
  for (int o=0;o<64;o++){
    float a = 0.f;
    #pragma unroll
    for (int c=0;c<64;c++) a += wf[WF_W2+o*64+c]*h1[c];
    float h2 = lrelu(wf[WF_G2+o]*a + wf[WF_B2+o]);
    ws[OFF_H2 + (long)n*64 + o] = h2;
    xx += h2*h2;
  }
  ws[OFF_XX + n] = xx;
  ws[OFF_X + n] = x0; ws[OFF_Y + n] = x1; ws[OFF_Z + n] = x2;
  ws[OFF_XXC + n] = x0*x0 + x1*x1 + x2*x2;
}

// ---------------- K2a: pair GEMM (fp32), per batch chunk --------------------
__global__ __launch_bounds__(256) void k_pair(const float* __restrict__ ws, float* __restrict__ pair,
                                              int b, int n0){
  __shared__ float As[64*128];
  __shared__ float Bs[64*128];
  int t = threadIdx.x;
  int bx = blockIdx.x, by = blockIdx.y;
  const float* h2 = ws + OFF_H2 + (long)b*N_*64;

  int r = t >> 1, c0 = (t & 1)*32;
  const float4* arow = (const float4*)(h2 + (long)(n0 + by*128 + r)*64 + c0);
  const float4* brow = (const float4*)(h2 + (long)(bx*128 + r)*64 + c0);
  #pragma unroll
  for (int q=0;q<8;q++){
    float4 av = arow[q];
    As[(c0+4*q+0)*128 + r] = av.x; As[(c0+4*q+1)*128 + r] = av.y;
    As[(c0+4*q+2)*128 + r] = av.z; As[(c0+4*q+3)*128 + r] = av.w;
    float4 bv = brow[q];
    Bs[(c0+4*q+0)*128 + r] = bv.x; Bs[(c0+4*q+1)*128 + r] = bv.y;
    Bs[(c0+4*q+2)*128 + r] = bv.z; Bs[(c0+4*q+3)*128 + r] = bv.w;
  }
  __syncthreads();

  int tr = t/16, tc = t%16;
  float acc[8][8] = {};
  #pragma unroll 4
  for (int k=0;k<64;k++){
    const float4* ap = (const float4*)&As[k*128 + tr*8];
    const float4* bp = (const float4*)&Bs[k*128 + tc*8];
    float4 a0 = ap[0], a1 = ap[1], c0v = bp[0], c1v = bp[1];
    float a[8] = {a0.x,a0.y,a0.z,a0.w,a1.x,a1.y,a1.z,a1.w};
    float c[8] = {c0v.x,c0v.y,c0v.z,c0v.w,c1v.x,c1v.y,c1v.z,c1v.w};
    #pragma unroll
    for (int i=0;i<8;i++)
      #pragma unroll
      for (int j=0;j<8;j++) acc[i][j] += a[i]*c[j];
  }
  const float* xxp = ws + OFF_XX + b*N_ + bx*128 + tc*8;
  float xxm[8];
  #pragma unroll
  for (int j=0;j<8;j++) xxm[j] = xxp[j];
  #pragma unroll
  for (int i=0;i<8;i++){
    long row = (long)(by*128 + tr*8 + i)*N_ + bx*128 + tc*8;
    float4 o0 = make_float4(2.f*acc[i][0]-xxm[0], 2.f*acc[i][1]-xxm[1],
                            2.f*acc[i][2]-xxm[2], 2.f*acc[i][3]-xxm[3]);
    float4 o1 = make_float4(2.f*acc[i][4]-xxm[4], 2.f*acc[i][5]-xxm[5],
                            2.f*acc[i][6]-xxm[6], 2.f*acc[i][7]-xxm[7]);
    ((float4*)(pair+row))[0] = o0;
    ((float4*)(pair+row))[1] = o1;
  }
}

// ---------------- K2b: top-20 over stored pair rows -------------------------
__global__ __launch_bounds__(64) void k_topk_pair(const float* __restrict__ pair, int* __restrict__ idx1,
                                                  int b, int n0){
  __shared__ float row[4160];
  int lane = threadIdx.x;
  const float4* src = (const float4*)(pair + (long)blockIdx.x*N_);
  float mv = -3.0e38f; uint32_t mi = 0;
  #pragma unroll
  for (int q=0;q<16;q++){
    float4 v = src[lane + 64*q];
    uint32_t m0 = 4u*(uint32_t)lane + 256u*q;
    *(float4*)&row[(m0 >> 6)*65 + (m0 & 63u)] = v;
    if (v.x > mv){ mv = v.x; mi = m0; }
    if (v.y > mv){ mv = v.y; mi = m0+1; }
    if (v.z > mv){ mv = v.z; mi = m0+2; }
    if (v.w > mv){ mv = v.w; mi = m0+3; }
  }
  uint64_t K = ((uint64_t)fsort(mv) << 32) | (uint32_t)(~mi);
  __syncthreads();
  topk_iter<1>(row, K, lane, idx1 + (long)(b*N_ + n0 + blockIdx.x)*KNN);
}

// ---------------- K3: fused coord-space kNN (MODE-1 fill, float4) -----------
__global__ __launch_bounds__(64) void k_knn2(const float* __restrict__ ws, int* __restrict__ idx2){
  __shared__ float row[4160];
  int n = blockIdx.x, lane = threadIdx.x;
  int base = n & ~4095;
  const float* Xp = ws + OFF_X, *Yp = ws + OFF_Y, *Zp = ws + OFF_Z, *Cp = ws + OFF_XXC;
  float xn = Xp[n], yn = Yp[n], zn = Zp[n];
  float mv = -3.0e38f; uint32_t mi = 0;
  #pragma unroll 4
  for (int q=0;q<16;q++){
    uint32_t m0 = 4u*(uint32_t)lane + 256u*q;
    float4 X4 = *(const float4*)(Xp + base + m0);
    float4 Y4 = *(const float4*)(Yp + base + m0);
    float4 Z4 = *(const float4*)(Zp + base + m0);
    float4 C4 = *(const float4*)(Cp + base + m0);
    float4 d;
    d.x = 2.f*(xn*X4.x + yn*Y4.x + zn*Z4.x) - C4.x;
    d.y = 2.f*(xn*X4.y + yn*Y4.y + zn*Z4.y) - C4.y;
    d.z = 2.f*(xn*X4.z + yn*Y4.z + zn*Z4.z) - C4.z;
    d.w = 2.f*(xn*X4.w + yn*Y4.w + zn*Z4.w) - C4.w;
    *(float4*)&row[(m0 >> 6)*65 + (m0 & 63u)] = d;
    if (d.x > mv){ mv = d.x; mi = m0; }
    if (d.y > mv){ mv = d.y; mi = m0+1; }
    if (d.z > mv){ mv = d.z; mi = m0+2; }
    if (d.w > mv){ mv = d.w; mi = m0+3; }
  }
  uint64_t K = ((uint64_t)fsort(mv) << 32) | (uint32_t)(~mi);
  __syncthreads();
  topk_iter<1>(row, K, lane, idx2 + (long)n*KNN);
}

// ---------------- K3b: u = (Wa-Wb)h2, v = Wb h2 (post-kNN) ------------------
__global__ void k_uv(float* __restrict__ ws){
  const float* wf = ws + OFF_WF;
  int n = blockIdx.x*256 + threadIdx.x;
  float h[64];
  const float4* src = (const float4*)(ws + OFF_H2 + (long)n*64);
  #pragma unroll
  for (int q=0;q<16;q++){ float4 v = src[q]; h[4*q]=v.x; h[4*q+1]=v.y; h[4*q+2]=v.z; h[4*q+3]=v.w; }
  #pragma unroll 1
  for (int o=0;o<64;o++){
    float va=0.f, vb=0.f;
    #pragma unroll
    for (int c=0;c<64;c++){
      va += wf[WF_WDG1+o*128+c]*h[c];
      vb += wf[WF_WDG1+o*128+64+c]*h[c];
    }
    ws[OFF_U + (long)n*64 + o] = va - vb;
    ws[OFF_V + (long)n*64 + o] = vb;
  }
}

// ---------------- K4/K5: edge stage (gathered first conv folded) ------------
// Software-pipelined: idx tile preloaded to LDS (kills dependent idx->gather
// chain); gather for k+1 register-prefetched before the MAC loop so HBM/L2
// latency hides under ~2k cycles of FMA+LDS work; `us` moved to registers
// (LDS 50KB -> 38.4KB -> 4 blocks/CU instead of 3).
template<int USE_U>
__global__ __launch_bounds__(256, 4) void k_edge(float* __restrict__ ws, const int* __restrict__ idxt,
      long uoff, long goff, int w2off,
      int g1off, int b1off, int g2off, int b2off, long outoff){
  __shared__ float y1s[64*65];
  __shared__ float w2s[64*65];
  __shared__ int   idxs[64*KNN];
  const float* wf = ws + OFF_WF;
  int t = threadIdx.x;
  int p0 = blockIdx.x*64;
  int b  = p0 >> 12;
  int lane = t & 63, wv = t >> 6;
  int tr = t & 15, oc = t >> 4;

  #pragma unroll 1
  for (int i=t;i<4096;i+=256){ int o = i>>6, kk = i&63; w2s[o*65+kk] = wf[w2off + i]; }
  #pragma unroll 1
  for (int i=t;i<64*KNN;i+=256) idxs[i] = idxt[(long)p0*KNN + i];

  // per-lane registers replacing LDS us/g1s/b1s/g2s/b2s
  float ur[16];
  if (USE_U){
    #pragma unroll
    for (int jj=0;jj<16;jj++)
      ur[jj] = ws[uoff + (long)(p0 + wv + 4*jj)*64 + lane];
  } else {
    #pragma unroll
    for (int jj=0;jj<16;jj++) ur[jj] = 0.f;
  }
  float g1v = wf[g1off+lane], b1v = wf[b1off+lane];
  float g2r[4], b2r[4];
  #pragma unroll
  for (int j=0;j<4;j++){ g2r[j] = wf[g2off+oc+16*j]; b2r[j] = wf[b2off+oc+16*j]; }

  float mx[4][4];
  #pragma unroll
  for (int i=0;i<4;i++)
    #pragma unroll
    for (int j=0;j<4;j++) mx[i][j] = -3.0e38f;

  __syncthreads();   // idxs + w2s ready

  long gbase = goff + ((long)b << 12)*64;
  float pf[16];
  #pragma unroll
  for (int jj=0;jj<16;jj++){
    int nb = idxs[(wv + 4*jj)*KNN];
    pf[jj] = ws[gbase + (long)nb*64 + lane];
  }

  for (int k=0;k<KNN;k++){
    // write phase: consume prefetched gather for this k
    #pragma unroll
    for (int jj=0;jj<16;jj++){
      int e = wv + 4*jj;
      float val = pf[jj];
      if (USE_U) val += ur[jj];
      y1s[e*65 + lane] = lrelu(g1v*val + b1v);
    }
    __syncthreads();
    // issue next-k gather NOW; latency hides under the MAC loop below
    if (k+1 < KNN){
      #pragma unroll
      for (int jj=0;jj<16;jj++){
        int nb = idxs[(wv + 4*jj)*KNN + k+1];
        pf[jj] = ws[gbase + (long)nb*64 + lane];
      }
    }
    float acc[4][4] = {};
    #pragma unroll 4
    for (int kk=0;kk<64;kk++){
      float a0 = y1s[(tr   )*65+kk], a1 = y1s[(tr+16)*65+kk];
      float a2 = y1s[(tr+32)*65+kk], a3 = y1s[(tr+48)*65+kk];
      float c0 = w2s[(oc   )*65+kk], c1 = w2s[(oc+16)*65+kk];
      float c2 = w2s[(oc+32)*65+kk], c3 = w2s[(oc+48)*65+kk];
      acc[0][0]+=a0*c0; acc[0][1]+=a0*c1; acc[0][2]+=a0*c2; acc[0][3]+=a0*c3;
      acc[1][0]+=a1*c0; acc[1][1]+=a1*c1; acc[1][2]+=a1*c2; acc[1][3]+=a1*c3;
      acc[2][0]+=a2*c0; acc[2][1]+=a2*c1; acc[2][2]+=a2*c2; acc[2][3]+=a2*c3;
      acc[3][0]+=a3*c0; acc[3][1]+=a3*c1; acc[3][2]+=a3*c2; acc[3][3]+=a3*c3;
    }
    #pragma unroll
    for (int i=0;i<4;i++)
      #pragma unroll
      for (int j=0;j<4;j++){
        float yy = lrelu(g2r[j]*acc[i][j] + b2r[j]);
        mx[i][j] = fmaxf(mx[i][j], yy);
      }
    __syncthreads();
  }
  #pragma unroll
  for (int i=0;i<4;i++)
    #pragma unroll
    for (int j=0;j<4;j++)
      ws[outoff + (long)(p0 + tr + 16*i)*64 + oc + 16*j] = mx[i][j];
}

// ---------------- K4b: w = Wsn1 . hdg per point (stored raw) ----------------
__global__ void k_w(float* __restrict__ ws){
  const float* wf = ws + OFF_WF;
  int n = blockIdx.x*256 + threadIdx.x;
  float h[64];
  const float4* src = (const float4*)(ws + OFF_HDG + (long)n*64);
  #pragma unroll
  for (int q=0;q<16;q++){ float4 v = src[q]; h[4*q]=v.x; h[4*q+1]=v.y; h[4*q+2]=v.z; h[4*q+3]=v.w; }
  #pragma unroll 1
  for (int o=0;o<64;o++){
    float a = 0.f;
    #pragma unroll
    for (int c=0;c<64;c++) a += wf[WF_WSN1 + o*64 + c]*h[c];
    ws[OFF_U + (long)n*64 + o] = a;
  }
}

// ---------------- K6a: head conv3+conv4, h4 out in k-major [128][NP] --------
__global__ __launch_bounds__(256) void k_h4(const float* __restrict__ ws, float* __restrict__ h4g){
  __shared__ float Hs[64*65];    // [ch][pt] (hsn), then reused as [o3][pt] (h3)
  __shared__ float wb[64*130];   // W3 as wb[c*65+o]; later W4 as wb[c*130+o]
  const float* wf = ws + OFF_WF;
  int t = threadIdx.x;
  int p0 = blockIdx.x*64;

  {
    int r = t >> 2, c0 = (t & 3)*16;
    const float4* src = (const float4*)(ws + OFF_H2 + (long)(p0 + r)*64 + c0);
    #pragma unroll
    for (int q=0;q<4;q++){
      float4 v = src[q];
      Hs[(c0+4*q+0)*65 + r] = v.x; Hs[(c0+4*q+1)*65 + r] = v.y;
      Hs[(c0+4*q+2)*65 + r] = v.z; Hs[(c0+4*q+3)*65 + r] = v.w;
    }
  }
  {
    int r = t >> 2, c0 = (t & 3)*16;
    const float4* src = (const float4*)(wf + WF_W3 + (long)r*64 + c0);
    #pragma unroll
    for (int q=0;q<4;q++){
      float4 v = src[q];
      wb[(c0+4*q+0)*65 + r] = v.x; wb[(c0+4*q+1)*65 + r] = v.y;
      wb[(c0+4*q+2)*65 + r] = v.z; wb[(c0+4*q+3)*65 + r] = v.w;
    }
  }
  __syncthreads();

  int pr = t & 15, og = t >> 4;
  float acc[4][4] = {};
  #pragma unroll 8
  for (int k=0;k<64;k++){
    float4 a = *(const float4*)&Hs[k*65 + pr*4];
    float4 c = *(const float4*)&wb[k*65 + og*4];
    float av[4] = {a.x,a.y,a.z,a.w}, cv[4] = {c.x,c.y,c.z,c.w};
    #pragma unroll
    for (int i=0;i<4;i++)
      #pragma unroll
      for (int j=0;j<4;j++) acc[i][j] += av[i]*cv[j];
  }
  __syncthreads();

  #pragma unroll
  for (int j=0;j<4;j++){
    int o = og*4 + j;
    float g3 = wf[WF_G3+o], b3 = wf[WF_B3+o];
    #pragma unroll
    for (int i=0;i<4;i++)
      Hs[o*65 + pr*4 + i] = lrelu(g3*acc[i][j] + b3);
  }
  {
    int r = t >> 1, c0 = (t & 1)*32;
    const float4* src = (const float4*)(wf + WF_W4 + (long)r*64 + c0);
    #pragma unroll
    for (int q=0;q<8;q++){
      float4 v = src[q];
      wb[(c0+4*q+0)*130 + r] = v.x; wb[(c0+4*q+1)*130 + r] = v.y;
      wb[(c0+4*q+2)*130 + r] = v.z; wb[(c0+4*q+3)*130 + r] = v.w;
    }
  }
  __syncthreads();

  float a2[4][8] = {};
  #pragma unroll 8
  for (int k=0;k<64;k++){
    float4 a = *(const float4*)&Hs[k*65 + pr*4];
    float4 c0 = *(const float4*)&wb[k*130 + og*8];
    float4 c1 = *(const float4*)&wb[k*130 + og*8 + 4];
    float av[4] = {a.x,a.y,a.z,a.w};
    float cv[8] = {c0.x,c0.y,c0.z,c0.w,c1.x,c1.y,c1.z,c1.w};
    #pragma unroll
    for (int i=0;i<4;i++)
      #pragma unroll
      for (int j=0;j<8;j++) a2[i][j] += av[i]*cv[j];
  }
  #pragma unroll
  for (int j=0;j<8;j++){
    int o = og*8 + j;
    float g4 = wf[WF_G4+o], b4 = wf[WF_B4+o];
    #pragma unroll
    for (int i=0;i<4;i++)
      h4g[(long)o*NP + p0 + pr*4 + i] = lrelu(g4*a2[i][j] + b4);
  }
}

// ---------------- K6b: conv5 GEMM [512 x 128] . [128 x NP] ------------------
#define KC 32
__global__ __launch_bounds__(256) void k_conv5(const float* __restrict__ ws, void* __restrict__ outv){
  __shared__ float As[KC*128];   // [k][o]
  __shared__ float Bs[KC*128];   // [k][pt]
  const float* wf = ws + OFF_WF;
  int f = ((const int*)(ws + OFF_FLAG))[0];
  int t = threadIdx.x;
  int p0 = blockIdx.x*128;
  int o0 = blockIdx.y*128;
  const float* H4 = ws + OFF_H4;
  float acc[8][8] = {};

  for (int kc = 0; kc < 128; kc += KC){
    {
      int r = t >> 1, c0 = (t & 1)*16;
      const float4* src = (const float4*)(wf + WF_W5 + (long)(o0 + r)*128 + kc + c0);
      #pragma unroll
      for (int q=0;q<4;q++){
        float4 v = src[q];
        As[(c0+4*q+0)*128 + r] = v.x; As[(c0+4*q+1)*128 + r] = v.y;
        As[(c0+4*q+2)*128 + r] = v.z; As[(c0+4*q+3)*128 + r] = v.w;
      }
    }
    {
      int kr = t >> 3, pc = (t & 7)*16;
      const float4* src = (const float4*)(H4 + (long)(kc + kr)*NP + p0 + pc);
      float4 v0 = src[0], v1 = src[1], v2 = src[2], v3 = src[3];
      *(float4*)&Bs[kr*128 + pc     ] = v0;
      *(float4*)&Bs[kr*128 + pc + 4 ] = v1;
      *(float4*)&Bs[kr*128 + pc + 8 ] = v2;
      *(float4*)&Bs[kr*128 + pc + 12] = v3;
    }
    __syncthreads();
    int tr = t/16, tc = t%16;
    #pragma unroll 8
    for (int k=0;k<KC;k++){
      const float4* ap = (const float4*)&As[k*128 + tr*8];
      const float4* bp = (const float4*)&Bs[k*128 + tc*8];
      float4 a0 = ap[0], a1 = ap[1], b0 = bp[0], b1 = bp[1];
      float a[8] = {a0.x,a0.y,a0.z,a0.w,a1.x,a1.y,a1.z,a1.w};
      float b[8] = {b0.x,b0.y,b0.z,b0.w,b1.x,b1.y,b1.z,b1.w};
      #pragma unroll
      for (int i=0;i<8;i++)
        #pragma unroll
        for (int j=0;j<8;j++) acc[i][j] += a[i]*b[j];
    }
    __syncthreads();
  }

  int tr = t/16, tc = t%16;
  int b = p0 >> 12, nn = (p0 & 4095) + tc*8;
  #pragma unroll
  for (int i=0;i<8;i++){
    int oo = o0 + tr*8 + i;
    float g5 = wf[WF_G5+oo], b5 = wf[WF_B5+oo];
    long base = ((long)(b*512 + oo) << 12) + nn;
    if (f){
      float4 v0 = make_float4(lrelu(g5*acc[i][0]+b5), lrelu(g5*acc[i][1]+b5),
                              lrelu(g5*acc[i][2]+b5), lrelu(g5*acc[i][3]+b5));
      float4 v1 = make_float4(lrelu(g5*acc[i][4]+b5), lrelu(g5*acc[i][5]+b5),
                              lrelu(g5*acc[i][6]+b5), lrelu(g5*acc[i][7]+b5));
      *(float4*)((float*)outv + base)     = v0;
      *(float4*)((float*)outv + base + 4) = v1;
    } else {
      #pragma unroll
      for (int j=0;j<8;j++)
        ((bf16*)outv)[base + j] = __float2bfloat16(lrelu(g5*acc[i][j] + b5));
    }
  }
}

// ---------------- host ------------------------------------------------------
extern "C" void kernel_launch(void* const* d_in, const int* in_sizes, int n_in,
                              void* d_out, int out_size, void* d_ws, size_t ws_size,
                              hipStream_t stream) {
  const void* X = d_in[0];
  float* ws = (float*)d_ws;
  int* flagp = (int*)(ws + OFF_FLAG);

  WPack pk;
  static const int wsz[27] = {192,64,64, 4096,64,64, 8192,64,64, 4096,64,64, 4096,64,64,
                              4096,64,64, 4096,64,64, 8192,128,128, 65536,512,512};
  int off = 0;
  for (int i=0;i<27;i++){ pk.p[i] = d_in[i+1]; pk.off[i] = off; off += wsz[i]; }
  pk.off[27] = off;

  k_detect<<<dim3(1), dim3(64), 0, stream>>>(X, flagp);
  k_wcvt<<<dim3((WF_END+255)/256), dim3(256), 0, stream>>>(pk, ws + OFF_WF, flagp);
  k_point<<<dim3(NP/256), dim3(256), 0, stream>>>(X, ws);
  k_knn2<<<dim3(NP), dim3(64), 0, stream>>>(ws, (int*)(ws + OFF_IDX2));

  long availf = (long)(ws_size/4) - OFF_PAIR;
  int chunk = 4096;
  if (availf < (long)N_*N_){
    long c = (availf / N_) & ~127L;
    chunk = (int)(c < 128 ? 128 : c);
    if (chunk > 4096) chunk = 4096;
  }
  for (int b=0;b<8;b++){
    for (int n0=0;n0<N_; n0+=chunk){
      int rows = (N_ - n0 < chunk) ? (N_ - n0) : chunk;
      k_pair<<<dim3(32, rows/128), dim3(256), 0, stream>>>(ws, ws + OFF_PAIR, b, n0);
      k_topk_pair<<<dim3(rows), dim3(64), 0, stream>>>(ws + OFF_PAIR, (int*)(ws + OFF_IDX1), b, n0);
    }
  }
  k_uv<<<dim3(NP/256), dim3(256), 0, stream>>>(ws);
  k_edge<1><<<dim3(NP/64), dim3(256), 0, stream>>>(ws, (const int*)(ws + OFF_IDX1),
        OFF_U, OFF_V, WF_WDG2, WF_GDG1, WF_BDG1, WF_GDG2, WF_BDG2, OFF_HDG);
  k_w<<<dim3(NP/256), dim3(256), 0, stream>>>(ws);
  k_edge<0><<<dim3(NP/64), dim3(256), 0, stream>>>(ws, (const int*)(ws + OFF_IDX2),
        0, OFF_U, WF_WSN2, WF_GSN1, WF_BSN1, WF_GSN2, WF_BSN2, OFF_H2);
  k_h4<<<dim3(NP/64), dim3(256), 0, stream>>>(ws, ws + OFF_H4);
  k_conv5<<<dim3(NP/128, 4), dim3(256), 0, stream>>>(ws, d_out);
}

// Round 2
// 1310.821 us; speedup vs baseline: 1.1721x; 1.0428x over previous
//
#include <hip/hip_runtime.h>
#include <hip/hip_bf16.h>
#include <stdint.h>

typedef __hip_bfloat16 bf16;

#define N_   4096
#define NP   32768   // B*N
#define KNN  20

// ---- workspace layout (units: float) ----
#define OFF_H2   0L         // 32768*64 ; later reused as hsn output
#define OFF_XYZ  2097152L   // 3 planes of 32768 (SoA)
#define OFF_X    2097152L
#define OFF_Y    2129920L
#define OFF_Z    2162688L
#define OFF_XX   2195456L   // 32768  (|h2|^2)
#define OFF_XXC  2228224L   // 32768  (|x|^2)
#define OFF_IDX1 2260992L   // 32768*20 int
#define OFF_IDX2 2916352L   // 32768*20 int
#define OFF_WF   3571712L   // 104768 fp32 weights
#define OFF_FLAG 3676480L   // dtype flag (int), 64-float slot
#define OFF_PAIR 3676544L   // pair chunk lives here during kNN phase
// post-kNN reuse of the pair region:
#define OFF_U    3676544L   // 32768*64 ; u=(Wa-Wb)h2 ; later w = Wsn1*hdg
#define OFF_V    5773696L   // 32768*64 ; v = Wb*h2
#define OFF_HDG  7870848L   // 32768*64
#define OFF_H4   5773696L   // 128*32768 k-major; overlaps V+HDG (both dead by then)

// ---- fp32 weight bank offsets ----
#define WF_W1 0
#define WF_G1 192
#define WF_B1 256
#define WF_W2 320
#define WF_G2 4416
#define WF_B2 4480
#define WF_WDG1 4544
#define WF_GDG1 12736
#define WF_BDG1 12800
#define WF_WDG2 12864
#define WF_GDG2 16960
#define WF_BDG2 17024
#define WF_WSN1 17088
#define WF_GSN1 21184
#define WF_BSN1 21248
#define WF_WSN2 21312
#define WF_GSN2 25408
#define WF_BSN2 25472
#define WF_W3 25536
#define WF_G3 29632
#define WF_B3 29696
#define WF_W4 29760
#define WF_G4 37952
#define WF_B4 38080
#define WF_W5 38208
#define WF_G5 103744
#define WF_B5 104256
#define WF_END 104768

__device__ __forceinline__ float lrelu(float x){ return x >= 0.f ? x : 0.01f*x; }

// sortable-uint mapping: preserves float order as unsigned order
__device__ __forceinline__ uint32_t fsort(float v){
  uint32_t b = __float_as_uint(v);
  return b ^ ((uint32_t)((int32_t)b >> 31) | 0x80000000u);
}

// exact-deterministic distance: MUST be the single source for both fill and
// rescan in k_knn2 (bit-identical results required for ordering consistency)
__device__ __forceinline__ float distf(float xn,float yn,float zn,
                                       float xm,float ym,float zm,float cm){
  return fmaf(2.f, fmaf(xn,xm, fmaf(yn,ym, zn*zm)), -cm);
}

// butterfly max over 64 lanes of a u64 key (packed compare: v_cmp_lt_u64 + 2 cndmask)
#define BSTEP_DPP(CTRL) { \
    uint32_t olo = (uint32_t)__builtin_amdgcn_update_dpp(0,(int)(uint32_t)k, CTRL, 0xF, 0xF, true); \
    uint32_t ohi = (uint32_t)__builtin_amdgcn_update_dpp(0,(int)(uint32_t)(k>>32), CTRL, 0xF, 0xF, true); \
    uint64_t o = ((uint64_t)ohi << 32) | olo; \
    if (o > k) k = o; }
#define BSTEP_SHFL(MASK) { \
    uint32_t olo = (uint32_t)__shfl_xor((int)(uint32_t)k, MASK, 64); \
    uint32_t ohi = (uint32_t)__shfl_xor((int)(uint32_t)(k>>32), MASK, 64); \
    uint64_t o = ((uint64_t)ohi << 32) | olo; \
    if (o > k) k = o; }

__device__ __forceinline__ uint64_t bfly_max_u64(uint64_t k){
  BSTEP_DPP(0xB1)   // quad_perm xor1
  BSTEP_DPP(0x4E)   // quad_perm xor2
  BSTEP_DPP(0x124)  // row_ror:4
  BSTEP_DPP(0x128)  // row_ror:8
  BSTEP_SHFL(16)
  BSTEP_SHFL(32)
  return k;
}

// Iterative exact top-20, LDS-free. Candidate m in 0..4095; owner lane
// js=(m>>2)&63, segment-position ord=((m>>8)<<2)|(m&3). K = per-lane
// segment-max key. fetch(mre) returns the value of candidate mre and must be
// bit-consistent with the values used to build K.
template<typename F>
__device__ __forceinline__ void topk_fetch(uint64_t K, int lane, F&& fetch,
                                           int* __restrict__ outp){
  uint32_t mlo = 0, mhi = 0;
  int keep = 0;
  #pragma unroll 1
  for (int tt = 0; tt < KNN; tt++){
    uint64_t g = bfly_max_u64(K);
    uint32_t m = ~(uint32_t)g;
    keep = (lane == tt) ? (int)m : keep;
    uint32_t js  = (m >> 2) & 63u;
    uint32_t mre = (((uint32_t)lane >> 2) << 8) + (js << 2) + ((uint32_t)lane & 3u);
    uint32_t ord = ((m >> 8) << 2) | (m & 3u);
    if ((uint32_t)lane == js){
      if (ord < 32u) mlo |= 1u << ord; else mhi |= 1u << (ord - 32u);
    }
    int sjs = __builtin_amdgcn_readfirstlane((int)js);
    uint32_t bl = (uint32_t)__builtin_amdgcn_readlane((int)mlo, sjs);
    uint32_t bh = (uint32_t)__builtin_amdgcn_readlane((int)mhi, sjs);
    uint64_t bm = ((uint64_t)bh << 32) | bl;
    uint32_t excl = (uint32_t)((bm >> lane) & 1ull);
    float v = fetch(mre);
    uint64_t k2 = ((uint64_t)fsort(v) << 32) | (uint32_t)(~mre);
    if (excl) k2 = 0;
    uint64_t g2 = bfly_max_u64(k2);
    if ((uint32_t)lane == js) K = g2;
  }
  if (lane < KNN) outp[lane] = keep;
}

// ---------------- K-1: dtype detect (1 = fp32 inputs, 0 = bf16) -------------
__global__ void k_detect(const void* __restrict__ x, int* __restrict__ flag){
  int lane = threadIdx.x;
  const bf16* xb = (const bf16*)x;
  int cnt = 0;
  #pragma unroll 1
  for (int i = lane; i < 256; i += 64){
    float v = __bfloat162float(xb[2*i]);
    float a = fabsf(v);
    if (a > 1e-3f && a < 100.f) cnt++;
  }
  #pragma unroll
  for (int off = 32; off; off >>= 1) cnt += __shfl_down(cnt, off, 64);
  if (lane == 0) *flag = (cnt >= 128) ? 0 : 1;
}

// ---------------- K0: convert all weights -> fp32 bank ----------------------
struct WPack {
  const void* p[27];
  int off[28];
};

__global__ void k_wcvt(WPack pk, float* __restrict__ dst, const int* __restrict__ flagp){
  int i = blockIdx.x*256 + threadIdx.x;
  if (i >= WF_END) return;
  int f = *flagp;
  #pragma unroll 1
  for (int s = 0; s < 27; s++){
    if (i < pk.off[s+1]){
      int j = i - pk.off[s];
      dst[i] = f ? ((const float*)pk.p[s])[j]
                 : __bfloat162float(((const bf16*)pk.p[s])[j]);
      return;
    }
  }
}

// ---------------- K1: per-point MLP1+MLP2, norms, coords (SoA) --------------
__global__ void k_point(const void* __restrict__ x, float* __restrict__ ws){
  const float* wf = ws + OFF_WF;
  int f = ((const int*)(ws + OFF_FLAG))[0];
  int n = blockIdx.x*256 + threadIdx.x;
  float x0, x1, x2;
  if (f){
    const float* xf = (const float*)x;
    x0 = xf[n*3+0]; x1 = xf[n*3+1]; x2 = xf[n*3+2];
  } else {
    const bf16* xb = (const bf16*)x;
    x0 = __bfloat162float(xb[n*3+0]);
    x1 = __bfloat162float(xb[n*3+1]);
    x2 = __bfloat162float(xb[n*3+2]);
  }

  float h1[64];
  #pragma unroll
  for (int o=0;o<64;o++){
    float a = wf[WF_W1+o*3+0]*x0 + wf[WF_W1+o*3+1]*x1 + wf[WF_W1+o*3+2]*x2;
    h1[o] = lrelu(wf[WF_G1+o]*a + wf[WF_B1+o]);
  }
  float xx = 0.f;
  #pragma unroll 1
  for (int o=0;o<64;o++){
    float a = 0.f;
    #pragma unroll
    for (int c=0;c<64;c++) a += wf[WF_W2+o*64+c]*h1[c];
    float h2 = lrelu(wf[WF_G2+o]*a + wf[WF_B2+o]);
    ws[OFF_H2 + (long)n*64 + o] = h2;
    xx += h2*h2;
  }
  ws[OFF_XX + n] = xx;
  ws[OFF_X + n] = x0; ws[OFF_Y + n] = x1; ws[OFF_Z + n] = x2;
  ws[OFF_XXC + n] = x0*x0 + x1*x1 + x2*x2;
}

// ---------------- K2a: pair GEMM (fp32), per batch chunk --------------------
__global__ __launch_bounds__(256) void k_pair(const float* __restrict__ ws, float* __restrict__ pair,
                                              int b, int n0){
  __shared__ float As[64*128];
  __shared__ float Bs[64*128];
  int t = threadIdx.x;
  int bx = blockIdx.x, by = blockIdx.y;
  const float* h2 = ws + OFF_H2 + (long)b*N_*64;

  int r = t >> 1, c0 = (t & 1)*32;
  const float4* arow = (const float4*)(h2 + (long)(n0 + by*128 + r)*64 + c0);
  const float4* brow = (const float4*)(h2 + (long)(bx*128 + r)*64 + c0);
  #pragma unroll
  for (int q=0;q<8;q++){
    float4 av = arow[q];
    As[(c0+4*q+0)*128 + r] = av.x; As[(c0+4*q+1)*128 + r] = av.y;
    As[(c0+4*q+2)*128 + r] = av.z; As[(c0+4*q+3)*128 + r] = av.w;
    float4 bv = brow[q];
    Bs[(c0+4*q+0)*128 + r] = bv.x; Bs[(c0+4*q+1)*128 + r] = bv.y;
    Bs[(c0+4*q+2)*128 + r] = bv.z; Bs[(c0+4*q+3)*128 + r] = bv.w;
  }
  __syncthreads();

  int tr = t/16, tc = t%16;
  float acc[8][8] = {};
  #pragma unroll 4
  for (int k=0;k<64;k++){
    const float4* ap = (const float4*)&As[k*128 + tr*8];
    const float4* bp = (const float4*)&Bs[k*128 + tc*8];
    float4 a0 = ap[0], a1 = ap[1], c0v = bp[0], c1v = bp[1];
    float a[8] = {a0.x,a0.y,a0.z,a0.w,a1.x,a1.y,a1.z,a1.w};
    float c[8] = {c0v.x,c0v.y,c0v.z,c0v.w,c1v.x,c1v.y,c1v.z,c1v.w};
    #pragma unroll
    for (int i=0;i<8;i++)
      #pragma unroll
      for (int j=0;j<8;j++) acc[i][j] += a[i]*c[j];
  }
  const float* xxp = ws + OFF_XX + b*N_ + bx*128 + tc*8;
  float xxm[8];
  #pragma unroll
  for (int j=0;j<8;j++) xxm[j] = xxp[j];
  #pragma unroll
  for (int i=0;i<8;i++){
    long row = (long)(by*128 + tr*8 + i)*N_ + bx*128 + tc*8;
    float4 o0 = make_float4(2.f*acc[i][0]-xxm[0], 2.f*acc[i][1]-xxm[1],
                            2.f*acc[i][2]-xxm[2], 2.f*acc[i][3]-xxm[3]);
    float4 o1 = make_float4(2.f*acc[i][4]-xxm[4], 2.f*acc[i][5]-xxm[5],
                            2.f*acc[i][6]-xxm[6], 2.f*acc[i][7]-xxm[7]);
    ((float4*)(pair+row))[0] = o0;
    ((float4*)(pair+row))[1] = o1;
  }
}

// ---------------- K2b: top-20 over stored pair rows (LDS-free, 4 rows/blk) --
__global__ __launch_bounds__(256) void k_topk_pair(const float* __restrict__ pair, int* __restrict__ idx1,
                                                   int b, int n0){
  int t = threadIdx.x;
  int lane = t & 63, wv = t >> 6;
  int r = blockIdx.x*4 + wv;
  const float* rowp = pair + (long)r*N_;
  const float4* src = (const float4*)rowp;
  float mv = -3.0e38f; uint32_t mi = 0;
  #pragma unroll
  for (int q=0;q<16;q++){
    float4 v = src[lane + 64*q];
    uint32_t m0 = 4u*(uint32_t)lane + 256u*q;
    if (v.x > mv){ mv = v.x; mi = m0; }
    if (v.y > mv){ mv = v.y; mi = m0+1; }
    if (v.z > mv){ mv = v.z; mi = m0+2; }
    if (v.w > mv){ mv = v.w; mi = m0+3; }
  }
  uint64_t K = ((uint64_t)fsort(mv) << 32) | (uint32_t)(~mi);
  topk_fetch(K, lane, [&](uint32_t mre){ return rowp[mre]; },
             idx1 + (long)(b*N_ + n0 + r)*KNN);
}

// ---------------- K3: fused coord-space kNN (LDS-free, 4 queries/blk) -------
__global__ __launch_bounds__(256) void k_knn2(const float* __restrict__ ws, int* __restrict__ idx2){
  int t = threadIdx.x;
  int lane = t & 63, wv = t >> 6;
  int n = blockIdx.x*4 + wv;
  int base = n & ~4095;
  const float* Xp = ws + OFF_X, *Yp = ws + OFF_Y, *Zp = ws + OFF_Z, *Cp = ws + OFF_XXC;
  float xn = Xp[n], yn = Yp[n], zn = Zp[n];
  float mv = -3.0e38f; uint32_t mi = 0;
  #pragma unroll 4
  for (int q=0;q<16;q++){
    uint32_t m0 = 4u*(uint32_t)lane + 256u*q;
    float4 X4 = *(const float4*)(Xp + base + m0);
    float4 Y4 = *(const float4*)(Yp + base + m0);
    float4 Z4 = *(const float4*)(Zp + base + m0);
    float4 C4 = *(const float4*)(Cp + base + m0);
    float d0 = distf(xn,yn,zn, X4.x,Y4.x,Z4.x,C4.x);
    float d1 = distf(xn,yn,zn, X4.y,Y4.y,Z4.y,C4.y);
    float d2 = distf(xn,yn,zn, X4.z,Y4.z,Z4.z,C4.z);
    float d3 = distf(xn,yn,zn, X4.w,Y4.w,Z4.w,C4.w);
    if (d0 > mv){ mv = d0; mi = m0; }
    if (d1 > mv){ mv = d1; mi = m0+1; }
    if (d2 > mv){ mv = d2; mi = m0+2; }
    if (d3 > mv){ mv = d3; mi = m0+3; }
  }
  uint64_t K = ((uint64_t)fsort(mv) << 32) | (uint32_t)(~mi);
  topk_fetch(K, lane, [&](uint32_t mre){
      return distf(xn,yn,zn, Xp[base+mre], Yp[base+mre], Zp[base+mre], Cp[base+mre]);
    }, idx2 + (long)n*KNN);
}

// ---------------- K3b: u = (Wa-Wb)h2, v = Wb h2 (post-kNN) ------------------
__global__ void k_uv(float* __restrict__ ws){
  const float* wf = ws + OFF_WF;
  int n = blockIdx.x*256 + threadIdx.x;
  float h[64];
  const float4* src = (const float4*)(ws + OFF_H2 + (long)n*64);
  #pragma unroll
  for (int q=0;q<16;q++){ float4 v = src[q]; h[4*q]=v.x; h[4*q+1]=v.y; h[4*q+2]=v.z; h[4*q+3]=v.w; }
  #pragma unroll 1
  for (int o=0;o<64;o++){
    float va=0.f, vb=0.f;
    #pragma unroll
    for (int c=0;c<64;c++){
      va += wf[WF_WDG1+o*128+c]*h[c];
      vb += wf[WF_WDG1+o*128+64+c]*h[c];
    }
    ws[OFF_U + (long)n*64 + o] = va - vb;
    ws[OFF_V + (long)n*64 + o] = vb;
  }
}

// ---------------- K4/K5: edge stage (gathered first conv folded) ------------
// Software-pipelined: idx tile preloaded to LDS (kills dependent idx->gather
// chain); gather for k+1 register-prefetched before the MAC loop so HBM/L2
// latency hides under ~2k cycles of FMA+LDS work; `us` moved to registers
// (LDS 50KB -> 38.4KB -> 4 blocks/CU instead of 3).
template<int USE_U>
__global__ __launch_bounds__(256, 4) void k_edge(float* __restrict__ ws, const int* __restrict__ idxt,
      long uoff, long goff, int w2off,
      int g1off, int b1off, int g2off, int b2off, long outoff){
  __shared__ float y1s[64*65];
  __shared__ float w2s[64*65];
  __shared__ int   idxs[64*KNN];
  const float* wf = ws + OFF_WF;
  int t = threadIdx.x;
  int p0 = blockIdx.x*64;
  int b  = p0 >> 12;
  int lane = t & 63, wv = t >> 6;
  int tr = t & 15, oc = t >> 4;

  #pragma unroll 1
  for (int i=t;i<4096;i+=256){ int o = i>>6, kk = i&63; w2s[o*65+kk] = wf[w2off + i]; }
  #pragma unroll 1
  for (int i=t;i<64*KNN;i+=256) idxs[i] = idxt[(long)p0*KNN + i];

  // per-lane registers replacing LDS us/g1s/b1s/g2s/b2s
  float ur[16];
  if (USE_U){
    #pragma unroll
    for (int jj=0;jj<16;jj++)
      ur[jj] = ws[uoff + (long)(p0 + wv + 4*jj)*64 + lane];
  } else {
    #pragma unroll
    for (int jj=0;jj<16;jj++) ur[jj] = 0.f;
  }
  float g1v = wf[g1off+lane], b1v = wf[b1off+lane];
  float g2r[4], b2r[4];
  #pragma unroll
  for (int j=0;j<4;j++){ g2r[j] = wf[g2off+oc+16*j]; b2r[j] = wf[b2off+oc+16*j]; }

  float mx[4][4];
  #pragma unroll
  for (int i=0;i<4;i++)
    #pragma unroll
    for (int j=0;j<4;j++) mx[i][j] = -3.0e38f;

  __syncthreads();   // idxs + w2s ready

  long gbase = goff + ((long)b << 12)*64;
  float pf[16];
  #pragma unroll
  for (int jj=0;jj<16;jj++){
    int nb = idxs[(wv + 4*jj)*KNN];
    pf[jj] = ws[gbase + (long)nb*64 + lane];
  }

  for (int k=0;k<KNN;k++){
    // write phase: consume prefetched gather for this k
    #pragma unroll
    for (int jj=0;jj<16;jj++){
      int e = wv + 4*jj;
      float val = pf[jj];
      if (USE_U) val += ur[jj];
      y1s[e*65 + lane] = lrelu(g1v*val + b1v);
    }
    __syncthreads();
    // issue next-k gather NOW; latency hides under the MAC loop below
    if (k+1 < KNN){
      #pragma unroll
      for (int jj=0;jj<16;jj++){
        int nb = idxs[(wv + 4*jj)*KNN + k+1];
        pf[jj] = ws[gbase + (long)nb*64 + lane];
      }
    }
    float acc[4][4] = {};
    #pragma unroll 4
    for (int kk=0;kk<64;kk++){
      float a0 = y1s[(tr   )*65+kk], a1 = y1s[(tr+16)*65+kk];
      float a2 = y1s[(tr+32)*65+kk], a3 = y1s[(tr+48)*65+kk];
      float c0 = w2s[(oc   )*65+kk], c1 = w2s[(oc+16)*65+kk];
      float c2 = w2s[(oc+32)*65+kk], c3 = w2s[(oc+48)*65+kk];
      acc[0][0]+=a0*c0; acc[0][1]+=a0*c1; acc[0][2]+=a0*c2; acc[0][3]+=a0*c3;
      acc[1][0]+=a1*c0; acc[1][1]+=a1*c1; acc[1][2]+=a1*c2; acc[1][3]+=a1*c3;
      acc[2][0]+=a2*c0; acc[2][1]+=a2*c1; acc[2][2]+=a2*c2; acc[2][3]+=a2*c3;
      acc[3][0]+=a3*c0; acc[3][1]+=a3*c1; acc[3][2]+=a3*c2; acc[3][3]+=a3*c3;
    }
    #pragma unroll
    for (int i=0;i<4;i++)
      #pragma unroll
      for (int j=0;j<4;j++){
        float yy = lrelu(g2r[j]*acc[i][j] + b2r[j]);
        mx[i][j] = fmaxf(mx[i][j], yy);
      }
    __syncthreads();
  }
  #pragma unroll
  for (int i=0;i<4;i++)
    #pragma unroll
    for (int j=0;j<4;j++)
      ws[outoff + (long)(p0 + tr + 16*i)*64 + oc + 16*j] = mx[i][j];
}

// ---------------- K4b: w = Wsn1 . hdg per point (stored raw) ----------------
__global__ void k_w(float* __restrict__ ws){
  const float* wf = ws + OFF_WF;
  int n = blockIdx.x*256 + threadIdx.x;
  float h[64];
  const float4* src = (const float4*)(ws + OFF_HDG + (long)n*64);
  #pragma unroll
  for (int q=0;q<16;q++){ float4 v = src[q]; h[4*q]=v.x; h[4*q+1]=v.y; h[4*q+2]=v.z; h[4*q+3]=v.w; }
  #pragma unroll 1
  for (int o=0;o<64;o++){
    float a = 0.f;
    #pragma unroll
    for (int c=0;c<64;c++) a += wf[WF_WSN1 + o*64 + c]*h[c];
    ws[OFF_U + (long)n*64 + o] = a;
  }
}

// ---------------- K6a: head conv3+conv4, h4 out in k-major [128][NP] --------
__global__ __launch_bounds__(256) void k_h4(const float* __restrict__ ws, float* __restrict__ h4g){
  __shared__ float Hs[64*65];    // [ch][pt] (hsn), then reused as [o3][pt] (h3)
  __shared__ float wb[64*130];   // W3 as wb[c*65+o]; later W4 as wb[c*130+o]
  const float* wf = ws + OFF_WF;
  int t = threadIdx.x;
  int p0 = blockIdx.x*64;

  {
    int r = t >> 2, c0 = (t & 3)*16;
    const float4* src = (const float4*)(ws + OFF_H2 + (long)(p0 + r)*64 + c0);
    #pragma unroll
    for (int q=0;q<4;q++){
      float4 v = src[q];
      Hs[(c0+4*q+0)*65 + r] = v.x; Hs[(c0+4*q+1)*65 + r] = v.y;
      Hs[(c0+4*q+2)*65 + r] = v.z; Hs[(c0+4*q+3)*65 + r] = v.w;
    }
  }
  {
    int r = t >> 2, c0 = (t & 3)*16;
    const float4* src = (const float4*)(wf + WF_W3 + (long)r*64 + c0);
    #pragma unroll
    for (int q=0;q<4;q++){
      float4 v = src[q];
      wb[(c0+4*q+0)*65 + r] = v.x; wb[(c0+4*q+1)*65 + r] = v.y;
      wb[(c0+4*q+2)*65 + r] = v.z; wb[(c0+4*q+3)*65 + r] = v.w;
    }
  }
  __syncthreads();

  int pr = t & 15, og = t >> 4;
  float acc[4][4] = {};
  #pragma unroll 8
  for (int k=0;k<64;k++){
    float4 a = *(const float4*)&Hs[k*65 + pr*4];
    float4 c = *(const float4*)&wb[k*65 + og*4];
    float av[4] = {a.x,a.y,a.z,a.w}, cv[4] = {c.x,c.y,c.z,c.w};
    #pragma unroll
    for (int i=0;i<4;i++)
      #pragma unroll
      for (int j=0;j<4;j++) acc[i][j] += av[i]*cv[j];
  }
  __syncthreads();

  #pragma unroll
  for (int j=0;j<4;j++){
    int o = og*4 + j;
    float g3 = wf[WF_G3+o], b3 = wf[WF_B3+o];
    #pragma unroll
    for (int i=0;i<4;i++)
      Hs[o*65 + pr*4 + i] = lrelu(g3*acc[i][j] + b3);
  }
  {
    int r = t >> 1, c0 = (t & 1)*32;
    const float4* src = (const float4*)(wf + WF_W4 + (long)r*64 + c0);
    #pragma unroll
    for (int q=0;q<8;q++){
      float4 v = src[q];
      wb[(c0+4*q+0)*130 + r] = v.x; wb[(c0+4*q+1)*130 + r] = v.y;
      wb[(c0+4*q+2)*130 + r] = v.z; wb[(c0+4*q+3)*130 + r] = v.w;
    }
  }
  __syncthreads();

  float a2[4][8] = {};
  #pragma unroll 8
  for (int k=0;k<64;k++){
    float4 a = *(const float4*)&Hs[k*65 + pr*4];
    float4 c0 = *(const float4*)&wb[k*130 + og*8];
    float4 c1 = *(const float4*)&wb[k*130 + og*8 + 4];
    float av[4] = {a.x,a.y,a.z,a.w};
    float cv[8] = {c0.x,c0.y,c0.z,c0.w,c1.x,c1.y,c1.z,c1.w};
    #pragma unroll
    for (int i=0;i<4;i++)
      #pragma unroll
      for (int j=0;j<8;j++) a2[i][j] += av[i]*cv[j];
  }
  #pragma unroll
  for (int j=0;j<8;j++){
    int o = og*8 + j;
    float g4 = wf[WF_G4+o], b4 = wf[WF_B4+o];
    #pragma unroll
    for (int i=0;i<4;i++)
      h4g[(long)o*NP + p0 + pr*4 + i] = lrelu(g4*a2[i][j] + b4);
  }
}

// ---------------- K6b: conv5 GEMM [512 x 128] . [128 x NP] ------------------
#define KC 32
__global__ __launch_bounds__(256) void k_conv5(const float* __restrict__ ws, void* __restrict__ outv){
  __shared__ float As[KC*128];   // [k][o]
  __shared__ float Bs[KC*128];   // [k][pt]
  const float* wf = ws + OFF_WF;
  int f = ((const int*)(ws + OFF_FLAG))[0];
  int t = threadIdx.x;
  int p0 = blockIdx.x*128;
  int o0 = blockIdx.y*128;
  const float* H4 = ws + OFF_H4;
  float acc[8][8] = {};

  for (int kc = 0; kc < 128; kc += KC){
    {
      int r = t >> 1, c0 = (t & 1)*16;
      const float4* src = (const float4*)(wf + WF_W5 + (long)(o0 + r)*128 + kc + c0);
      #pragma unroll
      for (int q=0;q<4;q++){
        float4 v = src[q];
        As[(c0+4*q+0)*128 + r] = v.x; As[(c0+4*q+1)*128 + r] = v.y;
        As[(c0+4*q+2)*128 + r] = v.z; As[(c0+4*q+3)*128 + r] = v.w;
      }
    }
    {
      int kr = t >> 3, pc = (t & 7)*16;
      const float4* src = (const float4*)(H4 + (long)(kc + kr)*NP + p0 + pc);
      float4 v0 = src[0], v1 = src[1], v2 = src[2], v3 = src[3];
      *(float4*)&Bs[kr*128 + pc     ] = v0;
      *(float4*)&Bs[kr*128 + pc + 4 ] = v1;
      *(float4*)&Bs[kr*128 + pc + 8 ] = v2;
      *(float4*)&Bs[kr*128 + pc + 12] = v3;
    }
    __syncthreads();
    int tr = t/16, tc = t%16;
    #pragma unroll 8
    for (int k=0;k<KC;k++){
      const float4* ap = (const float4*)&As[k*128 + tr*8];
      const float4* bp = (const float4*)&Bs[k*128 + tc*8];
      float4 a0 = ap[0], a1 = ap[1], b0 = bp[0], b1 = bp[1];
      float a[8] = {a0.x,a0.y,a0.z,a0.w,a1.x,a1.y,a1.z,a1.w};
      float b[8] = {b0.x,b0.y,b0.z,b0.w,b1.x,b1.y,b1.z,b1.w};
      #pragma unroll
      for (int i=0;i<8;i++)
        #pragma unroll
        for (int j=0;j<8;j++) acc[i][j] += a[i]*b[j];
    }
    __syncthreads();
  }

  int tr = t/16, tc = t%16;
  int b = p0 >> 12, nn = (p0 & 4095) + tc*8;
  #pragma unroll
  for (int i=0;i<8;i++){
    int oo = o0 + tr*8 + i;
    float g5 = wf[WF_G5+oo], b5 = wf[WF_B5+oo];
    long base = ((long)(b*512 + oo) << 12) + nn;
    if (f){
      float4 v0 = make_float4(lrelu(g5*acc[i][0]+b5), lrelu(g5*acc[i][1]+b5),
                              lrelu(g5*acc[i][2]+b5), lrelu(g5*acc[i][3]+b5));
      float4 v1 = make_float4(lrelu(g5*acc[i][4]+b5), lrelu(g5*acc[i][5]+b5),
                              lrelu(g5*acc[i][6]+b5), lrelu(g5*acc[i][7]+b5));
      *(float4*)((float*)outv + base)     = v0;
      *(float4*)((float*)outv + base + 4) = v1;
    } else {
      #pragma unroll
      for (int j=0;j<8;j++)
        ((bf16*)outv)[base + j] = __float2bfloat16(lrelu(g5*acc[i][j] + b5));
    }
  }
}

// ---------------- host ------------------------------------------------------
extern "C" void kernel_launch(void* const* d_in, const int* in_sizes, int n_in,
                              void* d_out, int out_size, void* d_ws, size_t ws_size,
                              hipStream_t stream) {
  const void* X = d_in[0];
  float* ws = (float*)d_ws;
  int* flagp = (int*)(ws + OFF_FLAG);

  WPack pk;
  static const int wsz[27] = {192,64,64, 4096,64,64, 8192,64,64, 4096,64,64, 4096,64,64,
                              4096,64,64, 4096,64,64, 8192,128,128, 65536,512,512};
  int off = 0;
  for (int i=0;i<27;i++){ pk.p[i] = d_in[i+1]; pk.off[i] = off; off += wsz[i]; }
  pk.off[27] = off;

  k_detect<<<dim3(1), dim3(64), 0, stream>>>(X, flagp);
  k_wcvt<<<dim3((WF_END+255)/256), dim3(256), 0, stream>>>(pk, ws + OFF_WF, flagp);
  k_point<<<dim3(NP/256), dim3(256), 0, stream>>>(X, ws);
  k_knn2<<<dim3(NP/4), dim3(256), 0, stream>>>(ws, (int*)(ws + OFF_IDX2));

  long availf = (long)(ws_size/4) - OFF_PAIR;
  int chunk = 4096;
  if (availf < (long)N_*N_){
    long c = (availf / N_) & ~127L;
    chunk = (int)(c < 128 ? 128 : c);
    if (chunk > 4096) chunk = 4096;
  }
  for (int b=0;b<8;b++){
    for (int n0=0;n0<N_; n0+=chunk){
      int rows = (N_ - n0 < chunk) ? (N_ - n0) : chunk;
      k_pair<<<dim3(32, rows/128), dim3(256), 0, stream>>>(ws, ws + OFF_PAIR, b, n0);
      k_topk_pair<<<dim3(rows/4), dim3(256), 0, stream>>>(ws + OFF_PAIR, (int*)(ws + OFF_IDX1), b, n0);
    }
  }
  k_uv<<<dim3(NP/256), dim3(256), 0, stream>>>(ws);
  k_edge<1><<<dim3(NP/64), dim3(256), 0, stream>>>(ws, (const int*)(ws + OFF_IDX1),
        OFF_U, OFF_V, WF_WDG2, WF_GDG1, WF_BDG1, WF_GDG2, WF_BDG2, OFF_HDG);
  k_w<<<dim3(NP/256), dim3(256), 0, stream>>>(ws);
  k_edge<0><<<dim3(NP/64), dim3(256), 0, stream>>>(ws, (const int*)(ws + OFF_IDX2),
        0, OFF_U, WF_WSN2, WF_GSN1, WF_BSN1, WF_GSN2, WF_BSN2, OFF_H2);
  k_h4<<<dim3(NP/64), dim3(256), 0, stream>>>(ws, ws + OFF_H4);
  k_conv5<<<dim3(NP/128, 4), dim3(256), 0, stream>>>(ws, d_out);
}

// Round 4
// 1263.435 us; speedup vs baseline: 1.2161x; 1.0375x over previous
//
#include <hip/hip_runtime.h>
#include <hip/hip_bf16.h>
#include <stdint.h>

typedef __hip_bfloat16 bf16;

#define N_   4096
#define NP   32768   // B*N
#define KNN  20

// ---- workspace layout (units: float) ----
#define OFF_H2   0L         // 32768*64 ; later reused as hsn output
#define OFF_XYZ  2097152L   // 3 planes of 32768 (SoA)
#define OFF_X    2097152L
#define OFF_Y    2129920L
#define OFF_Z    2162688L
#define OFF_XX   2195456L   // 32768  (|h2|^2)
#define OFF_XXC  2228224L   // 32768  (|x|^2)
#define OFF_IDX1 2260992L   // 32768*20 int
#define OFF_P4   2260992L   // AoS (x,y,z,|x|^2) 32768*4 floats; lives in the
                            // idx1 region: written by k_point, read by k_knn2,
                            // dead before the pair loop writes idx1 over it.
#define OFF_IDX2 2916352L   // 32768*20 int
#define OFF_WF   3571712L   // 104768 fp32 weights
#define OFF_FLAG 3676480L   // dtype flag (int), 64-float slot
#define OFF_PAIR 3676544L   // pair chunk lives here during kNN phase
// post-kNN reuse of the pair region:
#define OFF_U    3676544L   // 32768*64 ; u=(Wa-Wb)h2 ; later w = Wsn1*hdg
#define OFF_V    5773696L   // 32768*64 ; v = Wb*h2
#define OFF_HDG  7870848L   // 32768*64
#define OFF_H4   5773696L   // 128*32768 k-major; overlaps V+HDG (both dead by then)

// ---- fp32 weight bank offsets ----
#define WF_W1 0
#define WF_G1 192
#define WF_B1 256
#define WF_W2 320
#define WF_G2 4416
#define WF_B2 4480
#define WF_WDG1 4544
#define WF_GDG1 12736
#define WF_BDG1 12800
#define WF_WDG2 12864
#define WF_GDG2 16960
#define WF_BDG2 17024
#define WF_WSN1 17088
#define WF_GSN1 21184
#define WF_BSN1 21248
#define WF_WSN2 21312
#define WF_GSN2 25408
#define WF_BSN2 25472
#define WF_W3 25536
#define WF_G3 29632
#define WF_B3 29696
#define WF_W4 29760
#define WF_G4 37952
#define WF_B4 38080
#define WF_W5 38208
#define WF_G5 103744
#define WF_B5 104256
#define WF_END 104768

__device__ __forceinline__ float lrelu(float x){ return x >= 0.f ? x : 0.01f*x; }

// exact-deterministic distance: MUST be the single source for both fill and
// rescan in k_knn2 (bit-identical results required for ordering consistency)
__device__ __forceinline__ float distf(float xn,float yn,float zn,
                                       float xm,float ym,float zm,float cm){
  return fmaf(2.f, fmaf(xn,xm, fmaf(yn,ym, zn*zm)), -cm);
}

// butterfly max over 64 lanes, float keys (2 instr/step vs ~5 for u64)
// CTRL must be a compile-time constant -> template parameter.
template<int CTRL>
__device__ __forceinline__ float fmax_dpp(float v){
  int o = __builtin_amdgcn_update_dpp(0, __float_as_int(v), CTRL, 0xF, 0xF, true);
  return fmaxf(v, __int_as_float(o));
}
__device__ __forceinline__ float bfly_max_f32(float v){
  v = fmax_dpp<0xB1>(v);    // quad_perm xor1
  v = fmax_dpp<0x4E>(v);    // quad_perm xor2
  v = fmax_dpp<0x124>(v);   // row_ror:4
  v = fmax_dpp<0x128>(v);   // row_ror:8
  v = fmaxf(v, __shfl_xor(v, 16, 64));
  v = fmaxf(v, __shfl_xor(v, 32, 64));
  return v;
}

// branchless insert of (c,m) into per-lane sorted top-2 (k1,i1) >= (k2,i2).
// strict > keeps the earlier (smaller-index) candidate ahead on ties.
__device__ __forceinline__ void ins2(float c, int m, float& k1, int& i1,
                                     float& k2, int& i2){
  bool g1 = c > k1, g2 = c > k2;
  k2 = g2 ? (g1 ? k1 : c) : k2;
  i2 = g2 ? (g1 ? i1 : m) : i2;
  k1 = g1 ? c : k1;
  i1 = g1 ? m : i1;
}

// Exact top-20 by iterative pop. Candidate m in 0..4095; owner lane
// js=(m>>2)&63, within-segment position ord=((m>>8)<<2)|(m&3).
// Each lane holds its segment's best-2 unextracted candidates; pop promotes,
// rescan (rare, ~3/query) rebuilds via refetch(mre) which must be
// bit-consistent with fill values. Ties: within-segment exact (lane order ==
// index order in rescan); cross-segment ties on bit-equal fp32 pick lowest
// owner lane (measure-zero for this data; self-distance is strictly max).
template<typename F>
__device__ __forceinline__ void topk_pairs(float k1, int i1, float k2, int i2,
                                           int lane, F&& refetch,
                                           int* __restrict__ outp){
  const float NEGINF = -__builtin_inff();
  uint32_t mlo = 0, mhi = 0;   // exclusion mask over MY segment's ords
  int keep = 0;
  #pragma unroll 1
  for (int tt = 0; tt < KNN; tt++){
    float g = bfly_max_f32(k1);
    uint64_t ball = __ballot(k1 == g);
    int js = __builtin_amdgcn_readfirstlane((int)(__ffsll((unsigned long long)ball) - 1));
    int wid = __builtin_amdgcn_readlane(i1, js);
    if (lane == tt) keep = wid;
    bool own = (lane == js);
    // exclusion bit for wid (ord/bit are wave-uniform scalars)
    uint32_t ord = (((uint32_t)wid >> 8) << 2) | ((uint32_t)wid & 3u);
    uint32_t blo = (ord < 32u) ? (1u << ord) : 0u;
    uint32_t bhi = (ord >= 32u) ? (1u << (ord - 32u)) : 0u;
    mlo |= own ? blo : 0u;
    mhi |= own ? bhi : 0u;
    k1 = own ? k2 : k1;  i1 = own ? i2 : i1;
    k2 = own ? NEGINF : k2;
    // owner dry? (wave-uniform branch, rare)
    int kown = __builtin_amdgcn_readlane(__float_as_int(k1), js);
    if (kown == (int)0xFF800000u){
      uint32_t mre = (((uint32_t)lane >> 2) << 8) | (((uint32_t)js) << 2) | ((uint32_t)lane & 3u);
      float v = refetch(mre);
      uint32_t bl = (uint32_t)__builtin_amdgcn_readlane((int)mlo, js);
      uint32_t bh = (uint32_t)__builtin_amdgcn_readlane((int)mhi, js);
      uint64_t bm = ((uint64_t)bh << 32) | bl;
      if ((bm >> lane) & 1ull) v = NEGINF;
      float g2 = bfly_max_f32(v);
      uint64_t b2 = __ballot(v == g2);
      int jw = (int)(__ffsll((unsigned long long)b2) - 1);
      uint32_t wm = (((uint32_t)jw >> 2) << 8) | (((uint32_t)js) << 2) | ((uint32_t)jw & 3u);
      if (lane == js){ k1 = g2; i1 = (int)wm; }
    }
  }
  if (lane < KNN) outp[lane] = keep;
}

// ---------------- K-1: dtype detect (1 = fp32 inputs, 0 = bf16) -------------
__global__ void k_detect(const void* __restrict__ x, int* __restrict__ flag){
  int lane = threadIdx.x;
  const bf16* xb = (const bf16*)x;
  int cnt = 0;
  #pragma unroll 1
  for (int i = lane; i < 256; i += 64){
    float v = __bfloat162float(xb[2*i]);
    float a = fabsf(v);
    if (a > 1e-3f && a < 100.f) cnt++;
  }
  #pragma unroll
  for (int off = 32; off; off >>= 1) cnt += __shfl_down(cnt, off, 64);
  if (lane == 0) *flag = (cnt >= 128) ? 0 : 1;
}

// ---------------- K0: convert all weights -> fp32 bank ----------------------
struct WPack {
  const void* p[27];
  int off[28];
};

__global__ void k_wcvt(WPack pk, float* __restrict__ dst, const int* __restrict__ flagp){
  int i = blockIdx.x*256 + threadIdx.x;
  if (i >= WF_END) return;
  int f = *flagp;
  #pragma unroll 1
  for (int s = 0; s < 27; s++){
    if (i < pk.off[s+1]){
      int j = i - pk.off[s];
      dst[i] = f ? ((const float*)pk.p[s])[j]
                 : __bfloat162float(((const bf16*)pk.p[s])[j]);
      return;
    }
  }
}

// ---------------- K1: per-point MLP1+MLP2, norms, coords (SoA + AoS) --------
__global__ void k_point(const void* __restrict__ x, float* __restrict__ ws){
  const float* wf = ws + OFF_WF;
  int f = ((const int*)(ws + OFF_FLAG))[0];
  int n = blockIdx.x*256 + threadIdx.x;
  float x0, x1, x2;
  if (f){
    const float* xf = (const float*)x;
    x0 = xf[n*3+0]; x1 = xf[n*3+1]; x2 = xf[n*3+2];
  } else {
    const bf16* xb = (const bf16*)x;
    x0 = __bfloat162float(xb[n*3+0]);
    x1 = __bfloat162float(xb[n*3+1]);
    x2 = __bfloat162float(xb[n*3+2]);
  }

  float h1[64];
  #pragma unroll
  for (int o=0;o<64;o++){
    float a = wf[WF_W1+o*3+0]*x0 + wf[WF_W1+o*3+1]*x1 + wf[WF_W1+o*3+2]*x2;
    h1[o] = lrelu(wf[WF_G1+o]*a + wf[WF_B1+o]);
  }
  float xx = 0.f;
  #pragma unroll 1
  for (int o=0;o<64;o++){
    float a = 0.f;
    #pragma unroll
    for (int c=0;c<64;c++) a += wf[WF_W2+o*64+c]*h1[c];
    float h2 = lrelu(wf[WF_G2+o]*a + wf[WF_B2+o]);
    ws[OFF_H2 + (long)n*64 + o] = h2;
    xx += h2*h2;
  }
  ws[OFF_XX + n] = xx;
  float cc = x0*x0 + x1*x1 + x2*x2;
  ws[OFF_X + n] = x0; ws[OFF_Y + n] = x1; ws[OFF_Z + n] = x2;
  ws[OFF_XXC + n] = cc;
  *(float4*)(ws + OFF_P4 + 4L*n) = make_float4(x0, x1, x2, cc);
}

// ---------------- K2a: pair GEMM (fp32), per batch chunk --------------------
__global__ __launch_bounds__(256) void k_pair(const float* __restrict__ ws, float* __restrict__ pair,
                                              int b, int n0){
  __shared__ float As[64*128];
  __shared__ float Bs[64*128];
  int t = threadIdx.x;
  int bx = blockIdx.x, by = blockIdx.y;
  const float* h2 = ws + OFF_H2 + (long)b*N_*64;

  int r = t >> 1, c0 = (t & 1)*32;
  const float4* arow = (const float4*)(h2 + (long)(n0 + by*128 + r)*64 + c0);
  const float4* brow = (const float4*)(h2 + (long)(bx*128 + r)*64 + c0);
  #pragma unroll
  for (int q=0;q<8;q++){
    float4 av = arow[q];
    As[(c0+4*q+0)*128 + r] = av.x; As[(c0+4*q+1)*128 + r] = av.y;
    As[(c0+4*q+2)*128 + r] = av.z; As[(c0+4*q+3)*128 + r] = av.w;
    float4 bv = brow[q];
    Bs[(c0+4*q+0)*128 + r] = bv.x; Bs[(c0+4*q+1)*128 + r] = bv.y;
    Bs[(c0+4*q+2)*128 + r] = bv.z; Bs[(c0+4*q+3)*128 + r] = bv.w;
  }
  __syncthreads();

  int tr = t/16, tc = t%16;
  float acc[8][8] = {};
  #pragma unroll 4
  for (int k=0;k<64;k++){
    const float4* ap = (const float4*)&As[k*128 + tr*8];
    const float4* bp = (const float4*)&Bs[k*128 + tc*8];
    float4 a0 = ap[0], a1 = ap[1], c0v = bp[0], c1v = bp[1];
    float a[8] = {a0.x,a0.y,a0.z,a0.w,a1.x,a1.y,a1.z,a1.w};
    float c[8] = {c0v.x,c0v.y,c0v.z,c0v.w,c1v.x,c1v.y,c1v.z,c1v.w};
    #pragma unroll
    for (int i=0;i<8;i++)
      #pragma unroll
      for (int j=0;j<8;j++) acc[i][j] += a[i]*c[j];
  }
  const float* xxp = ws + OFF_XX + b*N_ + bx*128 + tc*8;
  float xxm[8];
  #pragma unroll
  for (int j=0;j<8;j++) xxm[j] = xxp[j];
  #pragma unroll
  for (int i=0;i<8;i++){
    long row = (long)(by*128 + tr*8 + i)*N_ + bx*128 + tc*8;
    float4 o0 = make_float4(2.f*acc[i][0]-xxm[0], 2.f*acc[i][1]-xxm[1],
                            2.f*acc[i][2]-xxm[2], 2.f*acc[i][3]-xxm[3]);
    float4 o1 = make_float4(2.f*acc[i][4]-xxm[4], 2.f*acc[i][5]-xxm[5],
                            2.f*acc[i][6]-xxm[6], 2.f*acc[i][7]-xxm[7]);
    ((float4*)(pair+row))[0] = o0;
    ((float4*)(pair+row))[1] = o1;
  }
}

// ---------------- K2b: top-20 over stored pair rows (pairs-pop, 4 rows/blk) -
__global__ __launch_bounds__(256) void k_topk_pair(const float* __restrict__ pair, int* __restrict__ idx1,
                                                   int b, int n0){
  int t = threadIdx.x;
  int lane = t & 63, wv = t >> 6;
  int r = blockIdx.x*4 + wv;
  const float* rowp = pair + (long)r*N_;
  const float4* src = (const float4*)rowp;
  float k1 = -__builtin_inff(), k2 = -__builtin_inff();
  int i1 = 0, i2 = 0;
  #pragma unroll
  for (int q=0;q<16;q++){
    float4 v = src[lane + 64*q];
    int m0 = 4*lane + 256*q;
    ins2(v.x, m0,   k1,i1,k2,i2);
    ins2(v.y, m0+1, k1,i1,k2,i2);
    ins2(v.z, m0+2, k1,i1,k2,i2);
    ins2(v.w, m0+3, k1,i1,k2,i2);
  }
  topk_pairs(k1,i1,k2,i2, lane, [&](uint32_t mre){ return rowp[mre]; },
             idx1 + (long)(b*N_ + n0 + r)*KNN);
}

// ---------------- K3: fused coord-space kNN (pairs-pop, 4 queries/blk) ------
__global__ __launch_bounds__(256) void k_knn2(const float* __restrict__ ws, int* __restrict__ idx2){
  int t = threadIdx.x;
  int lane = t & 63, wv = t >> 6;
  int n = blockIdx.x*4 + wv;
  int base = n & ~4095;
  const float* Xp = ws + OFF_X, *Yp = ws + OFF_Y, *Zp = ws + OFF_Z, *Cp = ws + OFF_XXC;
  const float4* P4 = (const float4*)(ws + OFF_P4);
  float xn = Xp[n], yn = Yp[n], zn = Zp[n];
  float k1 = -__builtin_inff(), k2 = -__builtin_inff();
  int i1 = 0, i2 = 0;
  #pragma unroll 4
  for (int q=0;q<16;q++){
    int m0 = 4*lane + 256*q;
    float4 X4 = *(const float4*)(Xp + base + m0);
    float4 Y4 = *(const float4*)(Yp + base + m0);
    float4 Z4 = *(const float4*)(Zp + base + m0);
    float4 C4 = *(const float4*)(Cp + base + m0);
    ins2(distf(xn,yn,zn, X4.x,Y4.x,Z4.x,C4.x), m0,   k1,i1,k2,i2);
    ins2(distf(xn,yn,zn, X4.y,Y4.y,Z4.y,C4.y), m0+1, k1,i1,k2,i2);
    ins2(distf(xn,yn,zn, X4.z,Y4.z,Z4.z,C4.z), m0+2, k1,i1,k2,i2);
    ins2(distf(xn,yn,zn, X4.w,Y4.w,Z4.w,C4.w), m0+3, k1,i1,k2,i2);
  }
  topk_pairs(k1,i1,k2,i2, lane, [&](uint32_t mre){
      float4 p = P4[base + (int)mre];
      return distf(xn,yn,zn, p.x, p.y, p.z, p.w);
    }, idx2 + (long)n*KNN);
}

// ---------------- K3b: u = (Wa-Wb)h2, v = Wb h2 (post-kNN) ------------------
__global__ void k_uv(float* __restrict__ ws){
  const float* wf = ws + OFF_WF;
  int n = blockIdx.x*256 + threadIdx.x;
  float h[64];
  const float4* src = (const float4*)(ws + OFF_H2 + (long)n*64);
  #pragma unroll
  for (int q=0;q<16;q++){ float4 v = src[q]; h[4*q]=v.x; h[4*q+1]=v.y; h[4*q+2]=v.z; h[4*q+3]=v.w; }
  #pragma unroll 1
  for (int o=0;o<64;o++){
    float va=0.f, vb=0.f;
    #pragma unroll
    for (int c=0;c<64;c++){
      va += wf[WF_WDG1+o*128+c]*h[c];
      vb += wf[WF_WDG1+o*128+64+c]*h[c];
    }
    ws[OFF_U + (long)n*64 + o] = va - vb;
    ws[OFF_V + (long)n*64 + o] = vb;
  }
}

// ---------------- K4/K5: edge stage (gathered first conv folded) ------------
// Software-pipelined: idx tile preloaded to LDS (kills dependent idx->gather
// chain); gather for k+1 register-prefetched before the MAC loop so HBM/L2
// latency hides under ~2k cycles of FMA+LDS work; `us` moved to registers
// (LDS 50KB -> 38.4KB -> 4 blocks/CU instead of 3).
template<int USE_U>
__global__ __launch_bounds__(256, 4) void k_edge(float* __restrict__ ws, const int* __restrict__ idxt,
      long uoff, long goff, int w2off,
      int g1off, int b1off, int g2off, int b2off, long outoff){
  __shared__ float y1s[64*65];
  __shared__ float w2s[64*65];
  __shared__ int   idxs[64*KNN];
  const float* wf = ws + OFF_WF;
  int t = threadIdx.x;
  int p0 = blockIdx.x*64;
  int b  = p0 >> 12;
  int lane = t & 63, wv = t >> 6;
  int tr = t & 15, oc = t >> 4;

  #pragma unroll 1
  for (int i=t;i<4096;i+=256){ int o = i>>6, kk = i&63; w2s[o*65+kk] = wf[w2off + i]; }
  #pragma unroll 1
  for (int i=t;i<64*KNN;i+=256) idxs[i] = idxt[(long)p0*KNN + i];

  // per-lane registers replacing LDS us/g1s/b1s/g2s/b2s
  float ur[16];
  if (USE_U){
    #pragma unroll
    for (int jj=0;jj<16;jj++)
      ur[jj] = ws[uoff + (long)(p0 + wv + 4*jj)*64 + lane];
  } else {
    #pragma unroll
    for (int jj=0;jj<16;jj++) ur[jj] = 0.f;
  }
  float g1v = wf[g1off+lane], b1v = wf[b1off+lane];
  float g2r[4], b2r[4];
  #pragma unroll
  for (int j=0;j<4;j++){ g2r[j] = wf[g2off+oc+16*j]; b2r[j] = wf[b2off+oc+16*j]; }

  float mx[4][4];
  #pragma unroll
  for (int i=0;i<4;i++)
    #pragma unroll
    for (int j=0;j<4;j++) mx[i][j] = -3.0e38f;

  __syncthreads();   // idxs + w2s ready

  long gbase = goff + ((long)b << 12)*64;
  float pf[16];
  #pragma unroll
  for (int jj=0;jj<16;jj++){
    int nb = idxs[(wv + 4*jj)*KNN];
    pf[jj] = ws[gbase + (long)nb*64 + lane];
  }

  for (int k=0;k<KNN;k++){
    // write phase: consume prefetched gather for this k
    #pragma unroll
    for (int jj=0;jj<16;jj++){
      int e = wv + 4*jj;
      float val = pf[jj];
      if (USE_U) val += ur[jj];
      y1s[e*65 + lane] = lrelu(g1v*val + b1v);
    }
    __syncthreads();
    // issue next-k gather NOW; latency hides under the MAC loop below
    if (k+1 < KNN){
      #pragma unroll
      for (int jj=0;jj<16;jj++){
        int nb = idxs[(wv + 4*jj)*KNN + k+1];
        pf[jj] = ws[gbase + (long)nb*64 + lane];
      }
    }
    float acc[4][4] = {};
    #pragma unroll 4
    for (int kk=0;kk<64;kk++){
      float a0 = y1s[(tr   )*65+kk], a1 = y1s[(tr+16)*65+kk];
      float a2 = y1s[(tr+32)*65+kk], a3 = y1s[(tr+48)*65+kk];
      float c0 = w2s[(oc   )*65+kk], c1 = w2s[(oc+16)*65+kk];
      float c2 = w2s[(oc+32)*65+kk], c3 = w2s[(oc+48)*65+kk];
      acc[0][0]+=a0*c0; acc[0][1]+=a0*c1; acc[0][2]+=a0*c2; acc[0][3]+=a0*c3;
      acc[1][0]+=a1*c0; acc[1][1]+=a1*c1; acc[1][2]+=a1*c2; acc[1][3]+=a1*c3;
      acc[2][0]+=a2*c0; acc[2][1]+=a2*c1; acc[2][2]+=a2*c2; acc[2][3]+=a2*c3;
      acc[3][0]+=a3*c0; acc[3][1]+=a3*c1; acc[3][2]+=a3*c2; acc[3][3]+=a3*c3;
    }
    #pragma unroll
    for (int i=0;i<4;i++)
      #pragma unroll
      for (int j=0;j<4;j++){
        float yy = lrelu(g2r[j]*acc[i][j] + b2r[j]);
        mx[i][j] = fmaxf(mx[i][j], yy);
      }
    __syncthreads();
  }
  #pragma unroll
  for (int i=0;i<4;i++)
    #pragma unroll
    for (int j=0;j<4;j++)
      ws[outoff + (long)(p0 + tr + 16*i)*64 + oc + 16*j] = mx[i][j];
}

// ---------------- K4b: w = Wsn1 . hdg per point (stored raw) ----------------
__global__ void k_w(float* __restrict__ ws){
  const float* wf = ws + OFF_WF;
  int n = blockIdx.x*256 + threadIdx.x;
  float h[64];
  const float4* src = (const float4*)(ws + OFF_HDG + (long)n*64);
  #pragma unroll
  for (int q=0;q<16;q++){ float4 v = src[q]; h[4*q]=v.x; h[4*q+1]=v.y; h[4*q+2]=v.z; h[4*q+3]=v.w; }
  #pragma unroll 1
  for (int o=0;o<64;o++){
    float a = 0.f;
    #pragma unroll
    for (int c=0;c<64;c++) a += wf[WF_WSN1 + o*64 + c]*h[c];
    ws[OFF_U + (long)n*64 + o] = a;
  }
}

// ---------------- K6a: head conv3+conv4, h4 out in k-major [128][NP] --------
__global__ __launch_bounds__(256) void k_h4(const float* __restrict__ ws, float* __restrict__ h4g){
  __shared__ float Hs[64*65];    // [ch][pt] (hsn), then reused as [o3][pt] (h3)
  __shared__ float wb[64*130];   // W3 as wb[c*65+o]; later W4 as wb[c*130+o]
  const float* wf = ws + OFF_WF;
  int t = threadIdx.x;
  int p0 = blockIdx.x*64;

  {
    int r = t >> 2, c0 = (t & 3)*16;
    const float4* src = (const float4*)(ws + OFF_H2 + (long)(p0 + r)*64 + c0);
    #pragma unroll
    for (int q=0;q<4;q++){
      float4 v = src[q];
      Hs[(c0+4*q+0)*65 + r] = v.x; Hs[(c0+4*q+1)*65 + r] = v.y;
      Hs[(c0+4*q+2)*65 + r] = v.z; Hs[(c0+4*q+3)*65 + r] = v.w;
    }
  }
  {
    int r = t >> 2, c0 = (t & 3)*16;
    const float4* src = (const float4*)(wf + WF_W3 + (long)r*64 + c0);
    #pragma unroll
    for (int q=0;q<4;q++){
      float4 v = src[q];
      wb[(c0+4*q+0)*65 + r] = v.x; wb[(c0+4*q+1)*65 + r] = v.y;
      wb[(c0+4*q+2)*65 + r] = v.z; wb[(c0+4*q+3)*65 + r] = v.w;
    }
  }
  __syncthreads();

  int pr = t & 15, og = t >> 4;
  float acc[4][4] = {};
  #pragma unroll 8
  for (int k=0;k<64;k++){
    float4 a = *(const float4*)&Hs[k*65 + pr*4];
    float4 c = *(const float4*)&wb[k*65 + og*4];
    float av[4] = {a.x,a.y,a.z,a.w}, cv[4] = {c.x,c.y,c.z,c.w};
    #pragma unroll
    for (int i=0;i<4;i++)
      #pragma unroll
      for (int j=0;j<4;j++) acc[i][j] += av[i]*cv[j];
  }
  __syncthreads();

  #pragma unroll
  for (int j=0;j<4;j++){
    int o = og*4 + j;
    float g3 = wf[WF_G3+o], b3 = wf[WF_B3+o];
    #pragma unroll
    for (int i=0;i<4;i++)
      Hs[o*65 + pr*4 + i] = lrelu(g3*acc[i][j] + b3);
  }
  {
    int r = t >> 1, c0 = (t & 1)*32;
    const float4* src = (const float4*)(wf + WF_W4 + (long)r*64 + c0);
    #pragma unroll
    for (int q=0;q<8;q++){
      float4 v = src[q];
      wb[(c0+4*q+0)*130 + r] = v.x; wb[(c0+4*q+1)*130 + r] = v.y;
      wb[(c0+4*q+2)*130 + r] = v.z; wb[(c0+4*q+3)*130 + r] = v.w;
    }
  }
  __syncthreads();

  float a2[4][8] = {};
  #pragma unroll 8
  for (int k=0;k<64;k++){
    float4 a = *(const float4*)&Hs[k*65 + pr*4];
    float4 c0 = *(const float4*)&wb[k*130 + og*8];
    float4 c1 = *(const float4*)&wb[k*130 + og*8 + 4];
    float av[4] = {a.x,a.y,a.z,a.w};
    float cv[8] = {c0.x,c0.y,c0.z,c0.w,c1.x,c1.y,c1.z,c1.w};
    #pragma unroll
    for (int i=0;i<4;i++)
      #pragma unroll
      for (int j=0;j<8;j++) a2[i][j] += av[i]*cv[j];
  }
  #pragma unroll
  for (int j=0;j<8;j++){
    int o = og*8 + j;
    float g4 = wf[WF_G4+o], b4 = wf[WF_B4+o];
    #pragma unroll
    for (int i=0;i<4;i++)
      h4g[(long)o*NP + p0 + pr*4 + i] = lrelu(g4*a2[i][j] + b4);
  }
}

// ---------------- K6b: conv5 GEMM [512 x 128] . [128 x NP] ------------------
#define KC 32
__global__ __launch_bounds__(256) void k_conv5(const float* __restrict__ ws, void* __restrict__ outv){
  __shared__ float As[KC*128];   // [k][o]
  __shared__ float Bs[KC*128];   // [k][pt]
  const float* wf = ws + OFF_WF;
  int f = ((const int*)(ws + OFF_FLAG))[0];
  int t = threadIdx.x;
  int p0 = blockIdx.x*128;
  int o0 = blockIdx.y*128;
  const float* H4 = ws + OFF_H4;
  float acc[8][8] = {};

  for (int kc = 0; kc < 128; kc += KC){
    {
      int r = t >> 1, c0 = (t & 1)*16;
      const float4* src = (const float4*)(wf + WF_W5 + (long)(o0 + r)*128 + kc + c0);
      #pragma unroll
      for (int q=0;q<4;q++){
        float4 v = src[q];
        As[(c0+4*q+0)*128 + r] = v.x; As[(c0+4*q+1)*128 + r] = v.y;
        As[(c0+4*q+2)*128 + r] = v.z; As[(c0+4*q+3)*128 + r] = v.w;
      }
    }
    {
      int kr = t >> 3, pc = (t & 7)*16;
      const float4* src = (const float4*)(H4 + (long)(kc + kr)*NP + p0 + pc);
      float4 v0 = src[0], v1 = src[1], v2 = src[2], v3 = src[3];
      *(float4*)&Bs[kr*128 + pc     ] = v0;
      *(float4*)&Bs[kr*128 + pc + 4 ] = v1;
      *(float4*)&Bs[kr*128 + pc + 8 ] = v2;
      *(float4*)&Bs[kr*128 + pc + 12] = v3;
    }
    __syncthreads();
    int tr = t/16, tc = t%16;
    #pragma unroll 8
    for (int k=0;k<KC;k++){
      const float4* ap = (const float4*)&As[k*128 + tr*8];
      const float4* bp = (const float4*)&Bs[k*128 + tc*8];
      float4 a0 = ap[0], a1 = ap[1], b0 = bp[0], b1 = bp[1];
      float a[8] = {a0.x,a0.y,a0.z,a0.w,a1.x,a1.y,a1.z,a1.w};
      float b[8] = {b0.x,b0.y,b0.z,b0.w,b1.x,b1.y,b1.z,b1.w};
      #pragma unroll
      for (int i=0;i<8;i++)
        #pragma unroll
        for (int j=0;j<8;j++) acc[i][j] += a[i]*b[j];
    }
    __syncthreads();
  }

  int tr = t/16, tc = t%16;
  int b = p0 >> 12, nn = (p0 & 4095) + tc*8;
  #pragma unroll
  for (int i=0;i<8;i++){
    int oo = o0 + tr*8 + i;
    float g5 = wf[WF_G5+oo], b5 = wf[WF_B5+oo];
    long base = ((long)(b*512 + oo) << 12) + nn;
    if (f){
      float4 v0 = make_float4(lrelu(g5*acc[i][0]+b5), lrelu(g5*acc[i][1]+b5),
                              lrelu(g5*acc[i][2]+b5), lrelu(g5*acc[i][3]+b5));
      float4 v1 = make_float4(lrelu(g5*acc[i][4]+b5), lrelu(g5*acc[i][5]+b5),
                              lrelu(g5*acc[i][6]+b5), lrelu(g5*acc[i][7]+b5));
      *(float4*)((float*)outv + base)     = v0;
      *(float4*)((float*)outv + base + 4) = v1;
    } else {
      #pragma unroll
      for (int j=0;j<8;j++)
        ((bf16*)outv)[base + j] = __float2bfloat16(lrelu(g5*acc[i][j] + b5));
    }
  }
}

// ---------------- host ------------------------------------------------------
extern "C" void kernel_launch(void* const* d_in, const int* in_sizes, int n_in,
                              void* d_out, int out_size, void* d_ws, size_t ws_size,
                              hipStream_t stream) {
  const void* X = d_in[0];
  float* ws = (float*)d_ws;
  int* flagp = (int*)(ws + OFF_FLAG);

  WPack pk;
  static const int wsz[27] = {192,64,64, 4096,64,64, 8192,64,64, 4096,64,64, 4096,64,64,
                              4096,64,64, 4096,64,64, 8192,128,128, 65536,512,512};
  int off = 0;
  for (int i=0;i<27;i++){ pk.p[i] = d_in[i+1]; pk.off[i] = off; off += wsz[i]; }
  pk.off[27] = off;

  k_detect<<<dim3(1), dim3(64), 0, stream>>>(X, flagp);
  k_wcvt<<<dim3((WF_END+255)/256), dim3(256), 0, stream>>>(pk, ws + OFF_WF, flagp);
  k_point<<<dim3(NP/256), dim3(256), 0, stream>>>(X, ws);
  k_knn2<<<dim3(NP/4), dim3(256), 0, stream>>>(ws, (int*)(ws + OFF_IDX2));

  long availf = (long)(ws_size/4) - OFF_PAIR;
  int chunk = 4096;
  if (availf < (long)N_*N_){
    long c = (availf / N_) & ~127L;
    chunk = (int)(c < 128 ? 128 : c);
    if (chunk > 4096) chunk = 4096;
  }
  for (int b=0;b<8;b++){
    for (int n0=0;n0<N_; n0+=chunk){
      int rows = (N_ - n0 < chunk) ? (N_ - n0) : chunk;
      k_pair<<<dim3(32, rows/128), dim3(256), 0, stream>>>(ws, ws + OFF_PAIR, b, n0);
      k_topk_pair<<<dim3(rows/4), dim3(256), 0, stream>>>(ws + OFF_PAIR, (int*)(ws + OFF_IDX1), b, n0);
    }
  }
  k_uv<<<dim3(NP/256), dim3(256), 0, stream>>>(ws);
  k_edge<1><<<dim3(NP/64), dim3(256), 0, stream>>>(ws, (const int*)(ws + OFF_IDX1),
        OFF_U, OFF_V, WF_WDG2, WF_GDG1, WF_BDG1, WF_GDG2, WF_BDG2, OFF_HDG);
  k_w<<<dim3(NP/256), dim3(256), 0, stream>>>(ws);
  k_edge<0><<<dim3(NP/64), dim3(256), 0, stream>>>(ws, (const int*)(ws + OFF_IDX2),
        0, OFF_U, WF_WSN2, WF_GSN1, WF_BSN1, WF_GSN2, WF_BSN2, OFF_H2);
  k_h4<<<dim3(NP/64), dim3(256), 0, stream>>>(ws, ws + OFF_H4);
  k_conv5<<<dim3(NP/128, 4), dim3(256), 0, stream>>>(ws, d_out);
}

// Round 5
// 1261.245 us; speedup vs baseline: 1.2182x; 1.0017x over previous
//
#include <hip/hip_runtime.h>
#include <hip/hip_bf16.h>
#include <stdint.h>

typedef __hip_bfloat16 bf16;

#define N_   4096
#define NP   32768   // B*N
#define KNN  20

// ---- workspace layout (units: float) ----
#define OFF_H2   0L         // 32768*64 ; later reused as hsn output
#define OFF_XYZ  2097152L   // 3 planes of 32768 (SoA)
#define OFF_X    2097152L
#define OFF_Y    2129920L
#define OFF_Z    2162688L
#define OFF_XX   2195456L   // 32768  (|h2|^2)
#define OFF_XXC  2228224L   // 32768  (|x|^2)
#define OFF_IDX1 2260992L   // 32768*20 int
#define OFF_P4   2260992L   // AoS (x,y,z,|x|^2) 32768*4 floats; lives in the
                            // idx1 region: written by k_point, read by k_knn2,
                            // dead before the pair loop writes idx1 over it.
#define OFF_IDX2 2916352L   // 32768*20 int
#define OFF_WF   3571712L   // 104768 fp32 weights
#define OFF_FLAG 3676480L   // dtype flag (int), 64-float slot
#define OFF_PAIR 3676544L   // pair chunk lives here during kNN phase
// post-kNN reuse of the pair region:
#define OFF_U    3676544L   // 32768*64 ; u=(Wa-Wb)h2 ; later w = Wsn1*hdg
#define OFF_V    5773696L   // 32768*64 ; v = Wb*h2
#define OFF_HDG  7870848L   // 32768*64
#define OFF_H4   5773696L   // 128*32768 k-major; overlaps V+HDG (both dead by then)

// ---- fp32 weight bank offsets ----
#define WF_W1 0
#define WF_G1 192
#define WF_B1 256
#define WF_W2 320
#define WF_G2 4416
#define WF_B2 4480
#define WF_WDG1 4544
#define WF_GDG1 12736
#define WF_BDG1 12800
#define WF_WDG2 12864
#define WF_GDG2 16960
#define WF_BDG2 17024
#define WF_WSN1 17088
#define WF_GSN1 21184
#define WF_BSN1 21248
#define WF_WSN2 21312
#define WF_GSN2 25408
#define WF_BSN2 25472
#define WF_W3 25536
#define WF_G3 29632
#define WF_B3 29696
#define WF_W4 29760
#define WF_G4 37952
#define WF_B4 38080
#define WF_W5 38208
#define WF_G5 103744
#define WF_B5 104256
#define WF_END 104768

__device__ __forceinline__ float lrelu(float x){ return x >= 0.f ? x : 0.01f*x; }

// exact-deterministic distance: MUST be the single source for both fill and
// rescan in k_knn2 (bit-identical results required for ordering consistency)
__device__ __forceinline__ float distf(float xn,float yn,float zn,
                                       float xm,float ym,float zm,float cm){
  return fmaf(2.f, fmaf(xn,xm, fmaf(yn,ym, zn*zm)), -cm);
}

// DPP-step max; CTRL must be a compile-time constant -> template parameter.
template<int CTRL>
__device__ __forceinline__ float fmax_dpp(float v){
  int o = __builtin_amdgcn_update_dpp(0, __float_as_int(v), CTRL, 0xF, 0xF, true);
  return fmaxf(v, __int_as_float(o));
}
// Full-wave max returned as a wave-uniform scalar (SGPR broadcast).
// Pure DPP/VALU — no ds_bpermute (the r4 stall): xor1/xor2/ror4/ror8 give
// 16-lane row maxes; ROW_BCAST15 (0x142) + ROW_BCAST31 (0x143) funnel the
// global max to lane 63; readlane broadcasts it. bound_ctrl=1 corrupts lanes
// 0-15 after bcast15 (fmax with 0.0) but those lanes are never on the
// dataflow path to lane 63.
__device__ __forceinline__ float wave_max_bcast(float v){
  v = fmax_dpp<0xB1>(v);    // quad_perm xor1
  v = fmax_dpp<0x4E>(v);    // quad_perm xor2
  v = fmax_dpp<0x124>(v);   // row_ror:4
  v = fmax_dpp<0x128>(v);   // row_ror:8  -> row max in all 16 lanes of a row
  v = fmax_dpp<0x142>(v);   // row_bcast15: 15->16..31, 47->48..63
  v = fmax_dpp<0x143>(v);   // row_bcast31: 31->32..63; lane 63 = global max
  return __int_as_float(__builtin_amdgcn_readlane(__float_as_int(v), 63));
}

// branchless insert of (c,m) into per-lane sorted top-2 (k1,i1) >= (k2,i2).
// strict > keeps the earlier (smaller-index) candidate ahead on ties.
__device__ __forceinline__ void ins2(float c, int m, float& k1, int& i1,
                                     float& k2, int& i2){
  bool g1 = c > k1, g2 = c > k2;
  k2 = g2 ? (g1 ? k1 : c) : k2;
  i2 = g2 ? (g1 ? i1 : m) : i2;
  k1 = g1 ? c : k1;
  i1 = g1 ? m : i1;
}

// Exact top-20 by iterative pop. Candidate m in 0..4095; owner lane
// js=(m>>2)&63, within-segment position ord=((m>>8)<<2)|(m&3).
// Each lane holds its segment's best-2 unextracted candidates; pop promotes,
// rescan (rare, ~3/query) rebuilds via refetch(mre) which must be
// bit-consistent with fill values. Ties: within-segment exact (lane order ==
// index order in rescan); cross-segment ties on bit-equal fp32 pick lowest
// owner lane (measure-zero for this data; self-distance is strictly max).
template<typename F>
__device__ __forceinline__ void topk_pairs(float k1, int i1, float k2, int i2,
                                           int lane, F&& refetch,
                                           int* __restrict__ outp){
  const float NEGINF = -__builtin_inff();
  uint32_t mlo = 0, mhi = 0;   // exclusion mask over MY segment's ords
  int keep = 0;
  #pragma unroll 1
  for (int tt = 0; tt < KNN; tt++){
    float g = wave_max_bcast(k1);
    uint64_t ball = __ballot(k1 == g);
    int js = __builtin_amdgcn_readfirstlane((int)(__ffsll((unsigned long long)ball) - 1));
    int wid = __builtin_amdgcn_readlane(i1, js);
    // dry check reads OLD k2 of js (== js's k1 after the pop below) so the
    // readlane doesn't serialize behind the cndmask updates.
    int kown = __builtin_amdgcn_readlane(__float_as_int(k2), js);
    if (lane == tt) keep = wid;
    bool own = (lane == js);
    // exclusion bit for wid (ord/bit are wave-uniform scalars)
    uint32_t ord = (((uint32_t)wid >> 8) << 2) | ((uint32_t)wid & 3u);
    uint32_t blo = (ord < 32u) ? (1u << ord) : 0u;
    uint32_t bhi = (ord >= 32u) ? (1u << (ord - 32u)) : 0u;
    mlo |= own ? blo : 0u;
    mhi |= own ? bhi : 0u;
    k1 = own ? k2 : k1;  i1 = own ? i2 : i1;
    k2 = own ? NEGINF : k2;
    // owner dry? (wave-uniform branch, rare)
    if (kown == (int)0xFF800000u){
      uint32_t mre = (((uint32_t)lane >> 2) << 8) | (((uint32_t)js) << 2) | ((uint32_t)lane & 3u);
      float v = refetch(mre);
      uint32_t bl = (uint32_t)__builtin_amdgcn_readlane((int)mlo, js);
      uint32_t bh = (uint32_t)__builtin_amdgcn_readlane((int)mhi, js);
      uint64_t bm = ((uint64_t)bh << 32) | bl;
      if ((bm >> lane) & 1ull) v = NEGINF;
      float g2 = wave_max_bcast(v);
      uint64_t b2 = __ballot(v == g2);
      int jw = (int)(__ffsll((unsigned long long)b2) - 1);
      uint32_t wm = (((uint32_t)jw >> 2) << 8) | (((uint32_t)js) << 2) | ((uint32_t)jw & 3u);
      if (lane == js){ k1 = g2; i1 = (int)wm; }
    }
  }
  if (lane < KNN) outp[lane] = keep;
}

// ---------------- K-1: dtype detect (1 = fp32 inputs, 0 = bf16) -------------
__global__ void k_detect(const void* __restrict__ x, int* __restrict__ flag){
  int lane = threadIdx.x;
  const bf16* xb = (const bf16*)x;
  int cnt = 0;
  #pragma unroll 1
  for (int i = lane; i < 256; i += 64){
    float v = __bfloat162float(xb[2*i]);
    float a = fabsf(v);
    if (a > 1e-3f && a < 100.f) cnt++;
  }
  #pragma unroll
  for (int off = 32; off; off >>= 1) cnt += __shfl_down(cnt, off, 64);
  if (lane == 0) *flag = (cnt >= 128) ? 0 : 1;
}

// ---------------- K0: convert all weights -> fp32 bank ----------------------
struct WPack {
  const void* p[27];
  int off[28];
};

__global__ void k_wcvt(WPack pk, float* __restrict__ dst, const int* __restrict__ flagp){
  int i = blockIdx.x*256 + threadIdx.x;
  if (i >= WF_END) return;
  int f = *flagp;
  #pragma unroll 1
  for (int s = 0; s < 27; s++){
    if (i < pk.off[s+1]){
      int j = i - pk.off[s];
      dst[i] = f ? ((const float*)pk.p[s])[j]
                 : __bfloat162float(((const bf16*)pk.p[s])[j]);
      return;
    }
  }
}

// ---------------- K1: per-point MLP1+MLP2, norms, coords (SoA + AoS) --------
__global__ void k_point(const void* __restrict__ x, float* __restrict__ ws){
  const float* wf = ws + OFF_WF;
  int f = ((const int*)(ws + OFF_FLAG))[0];
  int n = blockIdx.x*256 + threadIdx.x;
  float x0, x1, x2;
  if (f){
    const float* xf = (const float*)x;
    x0 = xf[n*3+0]; x1 = xf[n*3+1]; x2 = xf[n*3+2];
  } else {
    const bf16* xb = (const bf16*)x;
    x0 = __bfloat162float(xb[n*3+0]);
    x1 = __bfloat162float(xb[n*3+1]);
    x2 = __bfloat162float(xb[n*3+2]);
  }

  float h1[64];
  #pragma unroll
  for (int o=0;o<64;o++){
    float a = wf[WF_W1+o*3+0]*x0 + wf[WF_W1+o*3+1]*x1 + wf[WF_W1+o*3+2]*x2;
    h1[o] = lrelu(wf[WF_G1+o]*a + wf[WF_B1+o]);
  }
  float xx = 0.f;
  #pragma unroll 1
  for (int o=0;o<64;o++){
    float a = 0.f;
    #pragma unroll
    for (int c=0;c<64;c++) a += wf[WF_W2+o*64+c]*h1[c];
    float h2 = lrelu(wf[WF_G2+o]*a + wf[WF_B2+o]);
    ws[OFF_H2 + (long)n*64 + o] = h2;
    xx += h2*h2;
  }
  ws[OFF_XX + n] = xx;
  float cc = x0*x0 + x1*x1 + x2*x2;
  ws[OFF_X + n] = x0; ws[OFF_Y + n] = x1; ws[OFF_Z + n] = x2;
  ws[OFF_XXC + n] = cc;
  *(float4*)(ws + OFF_P4 + 4L*n) = make_float4(x0, x1, x2, cc);
}

// ---------------- K2a: pair GEMM (fp32), per batch chunk --------------------
__global__ __launch_bounds__(256) void k_pair(const float* __restrict__ ws, float* __restrict__ pair,
                                              int b, int n0){
  __shared__ float As[64*128];
  __shared__ float Bs[64*128];
  int t = threadIdx.x;
  int bx = blockIdx.x, by = blockIdx.y;
  const float* h2 = ws + OFF_H2 + (long)b*N_*64;

  int r = t >> 1, c0 = (t & 1)*32;
  const float4* arow = (const float4*)(h2 + (long)(n0 + by*128 + r)*64 + c0);
  const float4* brow = (const float4*)(h2 + (long)(bx*128 + r)*64 + c0);
  #pragma unroll
  for (int q=0;q<8;q++){
    float4 av = arow[q];
    As[(c0+4*q+0)*128 + r] = av.x; As[(c0+4*q+1)*128 + r] = av.y;
    As[(c0+4*q+2)*128 + r] = av.z; As[(c0+4*q+3)*128 + r] = av.w;
    float4 bv = brow[q];
    Bs[(c0+4*q+0)*128 + r] = bv.x; Bs[(c0+4*q+1)*128 + r] = bv.y;
    Bs[(c0+4*q+2)*128 + r] = bv.z; Bs[(c0+4*q+3)*128 + r] = bv.w;
  }
  __syncthreads();

  int tr = t/16, tc = t%16;
  float acc[8][8] = {};
  #pragma unroll 4
  for (int k=0;k<64;k++){
    const float4* ap = (const float4*)&As[k*128 + tr*8];
    const float4* bp = (const float4*)&Bs[k*128 + tc*8];
    float4 a0 = ap[0], a1 = ap[1], c0v = bp[0], c1v = bp[1];
    float a[8] = {a0.x,a0.y,a0.z,a0.w,a1.x,a1.y,a1.z,a1.w};
    float c[8] = {c0v.x,c0v.y,c0v.z,c0v.w,c1v.x,c1v.y,c1v.z,c1v.w};
    #pragma unroll
    for (int i=0;i<8;i++)
      #pragma unroll
      for (int j=0;j<8;j++) acc[i][j] += a[i]*c[j];
  }
  const float* xxp = ws + OFF_XX + b*N_ + bx*128 + tc*8;
  float xxm[8];
  #pragma unroll
  for (int j=0;j<8;j++) xxm[j] = xxp[j];
  #pragma unroll
  for (int i=0;i<8;i++){
    long row = (long)(by*128 + tr*8 + i)*N_ + bx*128 + tc*8;
    float4 o0 = make_float4(2.f*acc[i][0]-xxm[0], 2.f*acc[i][1]-xxm[1],
                            2.f*acc[i][2]-xxm[2], 2.f*acc[i][3]-xxm[3]);
    float4 o1 = make_float4(2.f*acc[i][4]-xxm[4], 2.f*acc[i][5]-xxm[5],
                            2.f*acc[i][6]-xxm[6], 2.f*acc[i][7]-xxm[7]);
    ((float4*)(pair+row))[0] = o0;
    ((float4*)(pair+row))[1] = o1;
  }
}

// ---------------- K2b: top-20 over stored pair rows (pairs-pop, 4 rows/blk) -
__global__ __launch_bounds__(256) void k_topk_pair(const float* __restrict__ pair, int* __restrict__ idx1,
                                                   int b, int n0){
  int t = threadIdx.x;
  int lane = t & 63, wv = t >> 6;
  int r = blockIdx.x*4 + wv;
  const float* rowp = pair + (long)r*N_;
  const float4* src = (const float4*)rowp;
  float k1 = -__builtin_inff(), k2 = -__builtin_inff();
  int i1 = 0, i2 = 0;
  #pragma unroll
  for (int q=0;q<16;q++){
    float4 v = src[lane + 64*q];
    int m0 = 4*lane + 256*q;
    ins2(v.x, m0,   k1,i1,k2,i2);
    ins2(v.y, m0+1, k1,i1,k2,i2);
    ins2(v.z, m0+2, k1,i1,k2,i2);
    ins2(v.w, m0+3, k1,i1,k2,i2);
  }
  topk_pairs(k1,i1,k2,i2, lane, [&](uint32_t mre){ return rowp[mre]; },
             idx1 + (long)(b*N_ + n0 + r)*KNN);
}

// ---------------- K3: fused coord-space kNN (pairs-pop, 4 queries/blk) ------
__global__ __launch_bounds__(256) void k_knn2(const float* __restrict__ ws, int* __restrict__ idx2){
  int t = threadIdx.x;
  int lane = t & 63, wv = t >> 6;
  int n = blockIdx.x*4 + wv;
  int base = n & ~4095;
  const float* Xp = ws + OFF_X, *Yp = ws + OFF_Y, *Zp = ws + OFF_Z, *Cp = ws + OFF_XXC;
  const float4* P4 = (const float4*)(ws + OFF_P4);
  float xn = Xp[n], yn = Yp[n], zn = Zp[n];
  float k1 = -__builtin_inff(), k2 = -__builtin_inff();
  int i1 = 0, i2 = 0;
  #pragma unroll 4
  for (int q=0;q<16;q++){
    int m0 = 4*lane + 256*q;
    float4 X4 = *(const float4*)(Xp + base + m0);
    float4 Y4 = *(const float4*)(Yp + base + m0);
    float4 Z4 = *(const float4*)(Zp + base + m0);
    float4 C4 = *(const float4*)(Cp + base + m0);
    ins2(distf(xn,yn,zn, X4.x,Y4.x,Z4.x,C4.x), m0,   k1,i1,k2,i2);
    ins2(distf(xn,yn,zn, X4.y,Y4.y,Z4.y,C4.y), m0+1, k1,i1,k2,i2);
    ins2(distf(xn,yn,zn, X4.z,Y4.z,Z4.z,C4.z), m0+2, k1,i1,k2,i2);
    ins2(distf(xn,yn,zn, X4.w,Y4.w,Z4.w,C4.w), m0+3, k1,i1,k2,i2);
  }
  topk_pairs(k1,i1,k2,i2, lane, [&](uint32_t mre){
      float4 p = P4[base + (int)mre];
      return distf(xn,yn,zn, p.x, p.y, p.z, p.w);
    }, idx2 + (long)n*KNN);
}

// ---------------- K3b: u = (Wa-Wb)h2, v = Wb h2 (post-kNN) ------------------
__global__ void k_uv(float* __restrict__ ws){
  const float* wf = ws + OFF_WF;
  int n = blockIdx.x*256 + threadIdx.x;
  float h[64];
  const float4* src = (const float4*)(ws + OFF_H2 + (long)n*64);
  #pragma unroll
  for (int q=0;q<16;q++){ float4 v = src[q]; h[4*q]=v.x; h[4*q+1]=v.y; h[4*q+2]=v.z; h[4*q+3]=v.w; }
  #pragma unroll 1
  for (int o=0;o<64;o++){
    float va=0.f, vb=0.f;
    #pragma unroll
    for (int c=0;c<64;c++){
      va += wf[WF_WDG1+o*128+c]*h[c];
      vb += wf[WF_WDG1+o*128+64+c]*h[c];
    }
    ws[OFF_U + (long)n*64 + o] = va - vb;
    ws[OFF_V + (long)n*64 + o] = vb;
  }
}

// ---------------- K4/K5: edge stage (gathered first conv folded) ------------
// Software-pipelined: idx tile preloaded to LDS (kills dependent idx->gather
// chain); gather for k+1 register-prefetched before the MAC loop so HBM/L2
// latency hides under ~2k cycles of FMA+LDS work; `us` moved to registers
// (LDS 50KB -> 38.4KB -> 4 blocks/CU instead of 3).
template<int USE_U>
__global__ __launch_bounds__(256, 4) void k_edge(float* __restrict__ ws, const int* __restrict__ idxt,
      long uoff, long goff, int w2off,
      int g1off, int b1off, int g2off, int b2off, long outoff){
  __shared__ float y1s[64*65];
  __shared__ float w2s[64*65];
  __shared__ int   idxs[64*KNN];
  const float* wf = ws + OFF_WF;
  int t = threadIdx.x;
  int p0 = blockIdx.x*64;
  int b  = p0 >> 12;
  int lane = t & 63, wv = t >> 6;
  int tr = t & 15, oc = t >> 4;

  #pragma unroll 1
  for (int i=t;i<4096;i+=256){ int o = i>>6, kk = i&63; w2s[o*65+kk] = wf[w2off + i]; }
  #pragma unroll 1
  for (int i=t;i<64*KNN;i+=256) idxs[i] = idxt[(long)p0*KNN + i];

  // per-lane registers replacing LDS us/g1s/b1s/g2s/b2s
  float ur[16];
  if (USE_U){
    #pragma unroll
    for (int jj=0;jj<16;jj++)
      ur[jj] = ws[uoff + (long)(p0 + wv + 4*jj)*64 + lane];
  } else {
    #pragma unroll
    for (int jj=0;jj<16;jj++) ur[jj] = 0.f;
  }
  float g1v = wf[g1off+lane], b1v = wf[b1off+lane];
  float g2r[4], b2r[4];
  #pragma unroll
  for (int j=0;j<4;j++){ g2r[j] = wf[g2off+oc+16*j]; b2r[j] = wf[b2off+oc+16*j]; }

  float mx[4][4];
  #pragma unroll
  for (int i=0;i<4;i++)
    #pragma unroll
    for (int j=0;j<4;j++) mx[i][j] = -3.0e38f;

  __syncthreads();   // idxs + w2s ready

  long gbase = goff + ((long)b << 12)*64;
  float pf[16];
  #pragma unroll
  for (int jj=0;jj<16;jj++){
    int nb = idxs[(wv + 4*jj)*KNN];
    pf[jj] = ws[gbase + (long)nb*64 + lane];
  }

  for (int k=0;k<KNN;k++){
    // write phase: consume prefetched gather for this k
    #pragma unroll
    for (int jj=0;jj<16;jj++){
      int e = wv + 4*jj;
      float val = pf[jj];
      if (USE_U) val += ur[jj];
      y1s[e*65 + lane] = lrelu(g1v*val + b1v);
    }
    __syncthreads();
    // issue next-k gather NOW; latency hides under the MAC loop below
    if (k+1 < KNN){
      #pragma unroll
      for (int jj=0;jj<16;jj++){
        int nb = idxs[(wv + 4*jj)*KNN + k+1];
        pf[jj] = ws[gbase + (long)nb*64 + lane];
      }
    }
    float acc[4][4] = {};
    #pragma unroll 4
    for (int kk=0;kk<64;kk++){
      float a0 = y1s[(tr   )*65+kk], a1 = y1s[(tr+16)*65+kk];
      float a2 = y1s[(tr+32)*65+kk], a3 = y1s[(tr+48)*65+kk];
      float c0 = w2s[(oc   )*65+kk], c1 = w2s[(oc+16)*65+kk];
      float c2 = w2s[(oc+32)*65+kk], c3 = w2s[(oc+48)*65+kk];
      acc[0][0]+=a0*c0; acc[0][1]+=a0*c1; acc[0][2]+=a0*c2; acc[0][3]+=a0*c3;
      acc[1][0]+=a1*c0; acc[1][1]+=a1*c1; acc[1][2]+=a1*c2; acc[1][3]+=a1*c3;
      acc[2][0]+=a2*c0; acc[2][1]+=a2*c1; acc[2][2]+=a2*c2; acc[2][3]+=a2*c3;
      acc[3][0]+=a3*c0; acc[3][1]+=a3*c1; acc[3][2]+=a3*c2; acc[3][3]+=a3*c3;
    }
    #pragma unroll
    for (int i=0;i<4;i++)
      #pragma unroll
      for (int j=0;j<4;j++){
        float yy = lrelu(g2r[j]*acc[i][j] + b2r[j]);
        mx[i][j] = fmaxf(mx[i][j], yy);
      }
    __syncthreads();
  }
  #pragma unroll
  for (int i=0;i<4;i++)
    #pragma unroll
    for (int j=0;j<4;j++)
      ws[outoff + (long)(p0 + tr + 16*i)*64 + oc + 16*j] = mx[i][j];
}

// ---------------- K4b: w = Wsn1 . hdg per point (stored raw) ----------------
__global__ void k_w(float* __restrict__ ws){
  const float* wf = ws + OFF_WF;
  int n = blockIdx.x*256 + threadIdx.x;
  float h[64];
  const float4* src = (const float4*)(ws + OFF_HDG + (long)n*64);
  #pragma unroll
  for (int q=0;q<16;q++){ float4 v = src[q]; h[4*q]=v.x; h[4*q+1]=v.y; h[4*q+2]=v.z; h[4*q+3]=v.w; }
  #pragma unroll 1
  for (int o=0;o<64;o++){
    float a = 0.f;
    #pragma unroll
    for (int c=0;c<64;c++) a += wf[WF_WSN1 + o*64 + c]*h[c];
    ws[OFF_U + (long)n*64 + o] = a;
  }
}

// ---------------- K6a: head conv3+conv4, h4 out in k-major [128][NP] --------
__global__ __launch_bounds__(256) void k_h4(const float* __restrict__ ws, float* __restrict__ h4g){
  __shared__ float Hs[64*65];    // [ch][pt] (hsn), then reused as [o3][pt] (h3)
  __shared__ float wb[64*130];   // W3 as wb[c*65+o]; later W4 as wb[c*130+o]
  const float* wf = ws + OFF_WF;
  int t = threadIdx.x;
  int p0 = blockIdx.x*64;

  {
    int r = t >> 2, c0 = (t & 3)*16;
    const float4* src = (const float4*)(ws + OFF_H2 + (long)(p0 + r)*64 + c0);
    #pragma unroll
    for (int q=0;q<4;q++){
      float4 v = src[q];
      Hs[(c0+4*q+0)*65 + r] = v.x; Hs[(c0+4*q+1)*65 + r] = v.y;
      Hs[(c0+4*q+2)*65 + r] = v.z; Hs[(c0+4*q+3)*65 + r] = v.w;
    }
  }
  {
    int r = t >> 2, c0 = (t & 3)*16;
    const float4* src = (const float4*)(wf + WF_W3 + (long)r*64 + c0);
    #pragma unroll
    for (int q=0;q<4;q++){
      float4 v = src[q];
      wb[(c0+4*q+0)*65 + r] = v.x; wb[(c0+4*q+1)*65 + r] = v.y;
      wb[(c0+4*q+2)*65 + r] = v.z; wb[(c0+4*q+3)*65 + r] = v.w;
    }
  }
  __syncthreads();

  int pr = t & 15, og = t >> 4;
  float acc[4][4] = {};
  #pragma unroll 8
  for (int k=0;k<64;k++){
    float4 a = *(const float4*)&Hs[k*65 + pr*4];
    float4 c = *(const float4*)&wb[k*65 + og*4];
    float av[4] = {a.x,a.y,a.z,a.w}, cv[4] = {c.x,c.y,c.z,c.w};
    #pragma unroll
    for (int i=0;i<4;i++)
      #pragma unroll
      for (int j=0;j<4;j++) acc[i][j] += av[i]*cv[j];
  }
  __syncthreads();

  #pragma unroll
  for (int j=0;j<4;j++){
    int o = og*4 + j;
    float g3 = wf[WF_G3+o], b3 = wf[WF_B3+o];
    #pragma unroll
    for (int i=0;i<4;i++)
      Hs[o*65 + pr*4 + i] = lrelu(g3*acc[i][j] + b3);
  }
  {
    int r = t >> 1, c0 = (t & 1)*32;
    const float4* src = (const float4*)(wf + WF_W4 + (long)r*64 + c0);
    #pragma unroll
    for (int q=0;q<8;q++){
      float4 v = src[q];
      wb[(c0+4*q+0)*130 + r] = v.x; wb[(c0+4*q+1)*130 + r] = v.y;
      wb[(c0+4*q+2)*130 + r] = v.z; wb[(c0+4*q+3)*130 + r] = v.w;
    }
  }
  __syncthreads();

  float a2[4][8] = {};
  #pragma unroll 8
  for (int k=0;k<64;k++){
    float4 a = *(const float4*)&Hs[k*65 + pr*4];
    float4 c0 = *(const float4*)&wb[k*130 + og*8];
    float4 c1 = *(const float4*)&wb[k*130 + og*8 + 4];
    float av[4] = {a.x,a.y,a.z,a.w};
    float cv[8] = {c0.x,c0.y,c0.z,c0.w,c1.x,c1.y,c1.z,c1.w};
    #pragma unroll
    for (int i=0;i<4;i++)
      #pragma unroll
      for (int j=0;j<8;j++) a2[i][j] += av[i]*cv[j];
  }
  #pragma unroll
  for (int j=0;j<8;j++){
    int o = og*8 + j;
    float g4 = wf[WF_G4+o], b4 = wf[WF_B4+o];
    #pragma unroll
    for (int i=0;i<4;i++)
      h4g[(long)o*NP + p0 + pr*4 + i] = lrelu(g4*a2[i][j] + b4);
  }
}

// ---------------- K6b: conv5 GEMM [512 x 128] . [128 x NP] ------------------
#define KC 32
__global__ __launch_bounds__(256) void k_conv5(const float* __restrict__ ws, void* __restrict__ outv){
  __shared__ float As[KC*128];   // [k][o]
  __shared__ float Bs[KC*128];   // [k][pt]
  const float* wf = ws + OFF_WF;
  int f = ((const int*)(ws + OFF_FLAG))[0];
  int t = threadIdx.x;
  int p0 = blockIdx.x*128;
  int o0 = blockIdx.y*128;
  const float* H4 = ws + OFF_H4;
  float acc[8][8] = {};

  for (int kc = 0; kc < 128; kc += KC){
    {
      int r = t >> 1, c0 = (t & 1)*16;
      const float4* src = (const float4*)(wf + WF_W5 + (long)(o0 + r)*128 + kc + c0);
      #pragma unroll
      for (int q=0;q<4;q++){
        float4 v = src[q];
        As[(c0+4*q+0)*128 + r] = v.x; As[(c0+4*q+1)*128 + r] = v.y;
        As[(c0+4*q+2)*128 + r] = v.z; As[(c0+4*q+3)*128 + r] = v.w;
      }
    }
    {
      int kr = t >> 3, pc = (t & 7)*16;
      const float4* src = (const float4*)(H4 + (long)(kc + kr)*NP + p0 + pc);
      float4 v0 = src[0], v1 = src[1], v2 = src[2], v3 = src[3];
      *(float4*)&Bs[kr*128 + pc     ] = v0;
      *(float4*)&Bs[kr*128 + pc + 4 ] = v1;
      *(float4*)&Bs[kr*128 + pc + 8 ] = v2;
      *(float4*)&Bs[kr*128 + pc + 12] = v3;
    }
    __syncthreads();
    int tr = t/16, tc = t%16;
    #pragma unroll 8
    for (int k=0;k<KC;k++){
      const float4* ap = (const float4*)&As[k*128 + tr*8];
      const float4* bp = (const float4*)&Bs[k*128 + tc*8];
      float4 a0 = ap[0], a1 = ap[1], b0 = bp[0], b1 = bp[1];
      float a[8] = {a0.x,a0.y,a0.z,a0.w,a1.x,a1.y,a1.z,a1.w};
      float b[8] = {b0.x,b0.y,b0.z,b0.w,b1.x,b1.y,b1.z,b1.w};
      #pragma unroll
      for (int i=0;i<8;i++)
        #pragma unroll
        for (int j=0;j<8;j++) acc[i][j] += a[i]*b[j];
    }
    __syncthreads();
  }

  int tr = t/16, tc = t%16;
  int b = p0 >> 12, nn = (p0 & 4095) + tc*8;
  #pragma unroll
  for (int i=0;i<8;i++){
    int oo = o0 + tr*8 + i;
    float g5 = wf[WF_G5+oo], b5 = wf[WF_B5+oo];
    long base = ((long)(b*512 + oo) << 12) + nn;
    if (f){
      float4 v0 = make_float4(lrelu(g5*acc[i][0]+b5), lrelu(g5*acc[i][1]+b5),
                              lrelu(g5*acc[i][2]+b5), lrelu(g5*acc[i][3]+b5));
      float4 v1 = make_float4(lrelu(g5*acc[i][4]+b5), lrelu(g5*acc[i][5]+b5),
                              lrelu(g5*acc[i][6]+b5), lrelu(g5*acc[i][7]+b5));
      *(float4*)((float*)outv + base)     = v0;
      *(float4*)((float*)outv + base + 4) = v1;
    } else {
      #pragma unroll
      for (int j=0;j<8;j++)
        ((bf16*)outv)[base + j] = __float2bfloat16(lrelu(g5*acc[i][j] + b5));
    }
  }
}

// ---------------- host ------------------------------------------------------
extern "C" void kernel_launch(void* const* d_in, const int* in_sizes, int n_in,
                              void* d_out, int out_size, void* d_ws, size_t ws_size,
                              hipStream_t stream) {
  const void* X = d_in[0];
  float* ws = (float*)d_ws;
  int* flagp = (int*)(ws + OFF_FLAG);

  WPack pk;
  static const int wsz[27] = {192,64,64, 4096,64,64, 8192,64,64, 4096,64,64, 4096,64,64,
                              4096,64,64, 4096,64,64, 8192,128,128, 65536,512,512};
  int off = 0;
  for (int i=0;i<27;i++){ pk.p[i] = d_in[i+1]; pk.off[i] = off; off += wsz[i]; }
  pk.off[27] = off;

  k_detect<<<dim3(1), dim3(64), 0, stream>>>(X, flagp);
  k_wcvt<<<dim3((WF_END+255)/256), dim3(256), 0, stream>>>(pk, ws + OFF_WF, flagp);
  k_point<<<dim3(NP/256), dim3(256), 0, stream>>>(X, ws);
  k_knn2<<<dim3(NP/4), dim3(256), 0, stream>>>(ws, (int*)(ws + OFF_IDX2));

  long availf = (long)(ws_size/4) - OFF_PAIR;
  int chunk = 4096;
  if (availf < (long)N_*N_){
    long c = (availf / N_) & ~127L;
    chunk = (int)(c < 128 ? 128 : c);
    if (chunk > 4096) chunk = 4096;
  }
  for (int b=0;b<8;b++){
    for (int n0=0;n0<N_; n0+=chunk){
      int rows = (N_ - n0 < chunk) ? (N_ - n0) : chunk;
      k_pair<<<dim3(32, rows/128), dim3(256), 0, stream>>>(ws, ws + OFF_PAIR, b, n0);
      k_topk_pair<<<dim3(rows/4), dim3(256), 0, stream>>>(ws + OFF_PAIR, (int*)(ws + OFF_IDX1), b, n0);
    }
  }
  k_uv<<<dim3(NP/256), dim3(256), 0, stream>>>(ws);
  k_edge<1><<<dim3(NP/64), dim3(256), 0, stream>>>(ws, (const int*)(ws + OFF_IDX1),
        OFF_U, OFF_V, WF_WDG2, WF_GDG1, WF_BDG1, WF_GDG2, WF_BDG2, OFF_HDG);
  k_w<<<dim3(NP/256), dim3(256), 0, stream>>>(ws);
  k_edge<0><<<dim3(NP/64), dim3(256), 0, stream>>>(ws, (const int*)(ws + OFF_IDX2),
        0, OFF_U, WF_WSN2, WF_GSN1, WF_BSN1, WF_GSN2, WF_BSN2, OFF_H2);
  k_h4<<<dim3(NP/64), dim3(256), 0, stream>>>(ws, ws + OFF_H4);
  k_conv5<<<dim3(NP/128, 4), dim3(256), 0, stream>>>(ws, d_out);
}

// Round 6
// 1172.917 us; speedup vs baseline: 1.3099x; 1.0753x over previous
//
#include <hip/hip_runtime.h>
#include <hip/hip_bf16.h>
#include <stdint.h>

typedef __hip_bfloat16 bf16;

#define N_   4096
#define NP   32768   // B*N
#define KNN  20

// ---- workspace layout (units: float) ----
#define OFF_H2   0L         // 32768*64 ; later reused as hsn output
#define OFF_XYZ  2097152L   // 3 planes of 32768 (SoA)
#define OFF_X    2097152L
#define OFF_Y    2129920L
#define OFF_Z    2162688L
#define OFF_XX   2195456L   // 32768  (|h2|^2)
#define OFF_XXC  2228224L   // 32768  (|x|^2)
#define OFF_IDX1 2260992L   // 32768*20 int
#define OFF_P4   2260992L   // AoS (x,y,z,|x|^2) 32768*4 floats; lives in the
                            // idx1 region: written by k_point, read by k_knn2,
                            // dead before the pair loop writes idx1 over it.
#define OFF_IDX2 2916352L   // 32768*20 int
#define OFF_WF   3571712L   // 104768 fp32 weights
#define OFF_FLAG 3676480L   // dtype flag (int), 64-float slot
#define OFF_PAIR 3676544L   // pair chunk lives here during kNN phase
// post-kNN reuse of the pair region:
#define OFF_U    3676544L   // 32768*64 ; u=(Wa-Wb)h2 ; later w = Wsn1*hdg
#define OFF_V    5773696L   // 32768*64 ; v = Wb*h2
#define OFF_HDG  7870848L   // 32768*64
#define OFF_H4   5773696L   // 128*32768 k-major; overlaps V+HDG (both dead by then)

// ---- fp32 weight bank offsets ----
#define WF_W1 0
#define WF_G1 192
#define WF_B1 256
#define WF_W2 320
#define WF_G2 4416
#define WF_B2 4480
#define WF_WDG1 4544
#define WF_GDG1 12736
#define WF_BDG1 12800
#define WF_WDG2 12864
#define WF_GDG2 16960
#define WF_BDG2 17024
#define WF_WSN1 17088
#define WF_GSN1 21184
#define WF_BSN1 21248
#define WF_WSN2 21312
#define WF_GSN2 25408
#define WF_BSN2 25472
#define WF_W3 25536
#define WF_G3 29632
#define WF_B3 29696
#define WF_W4 29760
#define WF_G4 37952
#define WF_B4 38080
#define WF_W5 38208
#define WF_G5 103744
#define WF_B5 104256
#define WF_END 104768

__device__ __forceinline__ float lrelu(float x){ return x >= 0.f ? x : 0.01f*x; }

// exact-deterministic distance: MUST be the single source for both fill and
// rescan in k_knn2 (bit-identical results required for ordering consistency)
__device__ __forceinline__ float distf(float xn,float yn,float zn,
                                       float xm,float ym,float zm,float cm){
  return fmaf(2.f, fmaf(xn,xm, fmaf(yn,ym, zn*zm)), -cm);
}

// DPP-step max; CTRL must be a compile-time constant -> template parameter.
template<int CTRL>
__device__ __forceinline__ float fmax_dpp(float v){
  int o = __builtin_amdgcn_update_dpp(0, __float_as_int(v), CTRL, 0xF, 0xF, true);
  return fmaxf(v, __int_as_float(o));
}
// Full-wave max returned as a wave-uniform scalar (SGPR broadcast).
// Pure DPP/VALU: xor1/xor2/ror4/ror8 give 16-lane row maxes; ROW_BCAST15
// (0x142) + ROW_BCAST31 (0x143) funnel the global max to lane 63; readlane
// broadcasts it. bound_ctrl=1 corrupts lanes 0-15 after bcast15 (fmax with
// 0.0) but those lanes are never on the dataflow path to lane 63.
__device__ __forceinline__ float wave_max_bcast(float v){
  v = fmax_dpp<0xB1>(v);    // quad_perm xor1
  v = fmax_dpp<0x4E>(v);    // quad_perm xor2
  v = fmax_dpp<0x124>(v);   // row_ror:4
  v = fmax_dpp<0x128>(v);   // row_ror:8  -> row max in all 16 lanes of a row
  v = fmax_dpp<0x142>(v);   // row_bcast15: 15->16..31, 47->48..63
  v = fmax_dpp<0x143>(v);   // row_bcast31: 31->32..63; lane 63 = global max
  return __int_as_float(__builtin_amdgcn_readlane(__float_as_int(v), 63));
}

// branchless insert of (c,m) into per-lane sorted top-2 (k1,i1) >= (k2,i2).
// strict > keeps the earlier (smaller-index) candidate ahead on ties.
__device__ __forceinline__ void ins2(float c, int m, float& k1, int& i1,
                                     float& k2, int& i2){
  bool g1 = c > k1, g2 = c > k2;
  k2 = g2 ? (g1 ? k1 : c) : k2;
  i2 = g2 ? (g1 ? i1 : m) : i2;
  k1 = g1 ? c : k1;
  i1 = g1 ? m : i1;
}

// Exact top-20 by iterative pop. Candidate m in 0..4095.
// MODE 0: owner lane js = m & 63,      ord = m >> 6          (lane-strided fill)
// MODE 1: owner lane js = (m>>2)&63,   ord = ((m>>8)<<2)|(m&3)
// Each lane holds its segment's best-2 unextracted candidates; pop promotes,
// rescan (rare, ~3/query) rebuilds via refetch(mre) which must be
// bit-consistent with fill values. In a rescan, lane scans its segment's
// candidate with ord == lane (both modes satisfy ord(mre(lane)) == lane).
template<int MODE, typename F>
__device__ __forceinline__ void topk_pairs(float k1, int i1, float k2, int i2,
                                           int lane, F&& refetch,
                                           int* __restrict__ outp){
  const float NEGINF = -__builtin_inff();
  uint32_t mlo = 0, mhi = 0;   // exclusion mask over MY segment's ords
  int keep = 0;
  #pragma unroll 1
  for (int tt = 0; tt < KNN; tt++){
    float g = wave_max_bcast(k1);
    uint64_t ball = __ballot(k1 == g);
    int js = __builtin_amdgcn_readfirstlane((int)(__ffsll((unsigned long long)ball) - 1));
    int wid = __builtin_amdgcn_readlane(i1, js);
    // dry check reads OLD k2 of js (== js's k1 after the pop below) so the
    // readlane doesn't serialize behind the cndmask updates.
    int kown = __builtin_amdgcn_readlane(__float_as_int(k2), js);
    if (lane == tt) keep = wid;
    bool own = (lane == js);
    // exclusion bit for wid (ord/bit are wave-uniform scalars)
    uint32_t ord = (MODE == 0) ? ((uint32_t)wid >> 6)
                               : ((((uint32_t)wid >> 8) << 2) | ((uint32_t)wid & 3u));
    uint32_t blo = (ord < 32u) ? (1u << ord) : 0u;
    uint32_t bhi = (ord >= 32u) ? (1u << (ord - 32u)) : 0u;
    mlo |= own ? blo : 0u;
    mhi |= own ? bhi : 0u;
    k1 = own ? k2 : k1;  i1 = own ? i2 : i1;
    k2 = own ? NEGINF : k2;
    // owner dry? (wave-uniform branch, rare)
    if (kown == (int)0xFF800000u){
      uint32_t mre = (MODE == 0)
        ? ((uint32_t)js + ((uint32_t)lane << 6))
        : ((((uint32_t)lane >> 2) << 8) | (((uint32_t)js) << 2) | ((uint32_t)lane & 3u));
      float v = refetch(mre);
      uint32_t bl = (uint32_t)__builtin_amdgcn_readlane((int)mlo, js);
      uint32_t bh = (uint32_t)__builtin_amdgcn_readlane((int)mhi, js);
      uint64_t bm = ((uint64_t)bh << 32) | bl;
      if ((bm >> lane) & 1ull) v = NEGINF;
      float g2 = wave_max_bcast(v);
      uint64_t b2 = __ballot(v == g2);
      int jw = (int)(__ffsll((unsigned long long)b2) - 1);
      uint32_t wm = (MODE == 0)
        ? ((uint32_t)js + ((uint32_t)jw << 6))
        : ((((uint32_t)jw >> 2) << 8) | (((uint32_t)js) << 2) | ((uint32_t)jw & 3u));
      if (lane == js){ k1 = g2; i1 = (int)wm; }
    }
  }
  if (lane < KNN) outp[lane] = keep;
}

// ---------------- K-1: dtype detect (1 = fp32 inputs, 0 = bf16) -------------
__global__ void k_detect(const void* __restrict__ x, int* __restrict__ flag){
  int lane = threadIdx.x;
  const bf16* xb = (const bf16*)x;
  int cnt = 0;
  #pragma unroll 1
  for (int i = lane; i < 256; i += 64){
    float v = __bfloat162float(xb[2*i]);
    float a = fabsf(v);
    if (a > 1e-3f && a < 100.f) cnt++;
  }
  #pragma unroll
  for (int off = 32; off; off >>= 1) cnt += __shfl_down(cnt, off, 64);
  if (lane == 0) *flag = (cnt >= 128) ? 0 : 1;
}

// ---------------- K0: convert all weights -> fp32 bank ----------------------
struct WPack {
  const void* p[27];
  int off[28];
};

__global__ void k_wcvt(WPack pk, float* __restrict__ dst, const int* __restrict__ flagp){
  int i = blockIdx.x*256 + threadIdx.x;
  if (i >= WF_END) return;
  int f = *flagp;
  #pragma unroll 1
  for (int s = 0; s < 27; s++){
    if (i < pk.off[s+1]){
      int j = i - pk.off[s];
      dst[i] = f ? ((const float*)pk.p[s])[j]
                 : __bfloat162float(((const bf16*)pk.p[s])[j]);
      return;
    }
  }
}

// ---------------- K1: per-point MLP1+MLP2, norms, coords (SoA + AoS) --------
__global__ void k_point(const void* __restrict__ x, float* __restrict__ ws){
  const float* wf = ws + OFF_WF;
  int f = ((const int*)(ws + OFF_FLAG))[0];
  int n = blockIdx.x*256 + threadIdx.x;
  float x0, x1, x2;
  if (f){
    const float* xf = (const float*)x;
    x0 = xf[n*3+0]; x1 = xf[n*3+1]; x2 = xf[n*3+2];
  } else {
    const bf16* xb = (const bf16*)x;
    x0 = __bfloat162float(xb[n*3+0]);
    x1 = __bfloat162float(xb[n*3+1]);
    x2 = __bfloat162float(xb[n*3+2]);
  }

  float h1[64];
  #pragma unroll
  for (int o=0;o<64;o++){
    float a = wf[WF_W1+o*3+0]*x0 + wf[WF_W1+o*3+1]*x1 + wf[WF_W1+o*3+2]*x2;
    h1[o] = lrelu(wf[WF_G1+o]*a + wf[WF_B1+o]);
  }
  float xx = 0.f;
  #pragma unroll 1
  for (int o=0;o<64;o++){
    float a = 0.f;
    #pragma unroll
    for (int c=0;c<64;c++) a += wf[WF_W2+o*64+c]*h1[c];
    float h2 = lrelu(wf[WF_G2+o]*a + wf[WF_B2+o]);
    ws[OFF_H2 + (long)n*64 + o] = h2;
    xx += h2*h2;
  }
  ws[OFF_XX + n] = xx;
  float cc = x0*x0 + x1*x1 + x2*x2;
  ws[OFF_X + n] = x0; ws[OFF_Y + n] = x1; ws[OFF_Z + n] = x2;
  ws[OFF_XXC + n] = cc;
  *(float4*)(ws + OFF_P4 + 4L*n) = make_float4(x0, x1, x2, cc);
}

// ---------------- K2a: pair GEMM (fp32), per batch chunk --------------------
__global__ __launch_bounds__(256) void k_pair(const float* __restrict__ ws, float* __restrict__ pair,
                                              int b, int n0){
  __shared__ float As[64*128];
  __shared__ float Bs[64*128];
  int t = threadIdx.x;
  int bx = blockIdx.x, by = blockIdx.y;
  const float* h2 = ws + OFF_H2 + (long)b*N_*64;

  int r = t >> 1, c0 = (t & 1)*32;
  const float4* arow = (const float4*)(h2 + (long)(n0 + by*128 + r)*64 + c0);
  const float4* brow = (const float4*)(h2 + (long)(bx*128 + r)*64 + c0);
  #pragma unroll
  for (int q=0;q<8;q++){
    float4 av = arow[q];
    As[(c0+4*q+0)*128 + r] = av.x; As[(c0+4*q+1)*128 + r] = av.y;
    As[(c0+4*q+2)*128 + r] = av.z; As[(c0+4*q+3)*128 + r] = av.w;
    float4 bv = brow[q];
    Bs[(c0+4*q+0)*128 + r] = bv.x; Bs[(c0+4*q+1)*128 + r] = bv.y;
    Bs[(c0+4*q+2)*128 + r] = bv.z; Bs[(c0+4*q+3)*128 + r] = bv.w;
  }
  __syncthreads();

  int tr = t/16, tc = t%16;
  float acc[8][8] = {};
  #pragma unroll 4
  for (int k=0;k<64;k++){
    const float4* ap = (const float4*)&As[k*128 + tr*8];
    const float4* bp = (const float4*)&Bs[k*128 + tc*8];
    float4 a0 = ap[0], a1 = ap[1], c0v = bp[0], c1v = bp[1];
    float a[8] = {a0.x,a0.y,a0.z,a0.w,a1.x,a1.y,a1.z,a1.w};
    float c[8] = {c0v.x,c0v.y,c0v.z,c0v.w,c1v.x,c1v.y,c1v.z,c1v.w};
    #pragma unroll
    for (int i=0;i<8;i++)
      #pragma unroll
      for (int j=0;j<8;j++) acc[i][j] += a[i]*c[j];
  }
  const float* xxp = ws + OFF_XX + b*N_ + bx*128 + tc*8;
  float xxm[8];
  #pragma unroll
  for (int j=0;j<8;j++) xxm[j] = xxp[j];
  #pragma unroll
  for (int i=0;i<8;i++){
    long row = (long)(by*128 + tr*8 + i)*N_ + bx*128 + tc*8;
    float4 o0 = make_float4(2.f*acc[i][0]-xxm[0], 2.f*acc[i][1]-xxm[1],
                            2.f*acc[i][2]-xxm[2], 2.f*acc[i][3]-xxm[3]);
    float4 o1 = make_float4(2.f*acc[i][4]-xxm[4], 2.f*acc[i][5]-xxm[5],
                            2.f*acc[i][6]-xxm[6], 2.f*acc[i][7]-xxm[7]);
    ((float4*)(pair+row))[0] = o0;
    ((float4*)(pair+row))[1] = o1;
  }
}

// ---------------- K2b: top-20 over stored pair rows (pairs-pop, 4 rows/blk) -
__global__ __launch_bounds__(256) void k_topk_pair(const float* __restrict__ pair, int* __restrict__ idx1,
                                                   int b, int n0){
  int t = threadIdx.x;
  int lane = t & 63, wv = t >> 6;
  int r = blockIdx.x*4 + wv;
  const float* rowp = pair + (long)r*N_;
  const float4* src = (const float4*)rowp;
  float k1 = -__builtin_inff(), k2 = -__builtin_inff();
  int i1 = 0, i2 = 0;
  #pragma unroll
  for (int q=0;q<16;q++){
    float4 v = src[lane + 64*q];
    int m0 = 4*lane + 256*q;
    ins2(v.x, m0,   k1,i1,k2,i2);
    ins2(v.y, m0+1, k1,i1,k2,i2);
    ins2(v.z, m0+2, k1,i1,k2,i2);
    ins2(v.w, m0+3, k1,i1,k2,i2);
  }
  topk_pairs<1>(k1,i1,k2,i2, lane, [&](uint32_t mre){ return rowp[mre]; },
                idx1 + (long)(b*N_ + n0 + r)*KNN);
}

// ---------------- K3: coord-space kNN, LDS chunk-staged (8 queries/blk) -----
// The fill was the floor (r2/r4/r5 all ~200us with different pop machinery):
// each wave streamed the same 64KB P4 window from L2 privately. Now 8 waves
// (8 queries) share double-buffered 512-candidate LDS chunks: global traffic
// /8, next chunk's loads issued before compute (latency hidden), LDS reads
// stride-16B conflict-free. Candidate mapping: seg = m&63 (MODE 0).
__global__ __launch_bounds__(512) void k_knn2(const float* __restrict__ ws, int* __restrict__ idx2){
  __shared__ float4 pbuf[2][512];
  int t = threadIdx.x;
  int lane = t & 63, wv = t >> 6;
  int n = blockIdx.x*8 + wv;
  int base = n & ~4095;
  const float4* P4 = (const float4*)(ws + OFF_P4);
  float4 qp = P4[n];
  float xn = qp.x, yn = qp.y, zn = qp.z;
  float k1 = -__builtin_inff(), k2 = -__builtin_inff();
  int i1 = 0, i2 = 0;

  pbuf[0][t] = P4[base + t];
  __syncthreads();
  #pragma unroll 1
  for (int c = 0; c < 8; c++){
    float4 nx;
    if (c < 7) nx = P4[base + (c+1)*512 + t];   // issue early; hides under compute
    const float4* pb = pbuf[c & 1];
    #pragma unroll
    for (int j = 0; j < 8; j++){
      float4 p = pb[lane + 64*j];
      int m = c*512 + 64*j + lane;              // m & 63 == lane  (MODE-0 segment)
      ins2(distf(xn,yn,zn, p.x,p.y,p.z,p.w), m, k1,i1,k2,i2);
    }
    __syncthreads();
    if (c < 7) pbuf[(c+1) & 1][t] = nx;
    __syncthreads();
  }
  topk_pairs<0>(k1,i1,k2,i2, lane, [&](uint32_t mre){
      float4 p = P4[base + (int)mre];
      return distf(xn,yn,zn, p.x, p.y, p.z, p.w);
    }, idx2 + (long)n*KNN);
}

// ---------------- K3b: u = (Wa-Wb)h2, v = Wb h2 (post-kNN) ------------------
__global__ void k_uv(float* __restrict__ ws){
  const float* wf = ws + OFF_WF;
  int n = blockIdx.x*256 + threadIdx.x;
  float h[64];
  const float4* src = (const float4*)(ws + OFF_H2 + (long)n*64);
  #pragma unroll
  for (int q=0;q<16;q++){ float4 v = src[q]; h[4*q]=v.x; h[4*q+1]=v.y; h[4*q+2]=v.z; h[4*q+3]=v.w; }
  #pragma unroll 1
  for (int o=0;o<64;o++){
    float va=0.f, vb=0.f;
    #pragma unroll
    for (int c=0;c<64;c++){
      va += wf[WF_WDG1+o*128+c]*h[c];
      vb += wf[WF_WDG1+o*128+64+c]*h[c];
    }
    ws[OFF_U + (long)n*64 + o] = va - vb;
    ws[OFF_V + (long)n*64 + o] = vb;
  }
}

// ---------------- K4/K5: edge stage (gathered first conv folded) ------------
// Software-pipelined: idx tile preloaded to LDS (kills dependent idx->gather
// chain); gather for k+1 register-prefetched before the MAC loop so HBM/L2
// latency hides under ~2k cycles of FMA+LDS work; `us` moved to registers
// (LDS 50KB -> 38.4KB -> 4 blocks/CU instead of 3).
template<int USE_U>
__global__ __launch_bounds__(256, 4) void k_edge(float* __restrict__ ws, const int* __restrict__ idxt,
      long uoff, long goff, int w2off,
      int g1off, int b1off, int g2off, int b2off, long outoff){
  __shared__ float y1s[64*65];
  __shared__ float w2s[64*65];
  __shared__ int   idxs[64*KNN];
  const float* wf = ws + OFF_WF;
  int t = threadIdx.x;
  int p0 = blockIdx.x*64;
  int b  = p0 >> 12;
  int lane = t & 63, wv = t >> 6;
  int tr = t & 15, oc = t >> 4;

  #pragma unroll 1
  for (int i=t;i<4096;i+=256){ int o = i>>6, kk = i&63; w2s[o*65+kk] = wf[w2off + i]; }
  #pragma unroll 1
  for (int i=t;i<64*KNN;i+=256) idxs[i] = idxt[(long)p0*KNN + i];

  // per-lane registers replacing LDS us/g1s/b1s/g2s/b2s
  float ur[16];
  if (USE_U){
    #pragma unroll
    for (int jj=0;jj<16;jj++)
      ur[jj] = ws[uoff + (long)(p0 + wv + 4*jj)*64 + lane];
  } else {
    #pragma unroll
    for (int jj=0;jj<16;jj++) ur[jj] = 0.f;
  }
  float g1v = wf[g1off+lane], b1v = wf[b1off+lane];
  float g2r[4], b2r[4];
  #pragma unroll
  for (int j=0;j<4;j++){ g2r[j] = wf[g2off+oc+16*j]; b2r[j] = wf[b2off+oc+16*j]; }

  float mx[4][4];
  #pragma unroll
  for (int i=0;i<4;i++)
    #pragma unroll
    for (int j=0;j<4;j++) mx[i][j] = -3.0e38f;

  __syncthreads();   // idxs + w2s ready

  long gbase = goff + ((long)b << 12)*64;
  float pf[16];
  #pragma unroll
  for (int jj=0;jj<16;jj++){
    int nb = idxs[(wv + 4*jj)*KNN];
    pf[jj] = ws[gbase + (long)nb*64 + lane];
  }

  for (int k=0;k<KNN;k++){
    // write phase: consume prefetched gather for this k
    #pragma unroll
    for (int jj=0;jj<16;jj++){
      int e = wv + 4*jj;
      float val = pf[jj];
      if (USE_U) val += ur[jj];
      y1s[e*65 + lane] = lrelu(g1v*val + b1v);
    }
    __syncthreads();
    // issue next-k gather NOW; latency hides under the MAC loop below
    if (k+1 < KNN){
      #pragma unroll
      for (int jj=0;jj<16;jj++){
        int nb = idxs[(wv + 4*jj)*KNN + k+1];
        pf[jj] = ws[gbase + (long)nb*64 + lane];
      }
    }
    float acc[4][4] = {};
    #pragma unroll 4
    for (int kk=0;kk<64;kk++){
      float a0 = y1s[(tr   )*65+kk], a1 = y1s[(tr+16)*65+kk];
      float a2 = y1s[(tr+32)*65+kk], a3 = y1s[(tr+48)*65+kk];
      float c0 = w2s[(oc   )*65+kk], c1 = w2s[(oc+16)*65+kk];
      float c2 = w2s[(oc+32)*65+kk], c3 = w2s[(oc+48)*65+kk];
      acc[0][0]+=a0*c0; acc[0][1]+=a0*c1; acc[0][2]+=a0*c2; acc[0][3]+=a0*c3;
      acc[1][0]+=a1*c0; acc[1][1]+=a1*c1; acc[1][2]+=a1*c2; acc[1][3]+=a1*c3;
      acc[2][0]+=a2*c0; acc[2][1]+=a2*c1; acc[2][2]+=a2*c2; acc[2][3]+=a2*c3;
      acc[3][0]+=a3*c0; acc[3][1]+=a3*c1; acc[3][2]+=a3*c2; acc[3][3]+=a3*c3;
    }
    #pragma unroll
    for (int i=0;i<4;i++)
      #pragma unroll
      for (int j=0;j<4;j++){
        float yy = lrelu(g2r[j]*acc[i][j] + b2r[j]);
        mx[i][j] = fmaxf(mx[i][j], yy);
      }
    __syncthreads();
  }
  #pragma unroll
  for (int i=0;i<4;i++)
    #pragma unroll
    for (int j=0;j<4;j++)
      ws[outoff + (long)(p0 + tr + 16*i)*64 + oc + 16*j] = mx[i][j];
}

// ---------------- K4b: w = Wsn1 . hdg per point (stored raw) ----------------
__global__ void k_w(float* __restrict__ ws){
  const float* wf = ws + OFF_WF;
  int n = blockIdx.x*256 + threadIdx.x;
  float h[64];
  const float4* src = (const float4*)(ws + OFF_HDG + (long)n*64);
  #pragma unroll
  for (int q=0;q<16;q++){ float4 v = src[q]; h[4*q]=v.x; h[4*q+1]=v.y; h[4*q+2]=v.z; h[4*q+3]=v.w; }
  #pragma unroll 1
  for (int o=0;o<64;o++){
    float a = 0.f;
    #pragma unroll
    for (int c=0;c<64;c++) a += wf[WF_WSN1 + o*64 + c]*h[c];
    ws[OFF_U + (long)n*64 + o] = a;
  }
}

// ---------------- K6a: head conv3+conv4, h4 out in k-major [128][NP] --------
__global__ __launch_bounds__(256) void k_h4(const float* __restrict__ ws, float* __restrict__ h4g){
  __shared__ float Hs[64*65];    // [ch][pt] (hsn), then reused as [o3][pt] (h3)
  __shared__ float wb[64*130];   // W3 as wb[c*65+o]; later W4 as wb[c*130+o]
  const float* wf = ws + OFF_WF;
  int t = threadIdx.x;
  int p0 = blockIdx.x*64;

  {
    int r = t >> 2, c0 = (t & 3)*16;
    const float4* src = (const float4*)(ws + OFF_H2 + (long)(p0 + r)*64 + c0);
    #pragma unroll
    for (int q=0;q<4;q++){
      float4 v = src[q];
      Hs[(c0+4*q+0)*65 + r] = v.x; Hs[(c0+4*q+1)*65 + r] = v.y;
      Hs[(c0+4*q+2)*65 + r] = v.z; Hs[(c0+4*q+3)*65 + r] = v.w;
    }
  }
  {
    int r = t >> 2, c0 = (t & 3)*16;
    const float4* src = (const float4*)(wf + WF_W3 + (long)r*64 + c0);
    #pragma unroll
    for (int q=0;q<4;q++){
      float4 v = src[q];
      wb[(c0+4*q+0)*65 + r] = v.x; wb[(c0+4*q+1)*65 + r] = v.y;
      wb[(c0+4*q+2)*65 + r] = v.z; wb[(c0+4*q+3)*65 + r] = v.w;
    }
  }
  __syncthreads();

  int pr = t & 15, og = t >> 4;
  float acc[4][4] = {};
  #pragma unroll 8
  for (int k=0;k<64;k++){
    float4 a = *(const float4*)&Hs[k*65 + pr*4];
    float4 c = *(const float4*)&wb[k*65 + og*4];
    float av[4] = {a.x,a.y,a.z,a.w}, cv[4] = {c.x,c.y,c.z,c.w};
    #pragma unroll
    for (int i=0;i<4;i++)
      #pragma unroll
      for (int j=0;j<4;j++) acc[i][j] += av[i]*cv[j];
  }
  __syncthreads();

  #pragma unroll
  for (int j=0;j<4;j++){
    int o = og*4 + j;
    float g3 = wf[WF_G3+o], b3 = wf[WF_B3+o];
    #pragma unroll
    for (int i=0;i<4;i++)
      Hs[o*65 + pr*4 + i] = lrelu(g3*acc[i][j] + b3);
  }
  {
    int r = t >> 1, c0 = (t & 1)*32;
    const float4* src = (const float4*)(wf + WF_W4 + (long)r*64 + c0);
    #pragma unroll
    for (int q=0;q<8;q++){
      float4 v = src[q];
      wb[(c0+4*q+0)*130 + r] = v.x; wb[(c0+4*q+1)*130 + r] = v.y;
      wb[(c0+4*q+2)*130 + r] = v.z; wb[(c0+4*q+3)*130 + r] = v.w;
    }
  }
  __syncthreads();

  float a2[4][8] = {};
  #pragma unroll 8
  for (int k=0;k<64;k++){
    float4 a = *(const float4*)&Hs[k*65 + pr*4];
    float4 c0 = *(const float4*)&wb[k*130 + og*8];
    float4 c1 = *(const float4*)&wb[k*130 + og*8 + 4];
    float av[4] = {a.x,a.y,a.z,a.w};
    float cv[8] = {c0.x,c0.y,c0.z,c0.w,c1.x,c1.y,c1.z,c1.w};
    #pragma unroll
    for (int i=0;i<4;i++)
      #pragma unroll
      for (int j=0;j<8;j++) a2[i][j] += av[i]*cv[j];
  }
  #pragma unroll
  for (int j=0;j<8;j++){
    int o = og*8 + j;
    float g4 = wf[WF_G4+o], b4 = wf[WF_B4+o];
    #pragma unroll
    for (int i=0;i<4;i++)
      h4g[(long)o*NP + p0 + pr*4 + i] = lrelu(g4*a2[i][j] + b4);
  }
}

// ---------------- K6b: conv5 GEMM [512 x 128] . [128 x NP] ------------------
#define KC 32
__global__ __launch_bounds__(256) void k_conv5(const float* __restrict__ ws, void* __restrict__ outv){
  __shared__ float As[KC*128];   // [k][o]
  __shared__ float Bs[KC*128];   // [k][pt]
  const float* wf = ws + OFF_WF;
  int f = ((const int*)(ws + OFF_FLAG))[0];
  int t = threadIdx.x;
  int p0 = blockIdx.x*128;
  int o0 = blockIdx.y*128;
  const float* H4 = ws + OFF_H4;
  float acc[8][8] = {};

  for (int kc = 0; kc < 128; kc += KC){
    {
      int r = t >> 1, c0 = (t & 1)*16;
      const float4* src = (const float4*)(wf + WF_W5 + (long)(o0 + r)*128 + kc + c0);
      #pragma unroll
      for (int q=0;q<4;q++){
        float4 v = src[q];
        As[(c0+4*q+0)*128 + r] = v.x; As[(c0+4*q+1)*128 + r] = v.y;
        As[(c0+4*q+2)*128 + r] = v.z; As[(c0+4*q+3)*128 + r] = v.w;
      }
    }
    {
      int kr = t >> 3, pc = (t & 7)*16;
      const float4* src = (const float4*)(H4 + (long)(kc + kr)*NP + p0 + pc);
      float4 v0 = src[0], v1 = src[1], v2 = src[2], v3 = src[3];
      *(float4*)&Bs[kr*128 + pc     ] = v0;
      *(float4*)&Bs[kr*128 + pc + 4 ] = v1;
      *(float4*)&Bs[kr*128 + pc + 8 ] = v2;
      *(float4*)&Bs[kr*128 + pc + 12] = v3;
    }
    __syncthreads();
    int tr = t/16, tc = t%16;
    #pragma unroll 8
    for (int k=0;k<KC;k++){
      const float4* ap = (const float4*)&As[k*128 + tr*8];
      const float4* bp = (const float4*)&Bs[k*128 + tc*8];
      float4 a0 = ap[0], a1 = ap[1], b0 = bp[0], b1 = bp[1];
      float a[8] = {a0.x,a0.y,a0.z,a0.w,a1.x,a1.y,a1.z,a1.w};
      float b[8] = {b0.x,b0.y,b0.z,b0.w,b1.x,b1.y,b1.z,b1.w};
      #pragma unroll
      for (int i=0;i<8;i++)
        #pragma unroll
        for (int j=0;j<8;j++) acc[i][j] += a[i]*b[j];
    }
    __syncthreads();
  }

  int tr = t/16, tc = t%16;
  int b = p0 >> 12, nn = (p0 & 4095) + tc*8;
  #pragma unroll
  for (int i=0;i<8;i++){
    int oo = o0 + tr*8 + i;
    float g5 = wf[WF_G5+oo], b5 = wf[WF_B5+oo];
    long base = ((long)(b*512 + oo) << 12) + nn;
    if (f){
      float4 v0 = make_float4(lrelu(g5*acc[i][0]+b5), lrelu(g5*acc[i][1]+b5),
                              lrelu(g5*acc[i][2]+b5), lrelu(g5*acc[i][3]+b5));
      float4 v1 = make_float4(lrelu(g5*acc[i][4]+b5), lrelu(g5*acc[i][5]+b5),
                              lrelu(g5*acc[i][6]+b5), lrelu(g5*acc[i][7]+b5));
      *(float4*)((float*)outv + base)     = v0;
      *(float4*)((float*)outv + base + 4) = v1;
    } else {
      #pragma unroll
      for (int j=0;j<8;j++)
        ((bf16*)outv)[base + j] = __float2bfloat16(lrelu(g5*acc[i][j] + b5));
    }
  }
}

// ---------------- host ------------------------------------------------------
extern "C" void kernel_launch(void* const* d_in, const int* in_sizes, int n_in,
                              void* d_out, int out_size, void* d_ws, size_t ws_size,
                              hipStream_t stream) {
  const void* X = d_in[0];
  float* ws = (float*)d_ws;
  int* flagp = (int*)(ws + OFF_FLAG);

  WPack pk;
  static const int wsz[27] = {192,64,64, 4096,64,64, 8192,64,64, 4096,64,64, 4096,64,64,
                              4096,64,64, 4096,64,64, 8192,128,128, 65536,512,512};
  int off = 0;
  for (int i=0;i<27;i++){ pk.p[i] = d_in[i+1]; pk.off[i] = off; off += wsz[i]; }
  pk.off[27] = off;

  k_detect<<<dim3(1), dim3(64), 0, stream>>>(X, flagp);
  k_wcvt<<<dim3((WF_END+255)/256), dim3(256), 0, stream>>>(pk, ws + OFF_WF, flagp);
  k_point<<<dim3(NP/256), dim3(256), 0, stream>>>(X, ws);
  k_knn2<<<dim3(NP/8), dim3(512), 0, stream>>>(ws, (int*)(ws + OFF_IDX2));

  long availf = (long)(ws_size/4) - OFF_PAIR;
  int chunk = 4096;
  if (availf < (long)N_*N_){
    long c = (availf / N_) & ~127L;
    chunk = (int)(c < 128 ? 128 : c);
    if (chunk > 4096) chunk = 4096;
  }
  for (int b=0;b<8;b++){
    for (int n0=0;n0<N_; n0+=chunk){
      int rows = (N_ - n0 < chunk) ? (N_ - n0) : chunk;
      k_pair<<<dim3(32, rows/128), dim3(256), 0, stream>>>(ws, ws + OFF_PAIR, b, n0);
      k_topk_pair<<<dim3(rows/4), dim3(256), 0, stream>>>(ws + OFF_PAIR, (int*)(ws + OFF_IDX1), b, n0);
    }
  }
  k_uv<<<dim3(NP/256), dim3(256), 0, stream>>>(ws);
  k_edge<1><<<dim3(NP/64), dim3(256), 0, stream>>>(ws, (const int*)(ws + OFF_IDX1),
        OFF_U, OFF_V, WF_WDG2, WF_GDG1, WF_BDG1, WF_GDG2, WF_BDG2, OFF_HDG);
  k_w<<<dim3(NP/256), dim3(256), 0, stream>>>(ws);
  k_edge<0><<<dim3(NP/64), dim3(256), 0, stream>>>(ws, (const int*)(ws + OFF_IDX2),
        0, OFF_U, WF_WSN2, WF_GSN1, WF_BSN1, WF_GSN2, WF_BSN2, OFF_H2);
  k_h4<<<dim3(NP/64), dim3(256), 0, stream>>>(ws, ws + OFF_H4);
  k_conv5<<<dim3(NP/128, 4), dim3(256), 0, stream>>>(ws, d_out);
}

// Round 7
// 1156.017 us; speedup vs baseline: 1.3291x; 1.0146x over previous
//
#include <hip/hip_runtime.h>
#include <hip/hip_bf16.h>
#include <stdint.h>

typedef __hip_bfloat16 bf16;

#define N_   4096
#define NP   32768   // B*N
#define KNN  20

// ---- workspace layout (units: float) ----
#define OFF_H2   0L         // 32768*64 ; later reused as hsn output
#define OFF_XYZ  2097152L   // 3 planes of 32768 (SoA)
#define OFF_X    2097152L
#define OFF_Y    2129920L
#define OFF_Z    2162688L
#define OFF_XX   2195456L   // 32768  (|h2|^2)
#define OFF_XXC  2228224L   // 32768  (|x|^2)
#define OFF_IDX1 2260992L   // 32768*20 int
#define OFF_P4   2260992L   // AoS (x,y,z,|x|^2) 32768*4 floats; lives in the
                            // idx1 region: written by k_point, read by k_knn2,
                            // dead before the pair loop writes idx1 over it.
#define OFF_IDX2 2916352L   // 32768*20 int
#define OFF_WF   3571712L   // 104768 fp32 weights
#define OFF_FLAG 3676480L   // dtype flag (int), 64-float slot
#define OFF_PAIR 3676544L   // pair chunk lives here during kNN phase
// post-kNN reuse of the pair region:
#define OFF_U    3676544L   // 32768*64 ; u=(Wa-Wb)h2 ; later w = Wsn1*hdg
#define OFF_V    5773696L   // 32768*64 ; v = Wb*h2
#define OFF_HDG  7870848L   // 32768*64
#define OFF_H4   5773696L   // 128*32768 k-major; overlaps V+HDG (both dead by then)

// ---- fp32 weight bank offsets ----
#define WF_W1 0
#define WF_G1 192
#define WF_B1 256
#define WF_W2 320
#define WF_G2 4416
#define WF_B2 4480
#define WF_WDG1 4544
#define WF_GDG1 12736
#define WF_BDG1 12800
#define WF_WDG2 12864
#define WF_GDG2 16960
#define WF_BDG2 17024
#define WF_WSN1 17088
#define WF_GSN1 21184
#define WF_BSN1 21248
#define WF_WSN2 21312
#define WF_GSN2 25408
#define WF_BSN2 25472
#define WF_W3 25536
#define WF_G3 29632
#define WF_B3 29696
#define WF_W4 29760
#define WF_G4 37952
#define WF_B4 38080
#define WF_W5 38208
#define WF_G5 103744
#define WF_B5 104256
#define WF_END 104768

__device__ __forceinline__ float lrelu(float x){ return x >= 0.f ? x : 0.01f*x; }

// exact-deterministic distance: MUST be the single source for both fill and
// rescan in k_knn2 (bit-identical results required for ordering consistency)
__device__ __forceinline__ float distf(float xn,float yn,float zn,
                                       float xm,float ym,float zm,float cm){
  return fmaf(2.f, fmaf(xn,xm, fmaf(yn,ym, zn*zm)), -cm);
}

// DPP-step max; CTRL must be a compile-time constant -> template parameter.
template<int CTRL>
__device__ __forceinline__ float fmax_dpp(float v){
  int o = __builtin_amdgcn_update_dpp(0, __float_as_int(v), CTRL, 0xF, 0xF, true);
  return fmaxf(v, __int_as_float(o));
}
// Full-wave max returned as a wave-uniform scalar (SGPR broadcast).
// Pure DPP/VALU: xor1/xor2/ror4/ror8 give 16-lane row maxes; ROW_BCAST15
// (0x142) + ROW_BCAST31 (0x143) funnel the global max to lane 63; readlane
// broadcasts it. bound_ctrl=1 corrupts lanes 0-15 after bcast15 (fmax with
// 0.0) but those lanes are never on the dataflow path to lane 63.
__device__ __forceinline__ float wave_max_bcast(float v){
  v = fmax_dpp<0xB1>(v);    // quad_perm xor1
  v = fmax_dpp<0x4E>(v);    // quad_perm xor2
  v = fmax_dpp<0x124>(v);   // row_ror:4
  v = fmax_dpp<0x128>(v);   // row_ror:8  -> row max in all 16 lanes of a row
  v = fmax_dpp<0x142>(v);   // row_bcast15: 15->16..31, 47->48..63
  v = fmax_dpp<0x143>(v);   // row_bcast31: 31->32..63; lane 63 = global max
  return __int_as_float(__builtin_amdgcn_readlane(__float_as_int(v), 63));
}

// branchless insert of (c,m) into per-lane sorted top-2 (k1,i1) >= (k2,i2).
// strict > keeps the earlier (smaller-index) candidate ahead on ties.
__device__ __forceinline__ void ins2(float c, int m, float& k1, int& i1,
                                     float& k2, int& i2){
  bool g1 = c > k1, g2 = c > k2;
  k2 = g2 ? (g1 ? k1 : c) : k2;
  i2 = g2 ? (g1 ? i1 : m) : i2;
  k1 = g1 ? c : k1;
  i1 = g1 ? m : i1;
}

// Exact top-20 by iterative pop. Candidate m in 0..4095.
// MODE 0: owner lane js = m & 63,      ord = m >> 6          (lane-strided fill)
// MODE 1: owner lane js = (m>>2)&63,   ord = ((m>>8)<<2)|(m&3)
// Each lane holds its segment's best-2 unextracted candidates; pop promotes,
// rescan (rare, ~3/query) rebuilds via refetch(mre) which must be
// bit-consistent with fill values. In a rescan, lane scans its segment's
// candidate with ord == lane (both modes satisfy ord(mre(lane)) == lane).
template<int MODE, typename F>
__device__ __forceinline__ void topk_pairs(float k1, int i1, float k2, int i2,
                                           int lane, F&& refetch,
                                           int* __restrict__ outp){
  const float NEGINF = -__builtin_inff();
  uint32_t mlo = 0, mhi = 0;   // exclusion mask over MY segment's ords
  int keep = 0;
  #pragma unroll 1
  for (int tt = 0; tt < KNN; tt++){
    float g = wave_max_bcast(k1);
    uint64_t ball = __ballot(k1 == g);
    int js = __builtin_amdgcn_readfirstlane((int)(__ffsll((unsigned long long)ball) - 1));
    int wid = __builtin_amdgcn_readlane(i1, js);
    // dry check reads OLD k2 of js (== js's k1 after the pop below) so the
    // readlane doesn't serialize behind the cndmask updates.
    int kown = __builtin_amdgcn_readlane(__float_as_int(k2), js);
    if (lane == tt) keep = wid;
    bool own = (lane == js);
    // exclusion bit for wid (ord/bit are wave-uniform scalars)
    uint32_t ord = (MODE == 0) ? ((uint32_t)wid >> 6)
                               : ((((uint32_t)wid >> 8) << 2) | ((uint32_t)wid & 3u));
    uint32_t blo = (ord < 32u) ? (1u << ord) : 0u;
    uint32_t bhi = (ord >= 32u) ? (1u << (ord - 32u)) : 0u;
    mlo |= own ? blo : 0u;
    mhi |= own ? bhi : 0u;
    k1 = own ? k2 : k1;  i1 = own ? i2 : i1;
    k2 = own ? NEGINF : k2;
    // owner dry? (wave-uniform branch, rare)
    if (kown == (int)0xFF800000u){
      uint32_t mre = (MODE == 0)
        ? ((uint32_t)js + ((uint32_t)lane << 6))
        : ((((uint32_t)lane >> 2) << 8) | (((uint32_t)js) << 2) | ((uint32_t)lane & 3u));
      float v = refetch(mre);
      uint32_t bl = (uint32_t)__builtin_amdgcn_readlane((int)mlo, js);
      uint32_t bh = (uint32_t)__builtin_amdgcn_readlane((int)mhi, js);
      uint64_t bm = ((uint64_t)bh << 32) | bl;
      if ((bm >> lane) & 1ull) v = NEGINF;
      float g2 = wave_max_bcast(v);
      uint64_t b2 = __ballot(v == g2);
      int jw = (int)(__ffsll((unsigned long long)b2) - 1);
      uint32_t wm = (MODE == 0)
        ? ((uint32_t)js + ((uint32_t)jw << 6))
        : ((((uint32_t)jw >> 2) << 8) | (((uint32_t)js) << 2) | ((uint32_t)jw & 3u));
      if (lane == js){ k1 = g2; i1 = (int)wm; }
    }
  }
  if (lane < KNN) outp[lane] = keep;
}

// ---------------- K-1: dtype detect (1 = fp32 inputs, 0 = bf16) -------------
__global__ void k_detect(const void* __restrict__ x, int* __restrict__ flag){
  int lane = threadIdx.x;
  const bf16* xb = (const bf16*)x;
  int cnt = 0;
  #pragma unroll 1
  for (int i = lane; i < 256; i += 64){
    float v = __bfloat162float(xb[2*i]);
    float a = fabsf(v);
    if (a > 1e-3f && a < 100.f) cnt++;
  }
  #pragma unroll
  for (int off = 32; off; off >>= 1) cnt += __shfl_down(cnt, off, 64);
  if (lane == 0) *flag = (cnt >= 128) ? 0 : 1;
}

// ---------------- K0: convert all weights -> fp32 bank ----------------------
struct WPack {
  const void* p[27];
  int off[28];
};

__global__ void k_wcvt(WPack pk, float* __restrict__ dst, const int* __restrict__ flagp){
  int i = blockIdx.x*256 + threadIdx.x;
  if (i >= WF_END) return;
  int f = *flagp;
  #pragma unroll 1
  for (int s = 0; s < 27; s++){
    if (i < pk.off[s+1]){
      int j = i - pk.off[s];
      dst[i] = f ? ((const float*)pk.p[s])[j]
                 : __bfloat162float(((const bf16*)pk.p[s])[j]);
      return;
    }
  }
}

// ---------------- K1: per-point MLP1+MLP2, norms, coords (SoA + AoS) --------
__global__ void k_point(const void* __restrict__ x, float* __restrict__ ws){
  const float* wf = ws + OFF_WF;
  int f = ((const int*)(ws + OFF_FLAG))[0];
  int n = blockIdx.x*256 + threadIdx.x;
  float x0, x1, x2;
  if (f){
    const float* xf = (const float*)x;
    x0 = xf[n*3+0]; x1 = xf[n*3+1]; x2 = xf[n*3+2];
  } else {
    const bf16* xb = (const bf16*)x;
    x0 = __bfloat162float(xb[n*3+0]);
    x1 = __bfloat162float(xb[n*3+1]);
    x2 = __bfloat162float(xb[n*3+2]);
  }

  float h1[64];
  #pragma unroll
  for (int o=0;o<64;o++){
    float a = wf[WF_W1+o*3+0]*x0 + wf[WF_W1+o*3+1]*x1 + wf[WF_W1+o*3+2]*x2;
    h1[o] = lrelu(wf[WF_G1+o]*a + wf[WF_B1+o]);
  }
  float xx = 0.f;
  #pragma unroll 1
  for (int o=0;o<64;o++){
    float a = 0.f;
    #pragma unroll
    for (int c=0;c<64;c++) a += wf[WF_W2+o*64+c]*h1[c];
    float h2 = lrelu(wf[WF_G2+o]*a + wf[WF_B2+o]);
    ws[OFF_H2 + (long)n*64 + o] = h2;
    xx += h2*h2;
  }
  ws[OFF_XX + n] = xx;
  float cc = x0*x0 + x1*x1 + x2*x2;
  ws[OFF_X + n] = x0; ws[OFF_Y + n] = x1; ws[OFF_Z + n] = x2;
  ws[OFF_XXC + n] = cc;
  *(float4*)(ws + OFF_P4 + 4L*n) = make_float4(x0, x1, x2, cc);
}

// ---------------- K2a: pair GEMM (fp32), per batch chunk --------------------
__global__ __launch_bounds__(256) void k_pair(const float* __restrict__ ws, float* __restrict__ pair,
                                              int b, int n0){
  __shared__ float As[64*128];
  __shared__ float Bs[64*128];
  int t = threadIdx.x;
  int bx = blockIdx.x, by = blockIdx.y;
  const float* h2 = ws + OFF_H2 + (long)b*N_*64;

  int r = t >> 1, c0 = (t & 1)*32;
  const float4* arow = (const float4*)(h2 + (long)(n0 + by*128 + r)*64 + c0);
  const float4* brow = (const float4*)(h2 + (long)(bx*128 + r)*64 + c0);
  #pragma unroll
  for (int q=0;q<8;q++){
    float4 av = arow[q];
    As[(c0+4*q+0)*128 + r] = av.x; As[(c0+4*q+1)*128 + r] = av.y;
    As[(c0+4*q+2)*128 + r] = av.z; As[(c0+4*q+3)*128 + r] = av.w;
    float4 bv = brow[q];
    Bs[(c0+4*q+0)*128 + r] = bv.x; Bs[(c0+4*q+1)*128 + r] = bv.y;
    Bs[(c0+4*q+2)*128 + r] = bv.z; Bs[(c0+4*q+3)*128 + r] = bv.w;
  }
  __syncthreads();

  int tr = t/16, tc = t%16;
  float acc[8][8] = {};
  #pragma unroll 4
  for (int k=0;k<64;k++){
    const float4* ap = (const float4*)&As[k*128 + tr*8];
    const float4* bp = (const float4*)&Bs[k*128 + tc*8];
    float4 a0 = ap[0], a1 = ap[1], c0v = bp[0], c1v = bp[1];
    float a[8] = {a0.x,a0.y,a0.z,a0.w,a1.x,a1.y,a1.z,a1.w};
    float c[8] = {c0v.x,c0v.y,c0v.z,c0v.w,c1v.x,c1v.y,c1v.z,c1v.w};
    #pragma unroll
    for (int i=0;i<8;i++)
      #pragma unroll
      for (int j=0;j<8;j++) acc[i][j] += a[i]*c[j];
  }
  const float* xxp = ws + OFF_XX + b*N_ + bx*128 + tc*8;
  float xxm[8];
  #pragma unroll
  for (int j=0;j<8;j++) xxm[j] = xxp[j];
  #pragma unroll
  for (int i=0;i<8;i++){
    long row = (long)(by*128 + tr*8 + i)*N_ + bx*128 + tc*8;
    float4 o0 = make_float4(2.f*acc[i][0]-xxm[0], 2.f*acc[i][1]-xxm[1],
                            2.f*acc[i][2]-xxm[2], 2.f*acc[i][3]-xxm[3]);
    float4 o1 = make_float4(2.f*acc[i][4]-xxm[4], 2.f*acc[i][5]-xxm[5],
                            2.f*acc[i][6]-xxm[6], 2.f*acc[i][7]-xxm[7]);
    ((float4*)(pair+row))[0] = o0;
    ((float4*)(pair+row))[1] = o1;
  }
}

// ---------------- K2b: top-20 over stored pair rows (pairs-pop, 4 rows/blk) -
__global__ __launch_bounds__(256) void k_topk_pair(const float* __restrict__ pair, int* __restrict__ idx1,
                                                   int b, int n0){
  int t = threadIdx.x;
  int lane = t & 63, wv = t >> 6;
  int r = blockIdx.x*4 + wv;
  const float* rowp = pair + (long)r*N_;
  const float4* src = (const float4*)rowp;
  float k1 = -__builtin_inff(), k2 = -__builtin_inff();
  int i1 = 0, i2 = 0;
  #pragma unroll
  for (int q=0;q<16;q++){
    float4 v = src[lane + 64*q];
    int m0 = 4*lane + 256*q;
    ins2(v.x, m0,   k1,i1,k2,i2);
    ins2(v.y, m0+1, k1,i1,k2,i2);
    ins2(v.z, m0+2, k1,i1,k2,i2);
    ins2(v.w, m0+3, k1,i1,k2,i2);
  }
  topk_pairs<1>(k1,i1,k2,i2, lane, [&](uint32_t mre){ return rowp[mre]; },
                idx1 + (long)(b*N_ + n0 + r)*KNN);
}

// ---------------- K3: coord-space kNN, LDS chunk-staged (8 queries/blk) -----
__global__ __launch_bounds__(512) void k_knn2(const float* __restrict__ ws, int* __restrict__ idx2){
  __shared__ float4 pbuf[2][512];
  int t = threadIdx.x;
  int lane = t & 63, wv = t >> 6;
  int n = blockIdx.x*8 + wv;
  int base = n & ~4095;
  const float4* P4 = (const float4*)(ws + OFF_P4);
  float4 qp = P4[n];
  float xn = qp.x, yn = qp.y, zn = qp.z;
  float k1 = -__builtin_inff(), k2 = -__builtin_inff();
  int i1 = 0, i2 = 0;

  pbuf[0][t] = P4[base + t];
  __syncthreads();
  #pragma unroll 1
  for (int c = 0; c < 8; c++){
    float4 nx;
    if (c < 7) nx = P4[base + (c+1)*512 + t];   // issue early; hides under compute
    const float4* pb = pbuf[c & 1];
    #pragma unroll
    for (int j = 0; j < 8; j++){
      float4 p = pb[lane + 64*j];
      int m = c*512 + 64*j + lane;              // m & 63 == lane  (MODE-0 segment)
      ins2(distf(xn,yn,zn, p.x,p.y,p.z,p.w), m, k1,i1,k2,i2);
    }
    __syncthreads();
    if (c < 7) pbuf[(c+1) & 1][t] = nx;
    __syncthreads();
  }
  topk_pairs<0>(k1,i1,k2,i2, lane, [&](uint32_t mre){
      float4 p = P4[base + (int)mre];
      return distf(xn,yn,zn, p.x, p.y, p.z, p.w);
    }, idx2 + (long)n*KNN);
}

// ---------------- K3b: u = (Wa-Wb)h2, v = Wb h2 (post-kNN) ------------------
__global__ void k_uv(float* __restrict__ ws){
  const float* wf = ws + OFF_WF;
  int n = blockIdx.x*256 + threadIdx.x;
  float h[64];
  const float4* src = (const float4*)(ws + OFF_H2 + (long)n*64);
  #pragma unroll
  for (int q=0;q<16;q++){ float4 v = src[q]; h[4*q]=v.x; h[4*q+1]=v.y; h[4*q+2]=v.z; h[4*q+3]=v.w; }
  #pragma unroll 1
  for (int o=0;o<64;o++){
    float va=0.f, vb=0.f;
    #pragma unroll
    for (int c=0;c<64;c++){
      va += wf[WF_WDG1+o*128+c]*h[c];
      vb += wf[WF_WDG1+o*128+64+c]*h[c];
    }
    ws[OFF_U + (long)n*64 + o] = va - vb;
    ws[OFF_V + (long)n*64 + o] = vb;
  }
}

// ---------------- K4/K5: edge stage (gathered first conv folded) ------------
// r6: 512-thread blocks (8 waves -> 16 waves/CU, was grid-limited 8/CU at 20%
// occupancy) + transposed LDS with vector reads (1 b64 + 1 b128 per kk instead
// of 8 b32). Per-thread tile 2 edges x 4 outs. Software pipeline kept: idx in
// LDS, k+1 gather register-prefetched under the MAC loop.
template<int USE_U>
__global__ __launch_bounds__(512) void k_edge(float* __restrict__ ws, const int* __restrict__ idxt,
      long uoff, long goff, int w2off,
      int g1off, int b1off, int g2off, int b2off, long outoff){
  __shared__ float y1t[64*66];   // [channel][edge], row 66 (b64-aligned, 2-way reads)
  __shared__ float w2t[64*68];   // [channel][out],  row 68 (b128-aligned, 2-way reads)
  __shared__ int   idxs[64*KNN];
  const float* wf = ws + OFF_WF;
  int t = threadIdx.x;
  int p0 = blockIdx.x*64;
  int b  = p0 >> 12;
  int lane = t & 63, wv = t >> 6;        // write phase: channel=lane, 8 edges/wave
  int tr = t & 31, oc = t >> 5;          // MAC: edges 2tr..2tr+1, outs 4oc..4oc+3

  #pragma unroll 1
  for (int i=t;i<4096;i+=512){ int o = i>>6, kk = i&63; w2t[kk*68+o] = wf[w2off + i]; }
  #pragma unroll 1
  for (int i=t;i<64*KNN;i+=512) idxs[i] = idxt[(long)p0*KNN + i];

  // per-lane registers: u for my 8 edges (channel=lane), g1/b1, g2/b2
  float ur[8];
  if (USE_U){
    #pragma unroll
    for (int jj=0;jj<8;jj++)
      ur[jj] = ws[uoff + (long)(p0 + wv*8 + jj)*64 + lane];
  } else {
    #pragma unroll
    for (int jj=0;jj<8;jj++) ur[jj] = 0.f;
  }
  float g1v = wf[g1off+lane], b1v = wf[b1off+lane];
  float g2r[4], b2r[4];
  #pragma unroll
  for (int j=0;j<4;j++){ g2r[j] = wf[g2off+oc*4+j]; b2r[j] = wf[b2off+oc*4+j]; }

  float mx[2][4];
  #pragma unroll
  for (int i=0;i<2;i++)
    #pragma unroll
    for (int j=0;j<4;j++) mx[i][j] = -3.0e38f;

  __syncthreads();   // idxs + w2t ready

  long gbase = goff + ((long)b << 12)*64;
  float pf[8];
  #pragma unroll
  for (int jj=0;jj<8;jj++){
    int nb = idxs[(wv*8 + jj)*KNN];
    pf[jj] = ws[gbase + (long)nb*64 + lane];
  }

  for (int k=0;k<KNN;k++){
    // write phase: consume prefetched gather for this k
    #pragma unroll
    for (int jj=0;jj<8;jj++){
      int e = wv*8 + jj;
      float val = pf[jj];
      if (USE_U) val += ur[jj];
      y1t[lane*66 + e] = lrelu(g1v*val + b1v);
    }
    __syncthreads();
    // issue next-k gather NOW; latency hides under the MAC loop below
    if (k+1 < KNN){
      #pragma unroll
      for (int jj=0;jj<8;jj++){
        int nb = idxs[(wv*8 + jj)*KNN + k+1];
        pf[jj] = ws[gbase + (long)nb*64 + lane];
      }
    }
    float acc[2][4] = {};
    #pragma unroll 4
    for (int kk=0;kk<64;kk++){
      float2 a = *(const float2*)&y1t[kk*66 + tr*2];
      float4 c = *(const float4*)&w2t[kk*68 + oc*4];
      float av[2] = {a.x, a.y};
      float cv[4] = {c.x, c.y, c.z, c.w};
      #pragma unroll
      for (int i=0;i<2;i++)
        #pragma unroll
        for (int j=0;j<4;j++) acc[i][j] += av[i]*cv[j];
    }
    #pragma unroll
    for (int i=0;i<2;i++)
      #pragma unroll
      for (int j=0;j<4;j++){
        float yy = lrelu(g2r[j]*acc[i][j] + b2r[j]);
        mx[i][j] = fmaxf(mx[i][j], yy);
      }
    __syncthreads();
  }
  #pragma unroll
  for (int i=0;i<2;i++)
    #pragma unroll
    for (int j=0;j<4;j++)
      ws[outoff + (long)(p0 + tr*2 + i)*64 + oc*4 + j] = mx[i][j];
}

// ---------------- K4b: w = Wsn1 . hdg per point (stored raw) ----------------
__global__ void k_w(float* __restrict__ ws){
  const float* wf = ws + OFF_WF;
  int n = blockIdx.x*256 + threadIdx.x;
  float h[64];
  const float4* src = (const float4*)(ws + OFF_HDG + (long)n*64);
  #pragma unroll
  for (int q=0;q<16;q++){ float4 v = src[q]; h[4*q]=v.x; h[4*q+1]=v.y; h[4*q+2]=v.z; h[4*q+3]=v.w; }
  #pragma unroll 1
  for (int o=0;o<64;o++){
    float a = 0.f;
    #pragma unroll
    for (int c=0;c<64;c++) a += wf[WF_WSN1 + o*64 + c]*h[c];
    ws[OFF_U + (long)n*64 + o] = a;
  }
}

// ---------------- K6a: head conv3+conv4, h4 out in k-major [128][NP] --------
__global__ __launch_bounds__(256) void k_h4(const float* __restrict__ ws, float* __restrict__ h4g){
  __shared__ float Hs[64*65];    // [ch][pt] (hsn), then reused as [o3][pt] (h3)
  __shared__ float wb[64*130];   // W3 as wb[c*65+o]; later W4 as wb[c*130+o]
  const float* wf = ws + OFF_WF;
  int t = threadIdx.x;
  int p0 = blockIdx.x*64;

  {
    int r = t >> 2, c0 = (t & 3)*16;
    const float4* src = (const float4*)(ws + OFF_H2 + (long)(p0 + r)*64 + c0);
    #pragma unroll
    for (int q=0;q<4;q++){
      float4 v = src[q];
      Hs[(c0+4*q+0)*65 + r] = v.x; Hs[(c0+4*q+1)*65 + r] = v.y;
      Hs[(c0+4*q+2)*65 + r] = v.z; Hs[(c0+4*q+3)*65 + r] = v.w;
    }
  }
  {
    int r = t >> 2, c0 = (t & 3)*16;
    const float4* src = (const float4*)(wf + WF_W3 + (long)r*64 + c0);
    #pragma unroll
    for (int q=0;q<4;q++){
      float4 v = src[q];
      wb[(c0+4*q+0)*65 + r] = v.x; wb[(c0+4*q+1)*65 + r] = v.y;
      wb[(c0+4*q+2)*65 + r] = v.z; wb[(c0+4*q+3)*65 + r] = v.w;
    }
  }
  __syncthreads();

  int pr = t & 15, og = t >> 4;
  float acc[4][4] = {};
  #pragma unroll 8
  for (int k=0;k<64;k++){
    float4 a = *(const float4*)&Hs[k*65 + pr*4];
    float4 c = *(const float4*)&wb[k*65 + og*4];
    float av[4] = {a.x,a.y,a.z,a.w}, cv[4] = {c.x,c.y,c.z,c.w};
    #pragma unroll
    for (int i=0;i<4;i++)
      #pragma unroll
      for (int j=0;j<4;j++) acc[i][j] += av[i]*cv[j];
  }
  __syncthreads();

  #pragma unroll
  for (int j=0;j<4;j++){
    int o = og*4 + j;
    float g3 = wf[WF_G3+o], b3 = wf[WF_B3+o];
    #pragma unroll
    for (int i=0;i<4;i++)
      Hs[o*65 + pr*4 + i] = lrelu(g3*acc[i][j] + b3);
  }
  {
    int r = t >> 1, c0 = (t & 1)*32;
    const float4* src = (const float4*)(wf + WF_W4 + (long)r*64 + c0);
    #pragma unroll
    for (int q=0;q<8;q++){
      float4 v = src[q];
      wb[(c0+4*q+0)*130 + r] = v.x; wb[(c0+4*q+1)*130 + r] = v.y;
      wb[(c0+4*q+2)*130 + r] = v.z; wb[(c0+4*q+3)*130 + r] = v.w;
    }
  }
  __syncthreads();

  float a2[4][8] = {};
  #pragma unroll 8
  for (int k=0;k<64;k++){
    float4 a = *(const float4*)&Hs[k*65 + pr*4];
    float4 c0 = *(const float4*)&wb[k*130 + og*8];
    float4 c1 = *(const float4*)&wb[k*130 + og*8 + 4];
    float av[4] = {a.x,a.y,a.z,a.w};
    float cv[8] = {c0.x,c0.y,c0.z,c0.w,c1.x,c1.y,c1.z,c1.w};
    #pragma unroll
    for (int i=0;i<4;i++)
      #pragma unroll
      for (int j=0;j<8;j++) a2[i][j] += av[i]*cv[j];
  }
  #pragma unroll
  for (int j=0;j<8;j++){
    int o = og*8 + j;
    float g4 = wf[WF_G4+o], b4 = wf[WF_B4+o];
    #pragma unroll
    for (int i=0;i<4;i++)
      h4g[(long)o*NP + p0 + pr*4 + i] = lrelu(g4*a2[i][j] + b4);
  }
}

// ---------------- K6b: conv5 GEMM [512 x 128] . [128 x NP] ------------------
#define KC 32
__global__ __launch_bounds__(256) void k_conv5(const float* __restrict__ ws, void* __restrict__ outv){
  __shared__ float As[KC*128];   // [k][o]
  __shared__ float Bs[KC*128];   // [k][pt]
  const float* wf = ws + OFF_WF;
  int f = ((const int*)(ws + OFF_FLAG))[0];
  int t = threadIdx.x;
  int p0 = blockIdx.x*128;
  int o0 = blockIdx.y*128;
  const float* H4 = ws + OFF_H4;
  float acc[8][8] = {};

  for (int kc = 0; kc < 128; kc += KC){
    {
      int r = t >> 1, c0 = (t & 1)*16;
      const float4* src = (const float4*)(wf + WF_W5 + (long)(o0 + r)*128 + kc + c0);
      #pragma unroll
      for (int q=0;q<4;q++){
        float4 v = src[q];
        As[(c0+4*q+0)*128 + r] = v.x; As[(c0+4*q+1)*128 + r] = v.y;
        As[(c0+4*q+2)*128 + r] = v.z; As[(c0+4*q+3)*128 + r] = v.w;
      }
    }
    {
      int kr = t >> 3, pc = (t & 7)*16;
      const float4* src = (const float4*)(H4 + (long)(kc + kr)*NP + p0 + pc);
      float4 v0 = src[0], v1 = src[1], v2 = src[2], v3 = src[3];
      *(float4*)&Bs[kr*128 + pc     ] = v0;
      *(float4*)&Bs[kr*128 + pc + 4 ] = v1;
      *(float4*)&Bs[kr*128 + pc + 8 ] = v2;
      *(float4*)&Bs[kr*128 + pc + 12] = v3;
    }
    __syncthreads();
    int tr = t/16, tc = t%16;
    #pragma unroll 8
    for (int k=0;k<KC;k++){
      const float4* ap = (const float4*)&As[k*128 + tr*8];
      const float4* bp = (const float4*)&Bs[k*128 + tc*8];
      float4 a0 = ap[0], a1 = ap[1], b0 = bp[0], b1 = bp[1];
      float a[8] = {a0.x,a0.y,a0.z,a0.w,a1.x,a1.y,a1.z,a1.w};
      float b[8] = {b0.x,b0.y,b0.z,b0.w,b1.x,b1.y,b1.z,b1.w};
      #pragma unroll
      for (int i=0;i<8;i++)
        #pragma unroll
        for (int j=0;j<8;j++) acc[i][j] += a[i]*b[j];
    }
    __syncthreads();
  }

  int tr = t/16, tc = t%16;
  int b = p0 >> 12, nn = (p0 & 4095) + tc*8;
  #pragma unroll
  for (int i=0;i<8;i++){
    int oo = o0 + tr*8 + i;
    float g5 = wf[WF_G5+oo], b5 = wf[WF_B5+oo];
    long base = ((long)(b*512 + oo) << 12) + nn;
    if (f){
      float4 v0 = make_float4(lrelu(g5*acc[i][0]+b5), lrelu(g5*acc[i][1]+b5),
                              lrelu(g5*acc[i][2]+b5), lrelu(g5*acc[i][3]+b5));
      float4 v1 = make_float4(lrelu(g5*acc[i][4]+b5), lrelu(g5*acc[i][5]+b5),
                              lrelu(g5*acc[i][6]+b5), lrelu(g5*acc[i][7]+b5));
      *(float4*)((float*)outv + base)     = v0;
      *(float4*)((float*)outv + base + 4) = v1;
    } else {
      #pragma unroll
      for (int j=0;j<8;j++)
        ((bf16*)outv)[base + j] = __float2bfloat16(lrelu(g5*acc[i][j] + b5));
    }
  }
}

// ---------------- host ------------------------------------------------------
extern "C" void kernel_launch(void* const* d_in, const int* in_sizes, int n_in,
                              void* d_out, int out_size, void* d_ws, size_t ws_size,
                              hipStream_t stream) {
  const void* X = d_in[0];
  float* ws = (float*)d_ws;
  int* flagp = (int*)(ws + OFF_FLAG);

  WPack pk;
  static const int wsz[27] = {192,64,64, 4096,64,64, 8192,64,64, 4096,64,64, 4096,64,64,
                              4096,64,64, 4096,64,64, 8192,128,128, 65536,512,512};
  int off = 0;
  for (int i=0;i<27;i++){ pk.p[i] = d_in[i+1]; pk.off[i] = off; off += wsz[i]; }
  pk.off[27] = off;

  k_detect<<<dim3(1), dim3(64), 0, stream>>>(X, flagp);
  k_wcvt<<<dim3((WF_END+255)/256), dim3(256), 0, stream>>>(pk, ws + OFF_WF, flagp);
  k_point<<<dim3(NP/256), dim3(256), 0, stream>>>(X, ws);
  k_knn2<<<dim3(NP/8), dim3(512), 0, stream>>>(ws, (int*)(ws + OFF_IDX2));

  long availf = (long)(ws_size/4) - OFF_PAIR;
  int chunk = 4096;
  if (availf < (long)N_*N_){
    long c = (availf / N_) & ~127L;
    chunk = (int)(c < 128 ? 128 : c);
    if (chunk > 4096) chunk = 4096;
  }
  for (int b=0;b<8;b++){
    for (int n0=0;n0<N_; n0+=chunk){
      int rows = (N_ - n0 < chunk) ? (N_ - n0) : chunk;
      k_pair<<<dim3(32, rows/128), dim3(256), 0, stream>>>(ws, ws + OFF_PAIR, b, n0);
      k_topk_pair<<<dim3(rows/4), dim3(256), 0, stream>>>(ws + OFF_PAIR, (int*)(ws + OFF_IDX1), b, n0);
    }
  }
  k_uv<<<dim3(NP/256), dim3(256), 0, stream>>>(ws);
  k_edge<1><<<dim3(NP/64), dim3(512), 0, stream>>>(ws, (const int*)(ws + OFF_IDX1),
        OFF_U, OFF_V, WF_WDG2, WF_GDG1, WF_BDG1, WF_GDG2, WF_BDG2, OFF_HDG);
  k_w<<<dim3(NP/256), dim3(256), 0, stream>>>(ws);
  k_edge<0><<<dim3(NP/64), dim3(512), 0, stream>>>(ws, (const int*)(ws + OFF_IDX2),
        0, OFF_U, WF_WSN2, WF_GSN1, WF_BSN1, WF_GSN2, WF_BSN2, OFF_H2);
  k_h4<<<dim3(NP/64), dim3(256), 0, stream>>>(ws, ws + OFF_H4);
  k_conv5<<<dim3(NP/128, 4), dim3(256), 0, stream>>>(ws, d_out);
}

// Round 8
// 1027.982 us; speedup vs baseline: 1.4946x; 1.1245x over previous
//
#include <hip/hip_runtime.h>
#include <hip/hip_bf16.h>
#include <stdint.h>

typedef __hip_bfloat16 bf16;

#define N_   4096
#define NP   32768   // B*N
#define KNN  20

// ---- workspace layout (units: float) ----
#define OFF_H2   0L         // 32768*64 ; later reused as hsn output
#define OFF_XYZ  2097152L   // 3 planes of 32768 (SoA)
#define OFF_X    2097152L
#define OFF_Y    2129920L
#define OFF_Z    2162688L
#define OFF_XX   2195456L   // 32768  (|h2|^2)
#define OFF_XXC  2228224L   // 32768  (|x|^2)
#define OFF_IDX1 2260992L   // 32768*20 int
#define OFF_P4   2260992L   // AoS (x,y,z,|x|^2) 32768*4 floats; lives in the
                            // idx1 region: written by k_point, read by k_knn2,
                            // dead before the pair loop writes idx1 over it.
#define OFF_IDX2 2916352L   // 32768*20 int
#define OFF_WF   3571712L   // 104768 fp32 weights
#define OFF_FLAG 3676480L   // dtype flag (int), 64-float slot
#define OFF_PAIR 3676544L   // pair chunk lives here during kNN phase
// post-kNN reuse of the pair region:
#define OFF_U    3676544L   // 32768*64 ; u=(Wa-Wb)h2 ; later w = Wsn1*hdg
#define OFF_V    5773696L   // 32768*64 ; v = Wb*h2
#define OFF_HDG  7870848L   // 32768*64
#define OFF_H4   5773696L   // 128*32768 k-major; overlaps V+HDG (both dead by then)

// ---- fp32 weight bank offsets ----
#define WF_W1 0
#define WF_G1 192
#define WF_B1 256
#define WF_W2 320
#define WF_G2 4416
#define WF_B2 4480
#define WF_WDG1 4544
#define WF_GDG1 12736
#define WF_BDG1 12800
#define WF_WDG2 12864
#define WF_GDG2 16960
#define WF_BDG2 17024
#define WF_WSN1 17088
#define WF_GSN1 21184
#define WF_BSN1 21248
#define WF_WSN2 21312
#define WF_GSN2 25408
#define WF_BSN2 25472
#define WF_W3 25536
#define WF_G3 29632
#define WF_B3 29696
#define WF_W4 29760
#define WF_G4 37952
#define WF_B4 38080
#define WF_W5 38208
#define WF_G5 103744
#define WF_B5 104256
#define WF_END 104768

__device__ __forceinline__ float lrelu(float x){ return x >= 0.f ? x : 0.01f*x; }

// exact-deterministic distance: MUST be the single source for both fill and
// rescan in k_knn2 (bit-identical results required for ordering consistency)
__device__ __forceinline__ float distf(float xn,float yn,float zn,
                                       float xm,float ym,float zm,float cm){
  return fmaf(2.f, fmaf(xn,xm, fmaf(yn,ym, zn*zm)), -cm);
}

// DPP-step max; CTRL must be a compile-time constant -> template parameter.
template<int CTRL>
__device__ __forceinline__ float fmax_dpp(float v){
  int o = __builtin_amdgcn_update_dpp(0, __float_as_int(v), CTRL, 0xF, 0xF, true);
  return fmaxf(v, __int_as_float(o));
}
// Full-wave max returned as a wave-uniform scalar (SGPR broadcast).
// Pure DPP/VALU: xor1/xor2/ror4/ror8 give 16-lane row maxes; ROW_BCAST15
// (0x142) + ROW_BCAST31 (0x143) funnel the global max to lane 63; readlane
// broadcasts it. bound_ctrl=1 corrupts lanes 0-15 after bcast15 (fmax with
// 0.0) but those lanes are never on the dataflow path to lane 63.
__device__ __forceinline__ float wave_max_bcast(float v){
  v = fmax_dpp<0xB1>(v);    // quad_perm xor1
  v = fmax_dpp<0x4E>(v);    // quad_perm xor2
  v = fmax_dpp<0x124>(v);   // row_ror:4
  v = fmax_dpp<0x128>(v);   // row_ror:8  -> row max in all 16 lanes of a row
  v = fmax_dpp<0x142>(v);   // row_bcast15: 15->16..31, 47->48..63
  v = fmax_dpp<0x143>(v);   // row_bcast31: 31->32..63; lane 63 = global max
  return __int_as_float(__builtin_amdgcn_readlane(__float_as_int(v), 63));
}

// branchless insert of (c,m) into per-lane sorted top-2 (k1,i1) >= (k2,i2).
// strict > keeps the earlier (smaller-index) candidate ahead on ties.
__device__ __forceinline__ void ins2(float c, int m, float& k1, int& i1,
                                     float& k2, int& i2){
  bool g1 = c > k1, g2 = c > k2;
  k2 = g2 ? (g1 ? k1 : c) : k2;
  i2 = g2 ? (g1 ? i1 : m) : i2;
  k1 = g1 ? c : k1;
  i1 = g1 ? m : i1;
}

// Exact top-20 by iterative pop. Candidate m in 0..4095.
// MODE 0: owner lane js = m & 63,      ord = m >> 6          (lane-strided fill)
// MODE 1: owner lane js = (m>>2)&63,   ord = ((m>>8)<<2)|(m&3)
// Each lane holds its segment's best-2 unextracted candidates; pop promotes,
// rescan (rare, ~3/query) rebuilds via refetch(mre) which must be
// bit-consistent with fill values. In a rescan, lane scans its segment's
// candidate with ord == lane (both modes satisfy ord(mre(lane)) == lane).
template<int MODE, typename F>
__device__ __forceinline__ void topk_pairs(float k1, int i1, float k2, int i2,
                                           int lane, F&& refetch,
                                           int* __restrict__ outp){
  const float NEGINF = -__builtin_inff();
  uint32_t mlo = 0, mhi = 0;   // exclusion mask over MY segment's ords
  int keep = 0;
  #pragma unroll 1
  for (int tt = 0; tt < KNN; tt++){
    float g = wave_max_bcast(k1);
    uint64_t ball = __ballot(k1 == g);
    int js = __builtin_amdgcn_readfirstlane((int)(__ffsll((unsigned long long)ball) - 1));
    int wid = __builtin_amdgcn_readlane(i1, js);
    // dry check reads OLD k2 of js (== js's k1 after the pop below) so the
    // readlane doesn't serialize behind the cndmask updates.
    int kown = __builtin_amdgcn_readlane(__float_as_int(k2), js);
    if (lane == tt) keep = wid;
    bool own = (lane == js);
    // exclusion bit for wid (ord/bit are wave-uniform scalars)
    uint32_t ord = (MODE == 0) ? ((uint32_t)wid >> 6)
                               : ((((uint32_t)wid >> 8) << 2) | ((uint32_t)wid & 3u));
    uint32_t blo = (ord < 32u) ? (1u << ord) : 0u;
    uint32_t bhi = (ord >= 32u) ? (1u << (ord - 32u)) : 0u;
    mlo |= own ? blo : 0u;
    mhi |= own ? bhi : 0u;
    k1 = own ? k2 : k1;  i1 = own ? i2 : i1;
    k2 = own ? NEGINF : k2;
    // owner dry? (wave-uniform branch, rare)
    if (kown == (int)0xFF800000u){
      uint32_t mre = (MODE == 0)
        ? ((uint32_t)js + ((uint32_t)lane << 6))
        : ((((uint32_t)lane >> 2) << 8) | (((uint32_t)js) << 2) | ((uint32_t)lane & 3u));
      float v = refetch(mre);
      uint32_t bl = (uint32_t)__builtin_amdgcn_readlane((int)mlo, js);
      uint32_t bh = (uint32_t)__builtin_amdgcn_readlane((int)mhi, js);
      uint64_t bm = ((uint64_t)bh << 32) | bl;
      if ((bm >> lane) & 1ull) v = NEGINF;
      float g2 = wave_max_bcast(v);
      uint64_t b2 = __ballot(v == g2);
      int jw = (int)(__ffsll((unsigned long long)b2) - 1);
      uint32_t wm = (MODE == 0)
        ? ((uint32_t)js + ((uint32_t)jw << 6))
        : ((((uint32_t)jw >> 2) << 8) | (((uint32_t)js) << 2) | ((uint32_t)jw & 3u));
      if (lane == js){ k1 = g2; i1 = (int)wm; }
    }
  }
  if (lane < KNN) outp[lane] = keep;
}

// ---------------- K-1: dtype detect (1 = fp32 inputs, 0 = bf16) -------------
__global__ void k_detect(const void* __restrict__ x, int* __restrict__ flag){
  int lane = threadIdx.x;
  const bf16* xb = (const bf16*)x;
  int cnt = 0;
  #pragma unroll 1
  for (int i = lane; i < 256; i += 64){
    float v = __bfloat162float(xb[2*i]);
    float a = fabsf(v);
    if (a > 1e-3f && a < 100.f) cnt++;
  }
  #pragma unroll
  for (int off = 32; off; off >>= 1) cnt += __shfl_down(cnt, off, 64);
  if (lane == 0) *flag = (cnt >= 128) ? 0 : 1;
}

// ---------------- K0: convert all weights -> fp32 bank ----------------------
struct WPack {
  const void* p[27];
  int off[28];
};

__global__ void k_wcvt(WPack pk, float* __restrict__ dst, const int* __restrict__ flagp){
  int i = blockIdx.x*256 + threadIdx.x;
  if (i >= WF_END) return;
  int f = *flagp;
  #pragma unroll 1
  for (int s = 0; s < 27; s++){
    if (i < pk.off[s+1]){
      int j = i - pk.off[s];
      dst[i] = f ? ((const float*)pk.p[s])[j]
                 : __bfloat162float(((const bf16*)pk.p[s])[j]);
      return;
    }
  }
}

// ---------------- K1: per-point MLP1+MLP2, norms, coords (SoA + AoS) --------
__global__ void k_point(const void* __restrict__ x, float* __restrict__ ws){
  const float* wf = ws + OFF_WF;
  int f = ((const int*)(ws + OFF_FLAG))[0];
  int n = blockIdx.x*256 + threadIdx.x;
  float x0, x1, x2;
  if (f){
    const float* xf = (const float*)x;
    x0 = xf[n*3+0]; x1 = xf[n*3+1]; x2 = xf[n*3+2];
  } else {
    const bf16* xb = (const bf16*)x;
    x0 = __bfloat162float(xb[n*3+0]);
    x1 = __bfloat162float(xb[n*3+1]);
    x2 = __bfloat162float(xb[n*3+2]);
  }

  float h1[64];
  #pragma unroll
  for (int o=0;o<64;o++){
    float a = wf[WF_W1+o*3+0]*x0 + wf[WF_W1+o*3+1]*x1 + wf[WF_W1+o*3+2]*x2;
    h1[o] = lrelu(wf[WF_G1+o]*a + wf[WF_B1+o]);
  }
  float xx = 0.f;
  #pragma unroll 1
  for (int o=0;o<64;o++){
    float a = 0.f;
    #pragma unroll
    for (int c=0;c<64;c++) a += wf[WF_W2+o*64+c]*h1[c];
    float h2 = lrelu(wf[WF_G2+o]*a + wf[WF_B2+o]);
    ws[OFF_H2 + (long)n*64 + o] = h2;
    xx += h2*h2;
  }
  ws[OFF_XX + n] = xx;
  float cc = x0*x0 + x1*x1 + x2*x2;
  ws[OFF_X + n] = x0; ws[OFF_Y + n] = x1; ws[OFF_Z + n] = x2;
  ws[OFF_XXC + n] = cc;
  *(float4*)(ws + OFF_P4 + 4L*n) = make_float4(x0, x1, x2, cc);
}

// ---------------- K2a: pair GEMM (fp32), per batch chunk --------------------
__global__ __launch_bounds__(256) void k_pair(const float* __restrict__ ws, float* __restrict__ pair,
                                              int b, int n0){
  __shared__ float As[64*128];
  __shared__ float Bs[64*128];
  int t = threadIdx.x;
  int bx = blockIdx.x, by = blockIdx.y;
  const float* h2 = ws + OFF_H2 + (long)b*N_*64;

  int r = t >> 1, c0 = (t & 1)*32;
  const float4* arow = (const float4*)(h2 + (long)(n0 + by*128 + r)*64 + c0);
  const float4* brow = (const float4*)(h2 + (long)(bx*128 + r)*64 + c0);
  #pragma unroll
  for (int q=0;q<8;q++){
    float4 av = arow[q];
    As[(c0+4*q+0)*128 + r] = av.x; As[(c0+4*q+1)*128 + r] = av.y;
    As[(c0+4*q+2)*128 + r] = av.z; As[(c0+4*q+3)*128 + r] = av.w;
    float4 bv = brow[q];
    Bs[(c0+4*q+0)*128 + r] = bv.x; Bs[(c0+4*q+1)*128 + r] = bv.y;
    Bs[(c0+4*q+2)*128 + r] = bv.z; Bs[(c0+4*q+3)*128 + r] = bv.w;
  }
  __syncthreads();

  int tr = t/16, tc = t%16;
  float acc[8][8] = {};
  #pragma unroll 4
  for (int k=0;k<64;k++){
    const float4* ap = (const float4*)&As[k*128 + tr*8];
    const float4* bp = (const float4*)&Bs[k*128 + tc*8];
    float4 a0 = ap[0], a1 = ap[1], c0v = bp[0], c1v = bp[1];
    float a[8] = {a0.x,a0.y,a0.z,a0.w,a1.x,a1.y,a1.z,a1.w};
    float c[8] = {c0v.x,c0v.y,c0v.z,c0v.w,c1v.x,c1v.y,c1v.z,c1v.w};
    #pragma unroll
    for (int i=0;i<8;i++)
      #pragma unroll
      for (int j=0;j<8;j++) acc[i][j] += a[i]*c[j];
  }
  const float* xxp = ws + OFF_XX + b*N_ + bx*128 + tc*8;
  float xxm[8];
  #pragma unroll
  for (int j=0;j<8;j++) xxm[j] = xxp[j];
  #pragma unroll
  for (int i=0;i<8;i++){
    long row = (long)(by*128 + tr*8 + i)*N_ + bx*128 + tc*8;
    float4 o0 = make_float4(2.f*acc[i][0]-xxm[0], 2.f*acc[i][1]-xxm[1],
                            2.f*acc[i][2]-xxm[2], 2.f*acc[i][3]-xxm[3]);
    float4 o1 = make_float4(2.f*acc[i][4]-xxm[4], 2.f*acc[i][5]-xxm[5],
                            2.f*acc[i][6]-xxm[6], 2.f*acc[i][7]-xxm[7]);
    ((float4*)(pair+row))[0] = o0;
    ((float4*)(pair+row))[1] = o1;
  }
}

// ---------------- K2b: top-20 over stored pair rows (pairs-pop, 4 rows/blk) -
__global__ __launch_bounds__(256) void k_topk_pair(const float* __restrict__ pair, int* __restrict__ idx1,
                                                   int b, int n0){
  int t = threadIdx.x;
  int lane = t & 63, wv = t >> 6;
  int r = blockIdx.x*4 + wv;
  const float* rowp = pair + (long)r*N_;
  const float4* src = (const float4*)rowp;
  float k1 = -__builtin_inff(), k2 = -__builtin_inff();
  int i1 = 0, i2 = 0;
  #pragma unroll
  for (int q=0;q<16;q++){
    float4 v = src[lane + 64*q];
    int m0 = 4*lane + 256*q;
    ins2(v.x, m0,   k1,i1,k2,i2);
    ins2(v.y, m0+1, k1,i1,k2,i2);
    ins2(v.z, m0+2, k1,i1,k2,i2);
    ins2(v.w, m0+3, k1,i1,k2,i2);
  }
  topk_pairs<1>(k1,i1,k2,i2, lane, [&](uint32_t mre){ return rowp[mre]; },
                idx1 + (long)(b*N_ + n0 + r)*KNN);
}

// ---------------- K3: coord-space kNN, LDS chunk-staged (8 queries/blk) -----
__global__ __launch_bounds__(512) void k_knn2(const float* __restrict__ ws, int* __restrict__ idx2){
  __shared__ float4 pbuf[2][512];
  int t = threadIdx.x;
  int lane = t & 63, wv = t >> 6;
  int n = blockIdx.x*8 + wv;
  int base = n & ~4095;
  const float4* P4 = (const float4*)(ws + OFF_P4);
  float4 qp = P4[n];
  float xn = qp.x, yn = qp.y, zn = qp.z;
  float k1 = -__builtin_inff(), k2 = -__builtin_inff();
  int i1 = 0, i2 = 0;

  pbuf[0][t] = P4[base + t];
  __syncthreads();
  #pragma unroll 1
  for (int c = 0; c < 8; c++){
    float4 nx;
    if (c < 7) nx = P4[base + (c+1)*512 + t];   // issue early; hides under compute
    const float4* pb = pbuf[c & 1];
    #pragma unroll
    for (int j = 0; j < 8; j++){
      float4 p = pb[lane + 64*j];
      int m = c*512 + 64*j + lane;              // m & 63 == lane  (MODE-0 segment)
      ins2(distf(xn,yn,zn, p.x,p.y,p.z,p.w), m, k1,i1,k2,i2);
    }
    __syncthreads();
    if (c < 7) pbuf[(c+1) & 1][t] = nx;
    __syncthreads();
  }
  topk_pairs<0>(k1,i1,k2,i2, lane, [&](uint32_t mre){
      float4 p = P4[base + (int)mre];
      return distf(xn,yn,zn, p.x, p.y, p.z, p.w);
    }, idx2 + (long)n*KNN);
}

// ---------------- K3b: u = (Wa-Wb)h2, v = Wb h2 (post-kNN) ------------------
// r7: was grid-starved (128 blocks on 256 CUs, Occupancy 5.4%, VALUBusy 5%).
// Now 8 waves per 64-point group, each wave owns a wave-uniform 8-output
// slice (weights stay scalar s_loads); grid 128 -> 1024 blocks. Outputs
// buffered and stored as 2x float4 per stream. Dot-product order per output
// unchanged -> bit-identical results.
__global__ __launch_bounds__(256) void k_uv(float* __restrict__ ws){
  const float* wf = ws + OFF_WF;
  int t = threadIdx.x;
  int lane = t & 63;
  int W = blockIdx.x*4 + (t >> 6);
  int g = __builtin_amdgcn_readfirstlane(W >> 3);
  int s = __builtin_amdgcn_readfirstlane(W & 7);
  int n = g*64 + lane;
  int o0 = s*8;
  float h[64];
  const float4* src = (const float4*)(ws + OFF_H2 + (long)n*64);
  #pragma unroll
  for (int q=0;q<16;q++){ float4 v = src[q]; h[4*q]=v.x; h[4*q+1]=v.y; h[4*q+2]=v.z; h[4*q+3]=v.w; }
  float ua[8], vv[8];
  #pragma unroll 1
  for (int j=0;j<8;j++){
    int o = o0 + j;
    float va=0.f, vb=0.f;
    #pragma unroll
    for (int c=0;c<64;c++){
      va += wf[WF_WDG1+o*128+c]*h[c];
      vb += wf[WF_WDG1+o*128+64+c]*h[c];
    }
    ua[j] = va - vb;
    vv[j] = vb;
  }
  float* up = ws + OFF_U + (long)n*64 + o0;
  *(float4*)up     = make_float4(ua[0],ua[1],ua[2],ua[3]);
  *(float4*)(up+4) = make_float4(ua[4],ua[5],ua[6],ua[7]);
  float* vp = ws + OFF_V + (long)n*64 + o0;
  *(float4*)vp     = make_float4(vv[0],vv[1],vv[2],vv[3]);
  *(float4*)(vp+4) = make_float4(vv[4],vv[5],vv[6],vv[7]);
}

// ---------------- K4/K5: edge stage (gathered first conv folded) ------------
// r6: 512-thread blocks (8 waves -> 16 waves/CU, was grid-limited 8/CU at 20%
// occupancy) + transposed LDS with vector reads (1 b64 + 1 b128 per kk instead
// of 8 b32). Per-thread tile 2 edges x 4 outs. Software pipeline kept: idx in
// LDS, k+1 gather register-prefetched under the MAC loop.
template<int USE_U>
__global__ __launch_bounds__(512) void k_edge(float* __restrict__ ws, const int* __restrict__ idxt,
      long uoff, long goff, int w2off,
      int g1off, int b1off, int g2off, int b2off, long outoff){
  __shared__ float y1t[64*66];   // [channel][edge], row 66 (b64-aligned, 2-way reads)
  __shared__ float w2t[64*68];   // [channel][out],  row 68 (b128-aligned, 2-way reads)
  __shared__ int   idxs[64*KNN];
  const float* wf = ws + OFF_WF;
  int t = threadIdx.x;
  int p0 = blockIdx.x*64;
  int b  = p0 >> 12;
  int lane = t & 63, wv = t >> 6;        // write phase: channel=lane, 8 edges/wave
  int tr = t & 31, oc = t >> 5;          // MAC: edges 2tr..2tr+1, outs 4oc..4oc+3

  #pragma unroll 1
  for (int i=t;i<4096;i+=512){ int o = i>>6, kk = i&63; w2t[kk*68+o] = wf[w2off + i]; }
  #pragma unroll 1
  for (int i=t;i<64*KNN;i+=512) idxs[i] = idxt[(long)p0*KNN + i];

  // per-lane registers: u for my 8 edges (channel=lane), g1/b1, g2/b2
  float ur[8];
  if (USE_U){
    #pragma unroll
    for (int jj=0;jj<8;jj++)
      ur[jj] = ws[uoff + (long)(p0 + wv*8 + jj)*64 + lane];
  } else {
    #pragma unroll
    for (int jj=0;jj<8;jj++) ur[jj] = 0.f;
  }
  float g1v = wf[g1off+lane], b1v = wf[b1off+lane];
  float g2r[4], b2r[4];
  #pragma unroll
  for (int j=0;j<4;j++){ g2r[j] = wf[g2off+oc*4+j]; b2r[j] = wf[b2off+oc*4+j]; }

  float mx[2][4];
  #pragma unroll
  for (int i=0;i<2;i++)
    #pragma unroll
    for (int j=0;j<4;j++) mx[i][j] = -3.0e38f;

  __syncthreads();   // idxs + w2t ready

  long gbase = goff + ((long)b << 12)*64;
  float pf[8];
  #pragma unroll
  for (int jj=0;jj<8;jj++){
    int nb = idxs[(wv*8 + jj)*KNN];
    pf[jj] = ws[gbase + (long)nb*64 + lane];
  }

  for (int k=0;k<KNN;k++){
    // write phase: consume prefetched gather for this k
    #pragma unroll
    for (int jj=0;jj<8;jj++){
      int e = wv*8 + jj;
      float val = pf[jj];
      if (USE_U) val += ur[jj];
      y1t[lane*66 + e] = lrelu(g1v*val + b1v);
    }
    __syncthreads();
    // issue next-k gather NOW; latency hides under the MAC loop below
    if (k+1 < KNN){
      #pragma unroll
      for (int jj=0;jj<8;jj++){
        int nb = idxs[(wv*8 + jj)*KNN + k+1];
        pf[jj] = ws[gbase + (long)nb*64 + lane];
      }
    }
    float acc[2][4] = {};
    #pragma unroll 4
    for (int kk=0;kk<64;kk++){
      float2 a = *(const float2*)&y1t[kk*66 + tr*2];
      float4 c = *(const float4*)&w2t[kk*68 + oc*4];
      float av[2] = {a.x, a.y};
      float cv[4] = {c.x, c.y, c.z, c.w};
      #pragma unroll
      for (int i=0;i<2;i++)
        #pragma unroll
        for (int j=0;j<4;j++) acc[i][j] += av[i]*cv[j];
    }
    #pragma unroll
    for (int i=0;i<2;i++)
      #pragma unroll
      for (int j=0;j<4;j++){
        float yy = lrelu(g2r[j]*acc[i][j] + b2r[j]);
        mx[i][j] = fmaxf(mx[i][j], yy);
      }
    __syncthreads();
  }
  #pragma unroll
  for (int i=0;i<2;i++)
    #pragma unroll
    for (int j=0;j<4;j++)
      ws[outoff + (long)(p0 + tr*2 + i)*64 + oc*4 + j] = mx[i][j];
}

// ---------------- K4b: w = Wsn1 . hdg per point (stored raw) ----------------
// r7: same 8-slice-per-point restructure as k_uv (was 128-block grid-starved).
__global__ __launch_bounds__(256) void k_w(float* __restrict__ ws){
  const float* wf = ws + OFF_WF;
  int t = threadIdx.x;
  int lane = t & 63;
  int W = blockIdx.x*4 + (t >> 6);
  int g = __builtin_amdgcn_readfirstlane(W >> 3);
  int s = __builtin_amdgcn_readfirstlane(W & 7);
  int n = g*64 + lane;
  int o0 = s*8;
  float h[64];
  const float4* src = (const float4*)(ws + OFF_HDG + (long)n*64);
  #pragma unroll
  for (int q=0;q<16;q++){ float4 v = src[q]; h[4*q]=v.x; h[4*q+1]=v.y; h[4*q+2]=v.z; h[4*q+3]=v.w; }
  float ua[8];
  #pragma unroll 1
  for (int j=0;j<8;j++){
    int o = o0 + j;
    float a = 0.f;
    #pragma unroll
    for (int c=0;c<64;c++) a += wf[WF_WSN1 + o*64 + c]*h[c];
    ua[j] = a;
  }
  float* up = ws + OFF_U + (long)n*64 + o0;
  *(float4*)up     = make_float4(ua[0],ua[1],ua[2],ua[3]);
  *(float4*)(up+4) = make_float4(ua[4],ua[5],ua[6],ua[7]);
}

// ---------------- K6a: head conv3+conv4, h4 out in k-major [128][NP] --------
__global__ __launch_bounds__(256) void k_h4(const float* __restrict__ ws, float* __restrict__ h4g){
  __shared__ float Hs[64*65];    // [ch][pt] (hsn), then reused as [o3][pt] (h3)
  __shared__ float wb[64*130];   // W3 as wb[c*65+o]; later W4 as wb[c*130+o]
  const float* wf = ws + OFF_WF;
  int t = threadIdx.x;
  int p0 = blockIdx.x*64;

  {
    int r = t >> 2, c0 = (t & 3)*16;
    const float4* src = (const float4*)(ws + OFF_H2 + (long)(p0 + r)*64 + c0);
    #pragma unroll
    for (int q=0;q<4;q++){
      float4 v = src[q];
      Hs[(c0+4*q+0)*65 + r] = v.x; Hs[(c0+4*q+1)*65 + r] = v.y;
      Hs[(c0+4*q+2)*65 + r] = v.z; Hs[(c0+4*q+3)*65 + r] = v.w;
    }
  }
  {
    int r = t >> 2, c0 = (t & 3)*16;
    const float4* src = (const float4*)(wf + WF_W3 + (long)r*64 + c0);
    #pragma unroll
    for (int q=0;q<4;q++){
      float4 v = src[q];
      wb[(c0+4*q+0)*65 + r] = v.x; wb[(c0+4*q+1)*65 + r] = v.y;
      wb[(c0+4*q+2)*65 + r] = v.z; wb[(c0+4*q+3)*65 + r] = v.w;
    }
  }
  __syncthreads();

  int pr = t & 15, og = t >> 4;
  float acc[4][4] = {};
  #pragma unroll 8
  for (int k=0;k<64;k++){
    float4 a = *(const float4*)&Hs[k*65 + pr*4];
    float4 c = *(const float4*)&wb[k*65 + og*4];
    float av[4] = {a.x,a.y,a.z,a.w}, cv[4] = {c.x,c.y,c.z,c.w};
    #pragma unroll
    for (int i=0;i<4;i++)
      #pragma unroll
      for (int j=0;j<4;j++) acc[i][j] += av[i]*cv[j];
  }
  __syncthreads();

  #pragma unroll
  for (int j=0;j<4;j++){
    int o = og*4 + j;
    float g3 = wf[WF_G3+o], b3 = wf[WF_B3+o];
    #pragma unroll
    for (int i=0;i<4;i++)
      Hs[o*65 + pr*4 + i] = lrelu(g3*acc[i][j] + b3);
  }
  {
    int r = t >> 1, c0 = (t & 1)*32;
    const float4* src = (const float4*)(wf + WF_W4 + (long)r*64 + c0);
    #pragma unroll
    for (int q=0;q<8;q++){
      float4 v = src[q];
      wb[(c0+4*q+0)*130 + r] = v.x; wb[(c0+4*q+1)*130 + r] = v.y;
      wb[(c0+4*q+2)*130 + r] = v.z; wb[(c0+4*q+3)*130 + r] = v.w;
    }
  }
  __syncthreads();

  float a2[4][8] = {};
  #pragma unroll 8
  for (int k=0;k<64;k++){
    float4 a = *(const float4*)&Hs[k*65 + pr*4];
    float4 c0 = *(const float4*)&wb[k*130 + og*8];
    float4 c1 = *(const float4*)&wb[k*130 + og*8 + 4];
    float av[4] = {a.x,a.y,a.z,a.w};
    float cv[8] = {c0.x,c0.y,c0.z,c0.w,c1.x,c1.y,c1.z,c1.w};
    #pragma unroll
    for (int i=0;i<4;i++)
      #pragma unroll
      for (int j=0;j<8;j++) a2[i][j] += av[i]*cv[j];
  }
  #pragma unroll
  for (int j=0;j<8;j++){
    int o = og*8 + j;
    float g4 = wf[WF_G4+o], b4 = wf[WF_B4+o];
    #pragma unroll
    for (int i=0;i<4;i++)
      h4g[(long)o*NP + p0 + pr*4 + i] = lrelu(g4*a2[i][j] + b4);
  }
}

// ---------------- K6b: conv5 GEMM [512 x 128] . [128 x NP] ------------------
#define KC 32
__global__ __launch_bounds__(256) void k_conv5(const float* __restrict__ ws, void* __restrict__ outv){
  __shared__ float As[KC*128];   // [k][o]
  __shared__ float Bs[KC*128];   // [k][pt]
  const float* wf = ws + OFF_WF;
  int f = ((const int*)(ws + OFF_FLAG))[0];
  int t = threadIdx.x;
  int p0 = blockIdx.x*128;
  int o0 = blockIdx.y*128;
  const float* H4 = ws + OFF_H4;
  float acc[8][8] = {};

  for (int kc = 0; kc < 128; kc += KC){
    {
      int r = t >> 1, c0 = (t & 1)*16;
      const float4* src = (const float4*)(wf + WF_W5 + (long)(o0 + r)*128 + kc + c0);
      #pragma unroll
      for (int q=0;q<4;q++){
        float4 v = src[q];
        As[(c0+4*q+0)*128 + r] = v.x; As[(c0+4*q+1)*128 + r] = v.y;
        As[(c0+4*q+2)*128 + r] = v.z; As[(c0+4*q+3)*128 + r] = v.w;
      }
    }
    {
      int kr = t >> 3, pc = (t & 7)*16;
      const float4* src = (const float4*)(H4 + (long)(kc + kr)*NP + p0 + pc);
      float4 v0 = src[0], v1 = src[1], v2 = src[2], v3 = src[3];
      *(float4*)&Bs[kr*128 + pc     ] = v0;
      *(float4*)&Bs[kr*128 + pc + 4 ] = v1;
      *(float4*)&Bs[kr*128 + pc + 8 ] = v2;
      *(float4*)&Bs[kr*128 + pc + 12] = v3;
    }
    __syncthreads();
    int tr = t/16, tc = t%16;
    #pragma unroll 8
    for (int k=0;k<KC;k++){
      const float4* ap = (const float4*)&As[k*128 + tr*8];
      const float4* bp = (const float4*)&Bs[k*128 + tc*8];
      float4 a0 = ap[0], a1 = ap[1], b0 = bp[0], b1 = bp[1];
      float a[8] = {a0.x,a0.y,a0.z,a0.w,a1.x,a1.y,a1.z,a1.w};
      float b[8] = {b0.x,b0.y,b0.z,b0.w,b1.x,b1.y,b1.z,b1.w};
      #pragma unroll
      for (int i=0;i<8;i++)
        #pragma unroll
        for (int j=0;j<8;j++) acc[i][j] += a[i]*b[j];
    }
    __syncthreads();
  }

  int tr = t/16, tc = t%16;
  int b = p0 >> 12, nn = (p0 & 4095) + tc*8;
  #pragma unroll
  for (int i=0;i<8;i++){
    int oo = o0 + tr*8 + i;
    float g5 = wf[WF_G5+oo], b5 = wf[WF_B5+oo];
    long base = ((long)(b*512 + oo) << 12) + nn;
    if (f){
      float4 v0 = make_float4(lrelu(g5*acc[i][0]+b5), lrelu(g5*acc[i][1]+b5),
                              lrelu(g5*acc[i][2]+b5), lrelu(g5*acc[i][3]+b5));
      float4 v1 = make_float4(lrelu(g5*acc[i][4]+b5), lrelu(g5*acc[i][5]+b5),
                              lrelu(g5*acc[i][6]+b5), lrelu(g5*acc[i][7]+b5));
      *(float4*)((float*)outv + base)     = v0;
      *(float4*)((float*)outv + base + 4) = v1;
    } else {
      #pragma unroll
      for (int j=0;j<8;j++)
        ((bf16*)outv)[base + j] = __float2bfloat16(lrelu(g5*acc[i][j] + b5));
    }
  }
}

// ---------------- host ------------------------------------------------------
extern "C" void kernel_launch(void* const* d_in, const int* in_sizes, int n_in,
                              void* d_out, int out_size, void* d_ws, size_t ws_size,
                              hipStream_t stream) {
  const void* X = d_in[0];
  float* ws = (float*)d_ws;
  int* flagp = (int*)(ws + OFF_FLAG);

  WPack pk;
  static const int wsz[27] = {192,64,64, 4096,64,64, 8192,64,64, 4096,64,64, 4096,64,64,
                              4096,64,64, 4096,64,64, 8192,128,128, 65536,512,512};
  int off = 0;
  for (int i=0;i<27;i++){ pk.p[i] = d_in[i+1]; pk.off[i] = off; off += wsz[i]; }
  pk.off[27] = off;

  k_detect<<<dim3(1), dim3(64), 0, stream>>>(X, flagp);
  k_wcvt<<<dim3((WF_END+255)/256), dim3(256), 0, stream>>>(pk, ws + OFF_WF, flagp);
  k_point<<<dim3(NP/256), dim3(256), 0, stream>>>(X, ws);
  k_knn2<<<dim3(NP/8), dim3(512), 0, stream>>>(ws, (int*)(ws + OFF_IDX2));

  long availf = (long)(ws_size/4) - OFF_PAIR;
  int chunk = 4096;
  if (availf < (long)N_*N_){
    long c = (availf / N_) & ~127L;
    chunk = (int)(c < 128 ? 128 : c);
    if (chunk > 4096) chunk = 4096;
  }
  for (int b=0;b<8;b++){
    for (int n0=0;n0<N_; n0+=chunk){
      int rows = (N_ - n0 < chunk) ? (N_ - n0) : chunk;
      k_pair<<<dim3(32, rows/128), dim3(256), 0, stream>>>(ws, ws + OFF_PAIR, b, n0);
      k_topk_pair<<<dim3(rows/4), dim3(256), 0, stream>>>(ws + OFF_PAIR, (int*)(ws + OFF_IDX1), b, n0);
    }
  }
  k_uv<<<dim3(NP/32), dim3(256), 0, stream>>>(ws);
  k_edge<1><<<dim3(NP/64), dim3(512), 0, stream>>>(ws, (const int*)(ws + OFF_IDX1),
        OFF_U, OFF_V, WF_WDG2, WF_GDG1, WF_BDG1, WF_GDG2, WF_BDG2, OFF_HDG);
  k_w<<<dim3(NP/32), dim3(256), 0, stream>>>(ws);
  k_edge<0><<<dim3(NP/64), dim3(512), 0, stream>>>(ws, (const int*)(ws + OFF_IDX2),
        0, OFF_U, WF_WSN2, WF_GSN1, WF_BSN1, WF_GSN2, WF_BSN2, OFF_H2);
  k_h4<<<dim3(NP/64), dim3(256), 0, stream>>>(ws, ws + OFF_H4);
  k_conv5<<<dim3(NP/128, 4), dim3(256), 0, stream>>>(ws, d_out);
}

// Round 9
// 1023.132 us; speedup vs baseline: 1.5017x; 1.0047x over previous
//
#include <hip/hip_runtime.h>
#include <hip/hip_bf16.h>
#include <stdint.h>

typedef __hip_bfloat16 bf16;

#define N_   4096
#define NP   32768   // B*N
#define KNN  20

// ---- workspace layout (units: float) ----
#define OFF_H2   0L         // 32768*64 ; later reused as hsn output
#define OFF_XYZ  2097152L   // 3 planes of 32768 (SoA)
#define OFF_X    2097152L
#define OFF_Y    2129920L
#define OFF_Z    2162688L
#define OFF_XX   2195456L   // 32768  (|h2|^2); dead after pair loop ->
#define OFF_W2T  2195456L   //   reused: w2T-dg [kk][o] 4096 + w2T-sn 4096
#define OFF_XXC  2228224L   // 32768  (|x|^2)
#define OFF_IDX1 2260992L   // 32768*20 int
#define OFF_P4   2260992L   // AoS (x,y,z,|x|^2) 32768*4 floats; lives in the
                            // idx1 region: written by k_point, read by k_knn2,
                            // dead before the pair loop writes idx1 over it.
#define OFF_IDX2 2916352L   // 32768*20 int
#define OFF_WF   3571712L   // 104768 fp32 weights
#define OFF_FLAG 3676480L   // dtype flag (int), 64-float slot
#define OFF_PAIR 3676544L   // pair chunk lives here during kNN phase
// post-kNN reuse of the pair region:
#define OFF_U    3676544L   // 32768*64 ; u=(Wa-Wb)h2 ; later w = Wsn1*hdg
#define OFF_V    5773696L   // 32768*64 ; v = Wb*h2
#define OFF_HDG  7870848L   // 32768*64
#define OFF_H4   5773696L   // 128*32768 k-major; overlaps V+HDG (both dead by then)

// ---- fp32 weight bank offsets ----
#define WF_W1 0
#define WF_G1 192
#define WF_B1 256
#define WF_W2 320
#define WF_G2 4416
#define WF_B2 4480
#define WF_WDG1 4544
#define WF_GDG1 12736
#define WF_BDG1 12800
#define WF_WDG2 12864
#define WF_GDG2 16960
#define WF_BDG2 17024
#define WF_WSN1 17088
#define WF_GSN1 21184
#define WF_BSN1 21248
#define WF_WSN2 21312
#define WF_GSN2 25408
#define WF_BSN2 25472
#define WF_W3 25536
#define WF_G3 29632
#define WF_B3 29696
#define WF_W4 29760
#define WF_G4 37952
#define WF_B4 38080
#define WF_W5 38208
#define WF_G5 103744
#define WF_B5 104256
#define WF_END 104768

__device__ __forceinline__ float lrelu(float x){ return x >= 0.f ? x : 0.01f*x; }

// exact-deterministic distance: MUST be the single source for both fill and
// rescan in k_knn2 (bit-identical results required for ordering consistency)
__device__ __forceinline__ float distf(float xn,float yn,float zn,
                                       float xm,float ym,float zm,float cm){
  return fmaf(2.f, fmaf(xn,xm, fmaf(yn,ym, zn*zm)), -cm);
}

// DPP-step max; CTRL must be a compile-time constant -> template parameter.
template<int CTRL>
__device__ __forceinline__ float fmax_dpp(float v){
  int o = __builtin_amdgcn_update_dpp(0, __float_as_int(v), CTRL, 0xF, 0xF, true);
  return fmaxf(v, __int_as_float(o));
}
// Full-wave max returned as a wave-uniform scalar (SGPR broadcast).
// Pure DPP/VALU: xor1/xor2/ror4/ror8 give 16-lane row maxes; ROW_BCAST15
// (0x142) + ROW_BCAST31 (0x143) funnel the global max to lane 63; readlane
// broadcasts it. bound_ctrl=1 corrupts lanes 0-15 after bcast15 (fmax with
// 0.0) but those lanes are never on the dataflow path to lane 63.
__device__ __forceinline__ float wave_max_bcast(float v){
  v = fmax_dpp<0xB1>(v);    // quad_perm xor1
  v = fmax_dpp<0x4E>(v);    // quad_perm xor2
  v = fmax_dpp<0x124>(v);   // row_ror:4
  v = fmax_dpp<0x128>(v);   // row_ror:8  -> row max in all 16 lanes of a row
  v = fmax_dpp<0x142>(v);   // row_bcast15: 15->16..31, 47->48..63
  v = fmax_dpp<0x143>(v);   // row_bcast31: 31->32..63; lane 63 = global max
  return __int_as_float(__builtin_amdgcn_readlane(__float_as_int(v), 63));
}

// branchless insert of (c,m) into per-lane sorted top-2 (k1,i1) >= (k2,i2).
// strict > keeps the earlier (smaller-index) candidate ahead on ties.
__device__ __forceinline__ void ins2(float c, int m, float& k1, int& i1,
                                     float& k2, int& i2){
  bool g1 = c > k1, g2 = c > k2;
  k2 = g2 ? (g1 ? k1 : c) : k2;
  i2 = g2 ? (g1 ? i1 : m) : i2;
  k1 = g1 ? c : k1;
  i1 = g1 ? m : i1;
}

// Exact top-20 by iterative pop. Candidate m in 0..4095.
// MODE 0: owner lane js = m & 63,      ord = m >> 6          (lane-strided fill)
// MODE 1: owner lane js = (m>>2)&63,   ord = ((m>>8)<<2)|(m&3)
// Each lane holds its segment's best-2 unextracted candidates; pop promotes,
// rescan (rare, ~3/query) rebuilds via refetch(mre) which must be
// bit-consistent with fill values. In a rescan, lane scans its segment's
// candidate with ord == lane (both modes satisfy ord(mre(lane)) == lane).
template<int MODE, typename F>
__device__ __forceinline__ void topk_pairs(float k1, int i1, float k2, int i2,
                                           int lane, F&& refetch,
                                           int* __restrict__ outp){
  const float NEGINF = -__builtin_inff();
  uint32_t mlo = 0, mhi = 0;   // exclusion mask over MY segment's ords
  int keep = 0;
  #pragma unroll 1
  for (int tt = 0; tt < KNN; tt++){
    float g = wave_max_bcast(k1);
    uint64_t ball = __ballot(k1 == g);
    int js = __builtin_amdgcn_readfirstlane((int)(__ffsll((unsigned long long)ball) - 1));
    int wid = __builtin_amdgcn_readlane(i1, js);
    // dry check reads OLD k2 of js (== js's k1 after the pop below) so the
    // readlane doesn't serialize behind the cndmask updates.
    int kown = __builtin_amdgcn_readlane(__float_as_int(k2), js);
    if (lane == tt) keep = wid;
    bool own = (lane == js);
    // exclusion bit for wid (ord/bit are wave-uniform scalars)
    uint32_t ord = (MODE == 0) ? ((uint32_t)wid >> 6)
                               : ((((uint32_t)wid >> 8) << 2) | ((uint32_t)wid & 3u));
    uint32_t blo = (ord < 32u) ? (1u << ord) : 0u;
    uint32_t bhi = (ord >= 32u) ? (1u << (ord - 32u)) : 0u;
    mlo |= own ? blo : 0u;
    mhi |= own ? bhi : 0u;
    k1 = own ? k2 : k1;  i1 = own ? i2 : i1;
    k2 = own ? NEGINF : k2;
    // owner dry? (wave-uniform branch, rare)
    if (kown == (int)0xFF800000u){
      uint32_t mre = (MODE == 0)
        ? ((uint32_t)js + ((uint32_t)lane << 6))
        : ((((uint32_t)lane >> 2) << 8) | (((uint32_t)js) << 2) | ((uint32_t)lane & 3u));
      float v = refetch(mre);
      uint32_t bl = (uint32_t)__builtin_amdgcn_readlane((int)mlo, js);
      uint32_t bh = (uint32_t)__builtin_amdgcn_readlane((int)mhi, js);
      uint64_t bm = ((uint64_t)bh << 32) | bl;
      if ((bm >> lane) & 1ull) v = NEGINF;
      float g2 = wave_max_bcast(v);
      uint64_t b2 = __ballot(v == g2);
      int jw = (int)(__ffsll((unsigned long long)b2) - 1);
      uint32_t wm = (MODE == 0)
        ? ((uint32_t)js + ((uint32_t)jw << 6))
        : ((((uint32_t)jw >> 2) << 8) | (((uint32_t)js) << 2) | ((uint32_t)jw & 3u));
      if (lane == js){ k1 = g2; i1 = (int)wm; }
    }
  }
  if (lane < KNN) outp[lane] = keep;
}

// ---------------- K-1: dtype detect (1 = fp32 inputs, 0 = bf16) -------------
__global__ void k_detect(const void* __restrict__ x, int* __restrict__ flag){
  int lane = threadIdx.x;
  const bf16* xb = (const bf16*)x;
  int cnt = 0;
  #pragma unroll 1
  for (int i = lane; i < 256; i += 64){
    float v = __bfloat162float(xb[2*i]);
    float a = fabsf(v);
    if (a > 1e-3f && a < 100.f) cnt++;
  }
  #pragma unroll
  for (int off = 32; off; off >>= 1) cnt += __shfl_down(cnt, off, 64);
  if (lane == 0) *flag = (cnt >= 128) ? 0 : 1;
}

// ---------------- K0: convert all weights -> fp32 bank ----------------------
struct WPack {
  const void* p[27];
  int off[28];
};

__global__ void k_wcvt(WPack pk, float* __restrict__ dst, const int* __restrict__ flagp){
  int i = blockIdx.x*256 + threadIdx.x;
  if (i >= WF_END) return;
  int f = *flagp;
  #pragma unroll 1
  for (int s = 0; s < 27; s++){
    if (i < pk.off[s+1]){
      int j = i - pk.off[s];
      dst[i] = f ? ((const float*)pk.p[s])[j]
                 : __bfloat162float(((const bf16*)pk.p[s])[j]);
      return;
    }
  }
}

// ---------------- K0b: transpose W2 edge weights -> [kk][o] (for k_edge) ----
// Runs AFTER the pair loop (OFF_XX is dead then). bx=0: WDG2, bx=1: WSN2.
__global__ void k_wt(float* __restrict__ ws){
  const float* wf = ws + OFF_WF;
  int src = blockIdx.x ? WF_WSN2 : WF_WDG2;
  long dst = OFF_W2T + (long)blockIdx.x*4096;
  int t = threadIdx.x;
  #pragma unroll
  for (int i=t;i<4096;i+=256){
    int o = i >> 6, kk = i & 63;
    ws[dst + (long)kk*64 + o] = wf[src + o*64 + kk];
  }
}

// ---------------- K1: per-point MLP1+MLP2, norms, coords (SoA + AoS) --------
__global__ void k_point(const void* __restrict__ x, float* __restrict__ ws){
  const float* wf = ws + OFF_WF;
  int f = ((const int*)(ws + OFF_FLAG))[0];
  int n = blockIdx.x*256 + threadIdx.x;
  float x0, x1, x2;
  if (f){
    const float* xf = (const float*)x;
    x0 = xf[n*3+0]; x1 = xf[n*3+1]; x2 = xf[n*3+2];
  } else {
    const bf16* xb = (const bf16*)x;
    x0 = __bfloat162float(xb[n*3+0]);
    x1 = __bfloat162float(xb[n*3+1]);
    x2 = __bfloat162float(xb[n*3+2]);
  }

  float h1[64];
  #pragma unroll
  for (int o=0;o<64;o++){
    float a = wf[WF_W1+o*3+0]*x0 + wf[WF_W1+o*3+1]*x1 + wf[WF_W1+o*3+2]*x2;
    h1[o] = lrelu(wf[WF_G1+o]*a + wf[WF_B1+o]);
  }
  float xx = 0.f;
  #pragma unroll 1
  for (int o=0;o<64;o++){
    float a = 0.f;
    #pragma unroll
    for (int c=0;c<64;c++) a += wf[WF_W2+o*64+c]*h1[c];
    float h2 = lrelu(wf[WF_G2+o]*a + wf[WF_B2+o]);
    ws[OFF_H2 + (long)n*64 + o] = h2;
    xx += h2*h2;
  }
  ws[OFF_XX + n] = xx;
  float cc = x0*x0 + x1*x1 + x2*x2;
  ws[OFF_X + n] = x0; ws[OFF_Y + n] = x1; ws[OFF_Z + n] = x2;
  ws[OFF_XXC + n] = cc;
  *(float4*)(ws + OFF_P4 + 4L*n) = make_float4(x0, x1, x2, cc);
}

// ---------------- K2a: pair GEMM (fp32), per batch chunk --------------------
__global__ __launch_bounds__(256) void k_pair(const float* __restrict__ ws, float* __restrict__ pair,
                                              int b, int n0){
  __shared__ float As[64*128];
  __shared__ float Bs[64*128];
  int t = threadIdx.x;
  int bx = blockIdx.x, by = blockIdx.y;
  const float* h2 = ws + OFF_H2 + (long)b*N_*64;

  int r = t >> 1, c0 = (t & 1)*32;
  const float4* arow = (const float4*)(h2 + (long)(n0 + by*128 + r)*64 + c0);
  const float4* brow = (const float4*)(h2 + (long)(bx*128 + r)*64 + c0);
  #pragma unroll
  for (int q=0;q<8;q++){
    float4 av = arow[q];
    As[(c0+4*q+0)*128 + r] = av.x; As[(c0+4*q+1)*128 + r] = av.y;
    As[(c0+4*q+2)*128 + r] = av.z; As[(c0+4*q+3)*128 + r] = av.w;
    float4 bv = brow[q];
    Bs[(c0+4*q+0)*128 + r] = bv.x; Bs[(c0+4*q+1)*128 + r] = bv.y;
    Bs[(c0+4*q+2)*128 + r] = bv.z; Bs[(c0+4*q+3)*128 + r] = bv.w;
  }
  __syncthreads();

  int tr = t/16, tc = t%16;
  float acc[8][8] = {};
  #pragma unroll 4
  for (int k=0;k<64;k++){
    const float4* ap = (const float4*)&As[k*128 + tr*8];
    const float4* bp = (const float4*)&Bs[k*128 + tc*8];
    float4 a0 = ap[0], a1 = ap[1], c0v = bp[0], c1v = bp[1];
    float a[8] = {a0.x,a0.y,a0.z,a0.w,a1.x,a1.y,a1.z,a1.w};
    float c[8] = {c0v.x,c0v.y,c0v.z,c0v.w,c1v.x,c1v.y,c1v.z,c1v.w};
    #pragma unroll
    for (int i=0;i<8;i++)
      #pragma unroll
      for (int j=0;j<8;j++) acc[i][j] += a[i]*c[j];
  }
  const float* xxp = ws + OFF_XX + b*N_ + bx*128 + tc*8;
  float xxm[8];
  #pragma unroll
  for (int j=0;j<8;j++) xxm[j] = xxp[j];
  #pragma unroll
  for (int i=0;i<8;i++){
    long row = (long)(by*128 + tr*8 + i)*N_ + bx*128 + tc*8;
    float4 o0 = make_float4(2.f*acc[i][0]-xxm[0], 2.f*acc[i][1]-xxm[1],
                            2.f*acc[i][2]-xxm[2], 2.f*acc[i][3]-xxm[3]);
    float4 o1 = make_float4(2.f*acc[i][4]-xxm[4], 2.f*acc[i][5]-xxm[5],
                            2.f*acc[i][6]-xxm[6], 2.f*acc[i][7]-xxm[7]);
    ((float4*)(pair+row))[0] = o0;
    ((float4*)(pair+row))[1] = o1;
  }
}

// ---------------- K2b: top-20 over stored pair rows (pairs-pop, 4 rows/blk) -
__global__ __launch_bounds__(256) void k_topk_pair(const float* __restrict__ pair, int* __restrict__ idx1,
                                                   int b, int n0){
  int t = threadIdx.x;
  int lane = t & 63, wv = t >> 6;
  int r = blockIdx.x*4 + wv;
  const float* rowp = pair + (long)r*N_;
  const float4* src = (const float4*)rowp;
  float k1 = -__builtin_inff(), k2 = -__builtin_inff();
  int i1 = 0, i2 = 0;
  #pragma unroll
  for (int q=0;q<16;q++){
    float4 v = src[lane + 64*q];
    int m0 = 4*lane + 256*q;
    ins2(v.x, m0,   k1,i1,k2,i2);
    ins2(v.y, m0+1, k1,i1,k2,i2);
    ins2(v.z, m0+2, k1,i1,k2,i2);
    ins2(v.w, m0+3, k1,i1,k2,i2);
  }
  topk_pairs<1>(k1,i1,k2,i2, lane, [&](uint32_t mre){ return rowp[mre]; },
                idx1 + (long)(b*N_ + n0 + r)*KNN);
}

// ---------------- K3: coord-space kNN, LDS chunk-staged (8 queries/blk) -----
__global__ __launch_bounds__(512) void k_knn2(const float* __restrict__ ws, int* __restrict__ idx2){
  __shared__ float4 pbuf[2][512];
  int t = threadIdx.x;
  int lane = t & 63, wv = t >> 6;
  int n = blockIdx.x*8 + wv;
  int base = n & ~4095;
  const float4* P4 = (const float4*)(ws + OFF_P4);
  float4 qp = P4[n];
  float xn = qp.x, yn = qp.y, zn = qp.z;
  float k1 = -__builtin_inff(), k2 = -__builtin_inff();
  int i1 = 0, i2 = 0;

  pbuf[0][t] = P4[base + t];
  __syncthreads();
  #pragma unroll 1
  for (int c = 0; c < 8; c++){
    float4 nx;
    if (c < 7) nx = P4[base + (c+1)*512 + t];   // issue early; hides under compute
    const float4* pb = pbuf[c & 1];
    #pragma unroll
    for (int j = 0; j < 8; j++){
      float4 p = pb[lane + 64*j];
      int m = c*512 + 64*j + lane;              // m & 63 == lane  (MODE-0 segment)
      ins2(distf(xn,yn,zn, p.x,p.y,p.z,p.w), m, k1,i1,k2,i2);
    }
    __syncthreads();
    if (c < 7) pbuf[(c+1) & 1][t] = nx;
    __syncthreads();
  }
  topk_pairs<0>(k1,i1,k2,i2, lane, [&](uint32_t mre){
      float4 p = P4[base + (int)mre];
      return distf(xn,yn,zn, p.x, p.y, p.z, p.w);
    }, idx2 + (long)n*KNN);
}

// ---------------- K3b: u = (Wa-Wb)h2, v = Wb h2 (post-kNN) ------------------
// r7: 8 waves per 64-point group, wave-uniform 8-output slice; grid 1024.
__global__ __launch_bounds__(256) void k_uv(float* __restrict__ ws){
  const float* wf = ws + OFF_WF;
  int t = threadIdx.x;
  int lane = t & 63;
  int W = blockIdx.x*4 + (t >> 6);
  int g = __builtin_amdgcn_readfirstlane(W >> 3);
  int s = __builtin_amdgcn_readfirstlane(W & 7);
  int n = g*64 + lane;
  int o0 = s*8;
  float h[64];
  const float4* src = (const float4*)(ws + OFF_H2 + (long)n*64);
  #pragma unroll
  for (int q=0;q<16;q++){ float4 v = src[q]; h[4*q]=v.x; h[4*q+1]=v.y; h[4*q+2]=v.z; h[4*q+3]=v.w; }
  float ua[8], vv[8];
  #pragma unroll 1
  for (int j=0;j<8;j++){
    int o = o0 + j;
    float va=0.f, vb=0.f;
    #pragma unroll
    for (int c=0;c<64;c++){
      va += wf[WF_WDG1+o*128+c]*h[c];
      vb += wf[WF_WDG1+o*128+64+c]*h[c];
    }
    ua[j] = va - vb;
    vv[j] = vb;
  }
  float* up = ws + OFF_U + (long)n*64 + o0;
  *(float4*)up     = make_float4(ua[0],ua[1],ua[2],ua[3]);
  *(float4*)(up+4) = make_float4(ua[4],ua[5],ua[6],ua[7]);
  float* vp = ws + OFF_V + (long)n*64 + o0;
  *(float4*)vp     = make_float4(vv[0],vv[1],vv[2],vv[3]);
  *(float4*)(vp+4) = make_float4(vv[4],vv[5],vv[6],vv[7]);
}

// ---------------- K4/K5: edge stage (gathered first conv folded) ------------
// r8: LDS-pipe-bound fix. (1) W2 no longer staged in LDS: pre-transposed to
// [kk][o] in global (k_wt) and read as dwordx4 with 2 distinct lines/wave/kk
// -> 16KB L1-resident; removes the b128 from the LDS pipe (~half its cycles)
// and the 16KB staging preamble. (2) 2 neighbors per phase (y1a/y1b): halves
// barriers (40->20) and W2 re-reads. Max applied k-ascending -> bit-identical.
template<int USE_U>
__global__ __launch_bounds__(512) void k_edge(float* __restrict__ ws, const int* __restrict__ idxt,
      long uoff, long goff, long w2toff,
      int g1off, int b1off, int g2off, int b2off, long outoff){
  __shared__ float y1a[64*66];   // [channel][edge], row 66 (b64-aligned)
  __shared__ float y1b[64*66];
  __shared__ int   idxs[64*KNN];
  const float* wf = ws + OFF_WF;
  const float4* w2t = (const float4*)(ws + w2toff);   // [kk][o] as float4: kk*16+oc
  int t = threadIdx.x;
  int p0 = blockIdx.x*64;
  int b  = p0 >> 12;
  int lane = t & 63, wv = t >> 6;        // write phase: channel=lane, 8 edges/wave
  int tr = t & 31, oc = t >> 5;          // MAC: edges 2tr..2tr+1, outs 4oc..4oc+3

  #pragma unroll 1
  for (int i=t;i<64*KNN;i+=512) idxs[i] = idxt[(long)p0*KNN + i];

  // per-lane registers: u for my 8 edges (channel=lane), g1/b1, g2/b2
  float ur[8];
  if (USE_U){
    #pragma unroll
    for (int jj=0;jj<8;jj++)
      ur[jj] = ws[uoff + (long)(p0 + wv*8 + jj)*64 + lane];
  } else {
    #pragma unroll
    for (int jj=0;jj<8;jj++) ur[jj] = 0.f;
  }
  float g1v = wf[g1off+lane], b1v = wf[b1off+lane];
  float g2r[4], b2r[4];
  #pragma unroll
  for (int j=0;j<4;j++){ g2r[j] = wf[g2off+oc*4+j]; b2r[j] = wf[b2off+oc*4+j]; }

  float mx[2][4];
  #pragma unroll
  for (int i=0;i<2;i++)
    #pragma unroll
    for (int j=0;j<4;j++) mx[i][j] = -3.0e38f;

  __syncthreads();   // idxs ready

  long gbase = goff + ((long)b << 12)*64;
  float pfa[8], pfb[8];
  #pragma unroll
  for (int jj=0;jj<8;jj++){
    int e = wv*8 + jj;
    pfa[jj] = ws[gbase + (long)idxs[e*KNN + 0]*64 + lane];
    pfb[jj] = ws[gbase + (long)idxs[e*KNN + 1]*64 + lane];
  }

  for (int c=0;c<KNN/2;c++){
    // write phase: consume prefetched gathers for neighbors 2c, 2c+1
    #pragma unroll
    for (int jj=0;jj<8;jj++){
      int e = wv*8 + jj;
      float va = pfa[jj];
      float vb = pfb[jj];
      if (USE_U){ va += ur[jj]; vb += ur[jj]; }
      y1a[lane*66 + e] = lrelu(g1v*va + b1v);
      y1b[lane*66 + e] = lrelu(g1v*vb + b1v);
    }
    __syncthreads();
    // issue next-chunk gathers NOW; latency hides under the MAC loop below
    if (c+1 < KNN/2){
      #pragma unroll
      for (int jj=0;jj<8;jj++){
        int e = wv*8 + jj;
        pfa[jj] = ws[gbase + (long)idxs[e*KNN + 2*c+2]*64 + lane];
        pfb[jj] = ws[gbase + (long)idxs[e*KNN + 2*c+3]*64 + lane];
      }
    }
    float acca[2][4] = {}, accb[2][4] = {};
    #pragma unroll 4
    for (int kk=0;kk<64;kk++){
      float2 a  = *(const float2*)&y1a[kk*66 + tr*2];
      float2 bb = *(const float2*)&y1b[kk*66 + tr*2];
      float4 cv = w2t[kk*16 + oc];
      float av[2] = {a.x, a.y};
      float bv[2] = {bb.x, bb.y};
      float cvv[4] = {cv.x, cv.y, cv.z, cv.w};
      #pragma unroll
      for (int i=0;i<2;i++)
        #pragma unroll
        for (int j=0;j<4;j++){
          acca[i][j] += av[i]*cvv[j];
          accb[i][j] += bv[i]*cvv[j];
        }
    }
    #pragma unroll
    for (int i=0;i<2;i++)
      #pragma unroll
      for (int j=0;j<4;j++){
        mx[i][j] = fmaxf(mx[i][j], lrelu(g2r[j]*acca[i][j] + b2r[j]));
        mx[i][j] = fmaxf(mx[i][j], lrelu(g2r[j]*accb[i][j] + b2r[j]));
      }
    __syncthreads();
  }
  #pragma unroll
  for (int i=0;i<2;i++)
    #pragma unroll
    for (int j=0;j<4;j++)
      ws[outoff + (long)(p0 + tr*2 + i)*64 + oc*4 + j] = mx[i][j];
}

// ---------------- K4b: w = Wsn1 . hdg per point (stored raw) ----------------
// r7: same 8-slice-per-point restructure as k_uv.
__global__ __launch_bounds__(256) void k_w(float* __restrict__ ws){
  const float* wf = ws + OFF_WF;
  int t = threadIdx.x;
  int lane = t & 63;
  int W = blockIdx.x*4 + (t >> 6);
  int g = __builtin_amdgcn_readfirstlane(W >> 3);
  int s = __builtin_amdgcn_readfirstlane(W & 7);
  int n = g*64 + lane;
  int o0 = s*8;
  float h[64];
  const float4* src = (const float4*)(ws + OFF_HDG + (long)n*64);
  #pragma unroll
  for (int q=0;q<16;q++){ float4 v = src[q]; h[4*q]=v.x; h[4*q+1]=v.y; h[4*q+2]=v.z; h[4*q+3]=v.w; }
  float ua[8];
  #pragma unroll 1
  for (int j=0;j<8;j++){
    int o = o0 + j;
    float a = 0.f;
    #pragma unroll
    for (int c=0;c<64;c++) a += wf[WF_WSN1 + o*64 + c]*h[c];
    ua[j] = a;
  }
  float* up = ws + OFF_U + (long)n*64 + o0;
  *(float4*)up     = make_float4(ua[0],ua[1],ua[2],ua[3]);
  *(float4*)(up+4) = make_float4(ua[4],ua[5],ua[6],ua[7]);
}

// ---------------- K6a: head conv3+conv4, h4 out in k-major [128][NP] --------
__global__ __launch_bounds__(256) void k_h4(const float* __restrict__ ws, float* __restrict__ h4g){
  __shared__ float Hs[64*65];    // [ch][pt] (hsn), then reused as [o3][pt] (h3)
  __shared__ float wb[64*130];   // W3 as wb[c*65+o]; later W4 as wb[c*130+o]
  const float* wf = ws + OFF_WF;
  int t = threadIdx.x;
  int p0 = blockIdx.x*64;

  {
    int r = t >> 2, c0 = (t & 3)*16;
    const float4* src = (const float4*)(ws + OFF_H2 + (long)(p0 + r)*64 + c0);
    #pragma unroll
    for (int q=0;q<4;q++){
      float4 v = src[q];
      Hs[(c0+4*q+0)*65 + r] = v.x; Hs[(c0+4*q+1)*65 + r] = v.y;
      Hs[(c0+4*q+2)*65 + r] = v.z; Hs[(c0+4*q+3)*65 + r] = v.w;
    }
  }
  {
    int r = t >> 2, c0 = (t & 3)*16;
    const float4* src = (const float4*)(wf + WF_W3 + (long)r*64 + c0);
    #pragma unroll
    for (int q=0;q<4;q++){
      float4 v = src[q];
      wb[(c0+4*q+0)*65 + r] = v.x; wb[(c0+4*q+1)*65 + r] = v.y;
      wb[(c0+4*q+2)*65 + r] = v.z; wb[(c0+4*q+3)*65 + r] = v.w;
    }
  }
  __syncthreads();

  int pr = t & 15, og = t >> 4;
  float acc[4][4] = {};
  #pragma unroll 8
  for (int k=0;k<64;k++){
    float4 a = *(const float4*)&Hs[k*65 + pr*4];
    float4 c = *(const float4*)&wb[k*65 + og*4];
    float av[4] = {a.x,a.y,a.z,a.w}, cv[4] = {c.x,c.y,c.z,c.w};
    #pragma unroll
    for (int i=0;i<4;i++)
      #pragma unroll
      for (int j=0;j<4;j++) acc[i][j] += av[i]*cv[j];
  }
  __syncthreads();

  #pragma unroll
  for (int j=0;j<4;j++){
    int o = og*4 + j;
    float g3 = wf[WF_G3+o], b3 = wf[WF_B3+o];
    #pragma unroll
    for (int i=0;i<4;i++)
      Hs[o*65 + pr*4 + i] = lrelu(g3*acc[i][j] + b3);
  }
  {
    int r = t >> 1, c0 = (t & 1)*32;
    const float4* src = (const float4*)(wf + WF_W4 + (long)r*64 + c0);
    #pragma unroll
    for (int q=0;q<8;q++){
      float4 v = src[q];
      wb[(c0+4*q+0)*130 + r] = v.x; wb[(c0+4*q+1)*130 + r] = v.y;
      wb[(c0+4*q+2)*130 + r] = v.z; wb[(c0+4*q+3)*130 + r] = v.w;
    }
  }
  __syncthreads();

  float a2[4][8] = {};
  #pragma unroll 8
  for (int k=0;k<64;k++){
    float4 a = *(const float4*)&Hs[k*65 + pr*4];
    float4 c0 = *(const float4*)&wb[k*130 + og*8];
    float4 c1 = *(const float4*)&wb[k*130 + og*8 + 4];
    float av[4] = {a.x,a.y,a.z,a.w};
    float cv[8] = {c0.x,c0.y,c0.z,c0.w,c1.x,c1.y,c1.z,c1.w};
    #pragma unroll
    for (int i=0;i<4;i++)
      #pragma unroll
      for (int j=0;j<8;j++) a2[i][j] += av[i]*cv[j];
  }
  #pragma unroll
  for (int j=0;j<8;j++){
    int o = og*8 + j;
    float g4 = wf[WF_G4+o], b4 = wf[WF_B4+o];
    #pragma unroll
    for (int i=0;i<4;i++)
      h4g[(long)o*NP + p0 + pr*4 + i] = lrelu(g4*a2[i][j] + b4);
  }
}

// ---------------- K6b: conv5 GEMM [512 x 128] . [128 x NP] ------------------
#define KC 32
__global__ __launch_bounds__(256) void k_conv5(const float* __restrict__ ws, void* __restrict__ outv){
  __shared__ float As[KC*128];   // [k][o]
  __shared__ float Bs[KC*128];   // [k][pt]
  const float* wf = ws + OFF_WF;
  int f = ((const int*)(ws + OFF_FLAG))[0];
  int t = threadIdx.x;
  int p0 = blockIdx.x*128;
  int o0 = blockIdx.y*128;
  const float* H4 = ws + OFF_H4;
  float acc[8][8] = {};

  for (int kc = 0; kc < 128; kc += KC){
    {
      int r = t >> 1, c0 = (t & 1)*16;
      const float4* src = (const float4*)(wf + WF_W5 + (long)(o0 + r)*128 + kc + c0);
      #pragma unroll
      for (int q=0;q<4;q++){
        float4 v = src[q];
        As[(c0+4*q+0)*128 + r] = v.x; As[(c0+4*q+1)*128 + r] = v.y;
        As[(c0+4*q+2)*128 + r] = v.z; As[(c0+4*q+3)*128 + r] = v.w;
      }
    }
    {
      int kr = t >> 3, pc = (t & 7)*16;
      const float4* src = (const float4*)(H4 + (long)(kc + kr)*NP + p0 + pc);
      float4 v0 = src[0], v1 = src[1], v2 = src[2], v3 = src[3];
      *(float4*)&Bs[kr*128 + pc     ] = v0;
      *(float4*)&Bs[kr*128 + pc + 4 ] = v1;
      *(float4*)&Bs[kr*128 + pc + 8 ] = v2;
      *(float4*)&Bs[kr*128 + pc + 12] = v3;
    }
    __syncthreads();
    int tr = t/16, tc = t%16;
    #pragma unroll 8
    for (int k=0;k<KC;k++){
      const float4* ap = (const float4*)&As[k*128 + tr*8];
      const float4* bp = (const float4*)&Bs[k*128 + tc*8];
      float4 a0 = ap[0], a1 = ap[1], b0 = bp[0], b1 = bp[1];
      float a[8] = {a0.x,a0.y,a0.z,a0.w,a1.x,a1.y,a1.z,a1.w};
      float b[8] = {b0.x,b0.y,b0.z,b0.w,b1.x,b1.y,b1.z,b1.w};
      #pragma unroll
      for (int i=0;i<8;i++)
        #pragma unroll
        for (int j=0;j<8;j++) acc[i][j] += a[i]*b[j];
    }
    __syncthreads();
  }

  int tr = t/16, tc = t%16;
  int b = p0 >> 12, nn = (p0 & 4095) + tc*8;
  #pragma unroll
  for (int i=0;i<8;i++){
    int oo = o0 + tr*8 + i;
    float g5 = wf[WF_G5+oo], b5 = wf[WF_B5+oo];
    long base = ((long)(b*512 + oo) << 12) + nn;
    if (f){
      float4 v0 = make_float4(lrelu(g5*acc[i][0]+b5), lrelu(g5*acc[i][1]+b5),
                              lrelu(g5*acc[i][2]+b5), lrelu(g5*acc[i][3]+b5));
      float4 v1 = make_float4(lrelu(g5*acc[i][4]+b5), lrelu(g5*acc[i][5]+b5),
                              lrelu(g5*acc[i][6]+b5), lrelu(g5*acc[i][7]+b5));
      *(float4*)((float*)outv + base)     = v0;
      *(float4*)((float*)outv + base + 4) = v1;
    } else {
      #pragma unroll
      for (int j=0;j<8;j++)
        ((bf16*)outv)[base + j] = __float2bfloat16(lrelu(g5*acc[i][j] + b5));
    }
  }
}

// ---------------- host ------------------------------------------------------
extern "C" void kernel_launch(void* const* d_in, const int* in_sizes, int n_in,
                              void* d_out, int out_size, void* d_ws, size_t ws_size,
                              hipStream_t stream) {
  const void* X = d_in[0];
  float* ws = (float*)d_ws;
  int* flagp = (int*)(ws + OFF_FLAG);

  WPack pk;
  static const int wsz[27] = {192,64,64, 4096,64,64, 8192,64,64, 4096,64,64, 4096,64,64,
                              4096,64,64, 4096,64,64, 8192,128,128, 65536,512,512};
  int off = 0;
  for (int i=0;i<27;i++){ pk.p[i] = d_in[i+1]; pk.off[i] = off; off += wsz[i]; }
  pk.off[27] = off;

  k_detect<<<dim3(1), dim3(64), 0, stream>>>(X, flagp);
  k_wcvt<<<dim3((WF_END+255)/256), dim3(256), 0, stream>>>(pk, ws + OFF_WF, flagp);
  k_point<<<dim3(NP/256), dim3(256), 0, stream>>>(X, ws);
  k_knn2<<<dim3(NP/8), dim3(512), 0, stream>>>(ws, (int*)(ws + OFF_IDX2));

  long availf = (long)(ws_size/4) - OFF_PAIR;
  int chunk = 4096;
  if (availf < (long)N_*N_){
    long c = (availf / N_) & ~127L;
    chunk = (int)(c < 128 ? 128 : c);
    if (chunk > 4096) chunk = 4096;
  }
  for (int b=0;b<8;b++){
    for (int n0=0;n0<N_; n0+=chunk){
      int rows = (N_ - n0 < chunk) ? (N_ - n0) : chunk;
      k_pair<<<dim3(32, rows/128), dim3(256), 0, stream>>>(ws, ws + OFF_PAIR, b, n0);
      k_topk_pair<<<dim3(rows/4), dim3(256), 0, stream>>>(ws + OFF_PAIR, (int*)(ws + OFF_IDX1), b, n0);
    }
  }
  k_wt<<<dim3(2), dim3(256), 0, stream>>>(ws);   // OFF_XX dead now; w2T for k_edge
  k_uv<<<dim3(NP/32), dim3(256), 0, stream>>>(ws);
  k_edge<1><<<dim3(NP/64), dim3(512), 0, stream>>>(ws, (const int*)(ws + OFF_IDX1),
        OFF_U, OFF_V, OFF_W2T, WF_GDG1, WF_BDG1, WF_GDG2, WF_BDG2, OFF_HDG);
  k_w<<<dim3(NP/32), dim3(256), 0, stream>>>(ws);
  k_edge<0><<<dim3(NP/64), dim3(512), 0, stream>>>(ws, (const int*)(ws + OFF_IDX2),
        0, OFF_U, OFF_W2T + 4096, WF_GSN1, WF_BSN1, WF_GSN2, WF_BSN2, OFF_H2);
  k_h4<<<dim3(NP/64), dim3(256), 0, stream>>>(ws, ws + OFF_H4);
  k_conv5<<<dim3(NP/128, 4), dim3(256), 0, stream>>>(ws, d_out);
}

// Round 10
// 1005.712 us; speedup vs baseline: 1.5277x; 1.0173x over previous
//
#include <hip/hip_runtime.h>
#include <hip/hip_bf16.h>
#include <stdint.h>

typedef __hip_bfloat16 bf16;

#define N_   4096
#define NP   32768   // B*N
#define KNN  20

// ---- workspace layout (units: float) ----
#define OFF_H2   0L         // 32768*64 ; later reused as hsn output
#define OFF_XYZ  2097152L   // 3 planes of 32768 (SoA)
#define OFF_X    2097152L
#define OFF_Y    2129920L
#define OFF_Z    2162688L
#define OFF_XX   2195456L   // 32768  (|h2|^2); dead after pair loop ->
#define OFF_W2T  2195456L   //   reused: w2T-dg [kk][o] 4096 + w2T-sn 4096
#define OFF_XXC  2228224L   // 32768  (|x|^2)
#define OFF_IDX1 2260992L   // 32768*20 int
#define OFF_P4   2260992L   // AoS (x,y,z,|x|^2) 32768*4 floats; lives in the
                            // idx1 region: written by k_point, read by k_knn2,
                            // dead before the pair loop writes idx1 over it.
#define OFF_IDX2 2916352L   // 32768*20 int
#define OFF_WF   3571712L   // 104768 fp32 weights
#define OFF_FLAG 3676480L   // dtype flag (int), 64-float slot
#define OFF_PAIR 3676544L   // pair chunk lives here during kNN phase
// post-kNN reuse of the pair region:
#define OFF_U    3676544L   // 32768*64 ; u=(Wa-Wb)h2 ; later w = Wsn1*hdg
#define OFF_V    5773696L   // 32768*64 ; v = Wb*h2
#define OFF_HDG  7870848L   // 32768*64
#define OFF_H4   5773696L   // 128*32768 k-major; overlaps V+HDG (both dead by then)

// ---- fp32 weight bank offsets ----
#define WF_W1 0
#define WF_G1 192
#define WF_B1 256
#define WF_W2 320
#define WF_G2 4416
#define WF_B2 4480
#define WF_WDG1 4544
#define WF_GDG1 12736
#define WF_BDG1 12800
#define WF_WDG2 12864
#define WF_GDG2 16960
#define WF_BDG2 17024
#define WF_WSN1 17088
#define WF_GSN1 21184
#define WF_BSN1 21248
#define WF_WSN2 21312
#define WF_GSN2 25408
#define WF_BSN2 25472
#define WF_W3 25536
#define WF_G3 29632
#define WF_B3 29696
#define WF_W4 29760
#define WF_G4 37952
#define WF_B4 38080
#define WF_W5 38208
#define WF_G5 103744
#define WF_B5 104256
#define WF_END 104768

__device__ __forceinline__ float lrelu(float x){ return x >= 0.f ? x : 0.01f*x; }

// exact-deterministic distance: MUST be the single source for both fill and
// rescan in k_knn2 (bit-identical results required for ordering consistency)
__device__ __forceinline__ float distf(float xn,float yn,float zn,
                                       float xm,float ym,float zm,float cm){
  return fmaf(2.f, fmaf(xn,xm, fmaf(yn,ym, zn*zm)), -cm);
}

// DPP-step max; CTRL must be a compile-time constant -> template parameter.
template<int CTRL>
__device__ __forceinline__ float fmax_dpp(float v){
  int o = __builtin_amdgcn_update_dpp(0, __float_as_int(v), CTRL, 0xF, 0xF, true);
  return fmaxf(v, __int_as_float(o));
}
// Full-wave max returned as a wave-uniform scalar (SGPR broadcast).
// Pure DPP/VALU: xor1/xor2/ror4/ror8 give 16-lane row maxes; ROW_BCAST15
// (0x142) + ROW_BCAST31 (0x143) funnel the global max to lane 63; readlane
// broadcasts it. bound_ctrl=1 corrupts lanes 0-15 after bcast15 (fmax with
// 0.0) but those lanes are never on the dataflow path to lane 63.
__device__ __forceinline__ float wave_max_bcast(float v){
  v = fmax_dpp<0xB1>(v);    // quad_perm xor1
  v = fmax_dpp<0x4E>(v);    // quad_perm xor2
  v = fmax_dpp<0x124>(v);   // row_ror:4
  v = fmax_dpp<0x128>(v);   // row_ror:8  -> row max in all 16 lanes of a row
  v = fmax_dpp<0x142>(v);   // row_bcast15: 15->16..31, 47->48..63
  v = fmax_dpp<0x143>(v);   // row_bcast31: 31->32..63; lane 63 = global max
  return __int_as_float(__builtin_amdgcn_readlane(__float_as_int(v), 63));
}

// branchless insert of (c,m) into per-lane sorted top-2 (k1,i1) >= (k2,i2).
// strict > keeps the earlier (smaller-index) candidate ahead on ties.
__device__ __forceinline__ void ins2(float c, int m, float& k1, int& i1,
                                     float& k2, int& i2){
  bool g1 = c > k1, g2 = c > k2;
  k2 = g2 ? (g1 ? k1 : c) : k2;
  i2 = g2 ? (g1 ? i1 : m) : i2;
  k1 = g1 ? c : k1;
  i1 = g1 ? m : i1;
}

// Exact top-20 by iterative pop. Candidate m in 0..4095.
// MODE 0: owner lane js = m & 63,      ord = m >> 6          (lane-strided fill)
// MODE 1: owner lane js = (m>>2)&63,   ord = ((m>>8)<<2)|(m&3)
// Each lane holds its segment's best-2 unextracted candidates; pop promotes,
// rescan (rare, ~3/query) rebuilds via refetch(mre) which must be
// bit-consistent with fill values. In a rescan, lane scans its segment's
// candidate with ord == lane (both modes satisfy ord(mre(lane)) == lane).
template<int MODE, typename F>
__device__ __forceinline__ void topk_pairs(float k1, int i1, float k2, int i2,
                                           int lane, F&& refetch,
                                           int* __restrict__ outp){
  const float NEGINF = -__builtin_inff();
  uint32_t mlo = 0, mhi = 0;   // exclusion mask over MY segment's ords
  int keep = 0;
  #pragma unroll 1
  for (int tt = 0; tt < KNN; tt++){
    float g = wave_max_bcast(k1);
    uint64_t ball = __ballot(k1 == g);
    int js = __builtin_amdgcn_readfirstlane((int)(__ffsll((unsigned long long)ball) - 1));
    int wid = __builtin_amdgcn_readlane(i1, js);
    // dry check reads OLD k2 of js (== js's k1 after the pop below) so the
    // readlane doesn't serialize behind the cndmask updates.
    int kown = __builtin_amdgcn_readlane(__float_as_int(k2), js);
    if (lane == tt) keep = wid;
    bool own = (lane == js);
    // exclusion bit for wid (ord/bit are wave-uniform scalars)
    uint32_t ord = (MODE == 0) ? ((uint32_t)wid >> 6)
                               : ((((uint32_t)wid >> 8) << 2) | ((uint32_t)wid & 3u));
    uint32_t blo = (ord < 32u) ? (1u << ord) : 0u;
    uint32_t bhi = (ord >= 32u) ? (1u << (ord - 32u)) : 0u;
    mlo |= own ? blo : 0u;
    mhi |= own ? bhi : 0u;
    k1 = own ? k2 : k1;  i1 = own ? i2 : i1;
    k2 = own ? NEGINF : k2;
    // owner dry? (wave-uniform branch, rare)
    if (kown == (int)0xFF800000u){
      uint32_t mre = (MODE == 0)
        ? ((uint32_t)js + ((uint32_t)lane << 6))
        : ((((uint32_t)lane >> 2) << 8) | (((uint32_t)js) << 2) | ((uint32_t)lane & 3u));
      float v = refetch(mre);
      uint32_t bl = (uint32_t)__builtin_amdgcn_readlane((int)mlo, js);
      uint32_t bh = (uint32_t)__builtin_amdgcn_readlane((int)mhi, js);
      uint64_t bm = ((uint64_t)bh << 32) | bl;
      if ((bm >> lane) & 1ull) v = NEGINF;
      float g2 = wave_max_bcast(v);
      uint64_t b2 = __ballot(v == g2);
      int jw = (int)(__ffsll((unsigned long long)b2) - 1);
      uint32_t wm = (MODE == 0)
        ? ((uint32_t)js + ((uint32_t)jw << 6))
        : ((((uint32_t)jw >> 2) << 8) | (((uint32_t)js) << 2) | ((uint32_t)jw & 3u));
      if (lane == js){ k1 = g2; i1 = (int)wm; }
    }
  }
  if (lane < KNN) outp[lane] = keep;
}

// ---------------- K-1: dtype detect (1 = fp32 inputs, 0 = bf16) -------------
__global__ void k_detect(const void* __restrict__ x, int* __restrict__ flag){
  int lane = threadIdx.x;
  const bf16* xb = (const bf16*)x;
  int cnt = 0;
  #pragma unroll 1
  for (int i = lane; i < 256; i += 64){
    float v = __bfloat162float(xb[2*i]);
    float a = fabsf(v);
    if (a > 1e-3f && a < 100.f) cnt++;
  }
  #pragma unroll
  for (int off = 32; off; off >>= 1) cnt += __shfl_down(cnt, off, 64);
  if (lane == 0) *flag = (cnt >= 128) ? 0 : 1;
}

// ---------------- K0: convert all weights -> fp32 bank ----------------------
struct WPack {
  const void* p[27];
  int off[28];
};

__global__ void k_wcvt(WPack pk, float* __restrict__ dst, const int* __restrict__ flagp){
  int i = blockIdx.x*256 + threadIdx.x;
  if (i >= WF_END) return;
  int f = *flagp;
  #pragma unroll 1
  for (int s = 0; s < 27; s++){
    if (i < pk.off[s+1]){
      int j = i - pk.off[s];
      dst[i] = f ? ((const float*)pk.p[s])[j]
                 : __bfloat162float(((const bf16*)pk.p[s])[j]);
      return;
    }
  }
}

// ---------------- K0b: transpose W2 edge weights -> [kk][o] (for k_edge) ----
// Runs AFTER the pair loop (OFF_XX is dead then). bx=0: WDG2, bx=1: WSN2.
__global__ void k_wt(float* __restrict__ ws){
  const float* wf = ws + OFF_WF;
  int src = blockIdx.x ? WF_WSN2 : WF_WDG2;
  long dst = OFF_W2T + (long)blockIdx.x*4096;
  int t = threadIdx.x;
  #pragma unroll
  for (int i=t;i<4096;i+=256){
    int o = i >> 6, kk = i & 63;
    ws[dst + (long)kk*64 + o] = wf[src + o*64 + kk];
  }
}

// ---------------- K1: per-point MLP1+MLP2, norms, coords (SoA + AoS) --------
__global__ void k_point(const void* __restrict__ x, float* __restrict__ ws){
  const float* wf = ws + OFF_WF;
  int f = ((const int*)(ws + OFF_FLAG))[0];
  int n = blockIdx.x*256 + threadIdx.x;
  float x0, x1, x2;
  if (f){
    const float* xf = (const float*)x;
    x0 = xf[n*3+0]; x1 = xf[n*3+1]; x2 = xf[n*3+2];
  } else {
    const bf16* xb = (const bf16*)x;
    x0 = __bfloat162float(xb[n*3+0]);
    x1 = __bfloat162float(xb[n*3+1]);
    x2 = __bfloat162float(xb[n*3+2]);
  }

  float h1[64];
  #pragma unroll
  for (int o=0;o<64;o++){
    float a = wf[WF_W1+o*3+0]*x0 + wf[WF_W1+o*3+1]*x1 + wf[WF_W1+o*3+2]*x2;
    h1[o] = lrelu(wf[WF_G1+o]*a + wf[WF_B1+o]);
  }
  float xx = 0.f;
  #pragma unroll 1
  for (int o=0;o<64;o++){
    float a = 0.f;
    #pragma unroll
    for (int c=0;c<64;c++) a += wf[WF_W2+o*64+c]*h1[c];
    float h2 = lrelu(wf[WF_G2+o]*a + wf[WF_B2+o]);
    ws[OFF_H2 + (long)n*64 + o] = h2;
    xx += h2*h2;
  }
  ws[OFF_XX + n] = xx;
  float cc = x0*x0 + x1*x1 + x2*x2;
  ws[OFF_X + n] = x0; ws[OFF_Y + n] = x1; ws[OFF_Z + n] = x2;
  ws[OFF_XXC + n] = cc;
  *(float4*)(ws + OFF_P4 + 4L*n) = make_float4(x0, x1, x2, cc);
}

// ---------------- K2a: pair GEMM (fp32), per batch chunk --------------------
__global__ __launch_bounds__(256) void k_pair(const float* __restrict__ ws, float* __restrict__ pair,
                                              int b, int n0){
  __shared__ float As[64*128];
  __shared__ float Bs[64*128];
  int t = threadIdx.x;
  int bx = blockIdx.x, by = blockIdx.y;
  const float* h2 = ws + OFF_H2 + (long)b*N_*64;

  int r = t >> 1, c0 = (t & 1)*32;
  const float4* arow = (const float4*)(h2 + (long)(n0 + by*128 + r)*64 + c0);
  const float4* brow = (const float4*)(h2 + (long)(bx*128 + r)*64 + c0);
  #pragma unroll
  for (int q=0;q<8;q++){
    float4 av = arow[q];
    As[(c0+4*q+0)*128 + r] = av.x; As[(c0+4*q+1)*128 + r] = av.y;
    As[(c0+4*q+2)*128 + r] = av.z; As[(c0+4*q+3)*128 + r] = av.w;
    float4 bv = brow[q];
    Bs[(c0+4*q+0)*128 + r] = bv.x; Bs[(c0+4*q+1)*128 + r] = bv.y;
    Bs[(c0+4*q+2)*128 + r] = bv.z; Bs[(c0+4*q+3)*128 + r] = bv.w;
  }
  __syncthreads();

  int tr = t/16, tc = t%16;
  float acc[8][8] = {};
  #pragma unroll 4
  for (int k=0;k<64;k++){
    const float4* ap = (const float4*)&As[k*128 + tr*8];
    const float4* bp = (const float4*)&Bs[k*128 + tc*8];
    float4 a0 = ap[0], a1 = ap[1], c0v = bp[0], c1v = bp[1];
    float a[8] = {a0.x,a0.y,a0.z,a0.w,a1.x,a1.y,a1.z,a1.w};
    float c[8] = {c0v.x,c0v.y,c0v.z,c0v.w,c1v.x,c1v.y,c1v.z,c1v.w};
    #pragma unroll
    for (int i=0;i<8;i++)
      #pragma unroll
      for (int j=0;j<8;j++) acc[i][j] += a[i]*c[j];
  }
  const float* xxp = ws + OFF_XX + b*N_ + bx*128 + tc*8;
  float xxm[8];
  #pragma unroll
  for (int j=0;j<8;j++) xxm[j] = xxp[j];
  #pragma unroll
  for (int i=0;i<8;i++){
    long row = (long)(by*128 + tr*8 + i)*N_ + bx*128 + tc*8;
    float4 o0 = make_float4(2.f*acc[i][0]-xxm[0], 2.f*acc[i][1]-xxm[1],
                            2.f*acc[i][2]-xxm[2], 2.f*acc[i][3]-xxm[3]);
    float4 o1 = make_float4(2.f*acc[i][4]-xxm[4], 2.f*acc[i][5]-xxm[5],
                            2.f*acc[i][6]-xxm[6], 2.f*acc[i][7]-xxm[7]);
    ((float4*)(pair+row))[0] = o0;
    ((float4*)(pair+row))[1] = o1;
  }
}

// ---------------- K2b: top-20 over stored pair rows (pairs-pop, 4 rows/blk) -
__global__ __launch_bounds__(256) void k_topk_pair(const float* __restrict__ pair, int* __restrict__ idx1,
                                                   int b, int n0){
  int t = threadIdx.x;
  int lane = t & 63, wv = t >> 6;
  int r = blockIdx.x*4 + wv;
  const float* rowp = pair + (long)r*N_;
  const float4* src = (const float4*)rowp;
  float k1 = -__builtin_inff(), k2 = -__builtin_inff();
  int i1 = 0, i2 = 0;
  #pragma unroll
  for (int q=0;q<16;q++){
    float4 v = src[lane + 64*q];
    int m0 = 4*lane + 256*q;
    ins2(v.x, m0,   k1,i1,k2,i2);
    ins2(v.y, m0+1, k1,i1,k2,i2);
    ins2(v.z, m0+2, k1,i1,k2,i2);
    ins2(v.w, m0+3, k1,i1,k2,i2);
  }
  topk_pairs<1>(k1,i1,k2,i2, lane, [&](uint32_t mre){ return rowp[mre]; },
                idx1 + (long)(b*N_ + n0 + r)*KNN);
}

// ---------------- K3: coord-space kNN, LDS chunk-staged (8 queries/blk) -----
__global__ __launch_bounds__(512) void k_knn2(const float* __restrict__ ws, int* __restrict__ idx2){
  __shared__ float4 pbuf[2][512];
  int t = threadIdx.x;
  int lane = t & 63, wv = t >> 6;
  int n = blockIdx.x*8 + wv;
  int base = n & ~4095;
  const float4* P4 = (const float4*)(ws + OFF_P4);
  float4 qp = P4[n];
  float xn = qp.x, yn = qp.y, zn = qp.z;
  float k1 = -__builtin_inff(), k2 = -__builtin_inff();
  int i1 = 0, i2 = 0;

  pbuf[0][t] = P4[base + t];
  __syncthreads();
  #pragma unroll 1
  for (int c = 0; c < 8; c++){
    float4 nx;
    if (c < 7) nx = P4[base + (c+1)*512 + t];   // issue early; hides under compute
    const float4* pb = pbuf[c & 1];
    #pragma unroll
    for (int j = 0; j < 8; j++){
      float4 p = pb[lane + 64*j];
      int m = c*512 + 64*j + lane;              // m & 63 == lane  (MODE-0 segment)
      ins2(distf(xn,yn,zn, p.x,p.y,p.z,p.w), m, k1,i1,k2,i2);
    }
    __syncthreads();
    if (c < 7) pbuf[(c+1) & 1][t] = nx;
    __syncthreads();
  }
  topk_pairs<0>(k1,i1,k2,i2, lane, [&](uint32_t mre){
      float4 p = P4[base + (int)mre];
      return distf(xn,yn,zn, p.x, p.y, p.z, p.w);
    }, idx2 + (long)n*KNN);
}

// ---------------- K3b: u = (Wa-Wb)h2, v = Wb h2 (post-kNN) ------------------
// r7: 8 waves per 64-point group, wave-uniform 8-output slice; grid 1024.
__global__ __launch_bounds__(256) void k_uv(float* __restrict__ ws){
  const float* wf = ws + OFF_WF;
  int t = threadIdx.x;
  int lane = t & 63;
  int W = blockIdx.x*4 + (t >> 6);
  int g = __builtin_amdgcn_readfirstlane(W >> 3);
  int s = __builtin_amdgcn_readfirstlane(W & 7);
  int n = g*64 + lane;
  int o0 = s*8;
  float h[64];
  const float4* src = (const float4*)(ws + OFF_H2 + (long)n*64);
  #pragma unroll
  for (int q=0;q<16;q++){ float4 v = src[q]; h[4*q]=v.x; h[4*q+1]=v.y; h[4*q+2]=v.z; h[4*q+3]=v.w; }
  float ua[8], vv[8];
  #pragma unroll 1
  for (int j=0;j<8;j++){
    int o = o0 + j;
    float va=0.f, vb=0.f;
    #pragma unroll
    for (int c=0;c<64;c++){
      va += wf[WF_WDG1+o*128+c]*h[c];
      vb += wf[WF_WDG1+o*128+64+c]*h[c];
    }
    ua[j] = va - vb;
    vv[j] = vb;
  }
  float* up = ws + OFF_U + (long)n*64 + o0;
  *(float4*)up     = make_float4(ua[0],ua[1],ua[2],ua[3]);
  *(float4*)(up+4) = make_float4(ua[4],ua[5],ua[6],ua[7]);
  float* vp = ws + OFF_V + (long)n*64 + o0;
  *(float4*)vp     = make_float4(vv[0],vv[1],vv[2],vv[3]);
  *(float4*)(vp+4) = make_float4(vv[4],vv[5],vv[6],vv[7]);
}

// ---------------- K4/K5: edge stage (gathered first conv folded) ------------
// r9: 4 neighbors per phase (5 phases, 10 barriers vs 20): per kk the thread
// does 4 ds_read_b64 + 1 global dwordx4 + 32 FMA — per-kk overhead (w2t addr,
// loop inc) amortizes over 2x FMA, w2t loads per FMA halve. Max applied in
// ascending-k order -> bit-identical. LDS 72.7KB -> still 2 blocks/CU.
template<int USE_U>
__global__ __launch_bounds__(512) void k_edge(float* __restrict__ ws, const int* __restrict__ idxt,
      long uoff, long goff, long w2toff,
      int g1off, int b1off, int g2off, int b2off, long outoff){
  __shared__ float y1a[64*66];   // [channel][edge], row 66 (b64-aligned)
  __shared__ float y1b[64*66];
  __shared__ float y1c[64*66];
  __shared__ float y1d[64*66];
  __shared__ int   idxs[64*KNN];
  const float* wf = ws + OFF_WF;
  const float4* w2t = (const float4*)(ws + w2toff);   // [kk][o] as float4: kk*16+oc
  int t = threadIdx.x;
  int p0 = blockIdx.x*64;
  int b  = p0 >> 12;
  int lane = t & 63, wv = t >> 6;        // write phase: channel=lane, 8 edges/wave
  int tr = t & 31, oc = t >> 5;          // MAC: edges 2tr..2tr+1, outs 4oc..4oc+3

  #pragma unroll 1
  for (int i=t;i<64*KNN;i+=512) idxs[i] = idxt[(long)p0*KNN + i];

  // per-lane registers: u for my 8 edges (channel=lane), g1/b1, g2/b2
  float ur[8];
  if (USE_U){
    #pragma unroll
    for (int jj=0;jj<8;jj++)
      ur[jj] = ws[uoff + (long)(p0 + wv*8 + jj)*64 + lane];
  } else {
    #pragma unroll
    for (int jj=0;jj<8;jj++) ur[jj] = 0.f;
  }
  float g1v = wf[g1off+lane], b1v = wf[b1off+lane];
  float g2r[4], b2r[4];
  #pragma unroll
  for (int j=0;j<4;j++){ g2r[j] = wf[g2off+oc*4+j]; b2r[j] = wf[b2off+oc*4+j]; }

  float mx[2][4];
  #pragma unroll
  for (int i=0;i<2;i++)
    #pragma unroll
    for (int j=0;j<4;j++) mx[i][j] = -3.0e38f;

  __syncthreads();   // idxs ready

  long gbase = goff + ((long)b << 12)*64;
  float pfa[8], pfb[8], pfc[8], pfd[8];
  #pragma unroll
  for (int jj=0;jj<8;jj++){
    int e = wv*8 + jj;
    pfa[jj] = ws[gbase + (long)idxs[e*KNN + 0]*64 + lane];
    pfb[jj] = ws[gbase + (long)idxs[e*KNN + 1]*64 + lane];
    pfc[jj] = ws[gbase + (long)idxs[e*KNN + 2]*64 + lane];
    pfd[jj] = ws[gbase + (long)idxs[e*KNN + 3]*64 + lane];
  }

  for (int c=0;c<KNN/4;c++){
    // write phase: consume prefetched gathers for neighbors 4c..4c+3
    #pragma unroll
    for (int jj=0;jj<8;jj++){
      int e = wv*8 + jj;
      float va = pfa[jj], vb = pfb[jj], vc = pfc[jj], vd = pfd[jj];
      if (USE_U){ va += ur[jj]; vb += ur[jj]; vc += ur[jj]; vd += ur[jj]; }
      y1a[lane*66 + e] = lrelu(g1v*va + b1v);
      y1b[lane*66 + e] = lrelu(g1v*vb + b1v);
      y1c[lane*66 + e] = lrelu(g1v*vc + b1v);
      y1d[lane*66 + e] = lrelu(g1v*vd + b1v);
    }
    __syncthreads();
    // issue next-chunk gathers NOW; latency hides under the MAC loop below
    if (c+1 < KNN/4){
      #pragma unroll
      for (int jj=0;jj<8;jj++){
        int e = wv*8 + jj;
        pfa[jj] = ws[gbase + (long)idxs[e*KNN + 4*c+4]*64 + lane];
        pfb[jj] = ws[gbase + (long)idxs[e*KNN + 4*c+5]*64 + lane];
        pfc[jj] = ws[gbase + (long)idxs[e*KNN + 4*c+6]*64 + lane];
        pfd[jj] = ws[gbase + (long)idxs[e*KNN + 4*c+7]*64 + lane];
      }
    }
    float acca[2][4] = {}, accb[2][4] = {}, accc[2][4] = {}, accd[2][4] = {};
    #pragma unroll 2
    for (int kk=0;kk<64;kk++){
      float2 a  = *(const float2*)&y1a[kk*66 + tr*2];
      float2 bb = *(const float2*)&y1b[kk*66 + tr*2];
      float2 cc = *(const float2*)&y1c[kk*66 + tr*2];
      float2 dd = *(const float2*)&y1d[kk*66 + tr*2];
      float4 cv = w2t[kk*16 + oc];
      float av[2] = {a.x, a.y};
      float bv[2] = {bb.x, bb.y};
      float cvv2[2] = {cc.x, cc.y};
      float dv[2] = {dd.x, dd.y};
      float wvv[4] = {cv.x, cv.y, cv.z, cv.w};
      #pragma unroll
      for (int i=0;i<2;i++)
        #pragma unroll
        for (int j=0;j<4;j++){
          acca[i][j] += av[i]*wvv[j];
          accb[i][j] += bv[i]*wvv[j];
          accc[i][j] += cvv2[i]*wvv[j];
          accd[i][j] += dv[i]*wvv[j];
        }
    }
    #pragma unroll
    for (int i=0;i<2;i++)
      #pragma unroll
      for (int j=0;j<4;j++){
        mx[i][j] = fmaxf(mx[i][j], lrelu(g2r[j]*acca[i][j] + b2r[j]));
        mx[i][j] = fmaxf(mx[i][j], lrelu(g2r[j]*accb[i][j] + b2r[j]));
        mx[i][j] = fmaxf(mx[i][j], lrelu(g2r[j]*accc[i][j] + b2r[j]));
        mx[i][j] = fmaxf(mx[i][j], lrelu(g2r[j]*accd[i][j] + b2r[j]));
      }
    __syncthreads();
  }
  #pragma unroll
  for (int i=0;i<2;i++)
    #pragma unroll
    for (int j=0;j<4;j++)
      ws[outoff + (long)(p0 + tr*2 + i)*64 + oc*4 + j] = mx[i][j];
}

// ---------------- K4b: w = Wsn1 . hdg per point (stored raw) ----------------
// r7: same 8-slice-per-point restructure as k_uv.
__global__ __launch_bounds__(256) void k_w(float* __restrict__ ws){
  const float* wf = ws + OFF_WF;
  int t = threadIdx.x;
  int lane = t & 63;
  int W = blockIdx.x*4 + (t >> 6);
  int g = __builtin_amdgcn_readfirstlane(W >> 3);
  int s = __builtin_amdgcn_readfirstlane(W & 7);
  int n = g*64 + lane;
  int o0 = s*8;
  float h[64];
  const float4* src = (const float4*)(ws + OFF_HDG + (long)n*64);
  #pragma unroll
  for (int q=0;q<16;q++){ float4 v = src[q]; h[4*q]=v.x; h[4*q+1]=v.y; h[4*q+2]=v.z; h[4*q+3]=v.w; }
  float ua[8];
  #pragma unroll 1
  for (int j=0;j<8;j++){
    int o = o0 + j;
    float a = 0.f;
    #pragma unroll
    for (int c=0;c<64;c++) a += wf[WF_WSN1 + o*64 + c]*h[c];
    ua[j] = a;
  }
  float* up = ws + OFF_U + (long)n*64 + o0;
  *(float4*)up     = make_float4(ua[0],ua[1],ua[2],ua[3]);
  *(float4*)(up+4) = make_float4(ua[4],ua[5],ua[6],ua[7]);
}

// ---------------- K6a: head conv3+conv4, h4 out in k-major [128][NP] --------
__global__ __launch_bounds__(256) void k_h4(const float* __restrict__ ws, float* __restrict__ h4g){
  __shared__ float Hs[64*65];    // [ch][pt] (hsn), then reused as [o3][pt] (h3)
  __shared__ float wb[64*130];   // W3 as wb[c*65+o]; later W4 as wb[c*130+o]
  const float* wf = ws + OFF_WF;
  int t = threadIdx.x;
  int p0 = blockIdx.x*64;

  {
    int r = t >> 2, c0 = (t & 3)*16;
    const float4* src = (const float4*)(ws + OFF_H2 + (long)(p0 + r)*64 + c0);
    #pragma unroll
    for (int q=0;q<4;q++){
      float4 v = src[q];
      Hs[(c0+4*q+0)*65 + r] = v.x; Hs[(c0+4*q+1)*65 + r] = v.y;
      Hs[(c0+4*q+2)*65 + r] = v.z; Hs[(c0+4*q+3)*65 + r] = v.w;
    }
  }
  {
    int r = t >> 2, c0 = (t & 3)*16;
    const float4* src = (const float4*)(wf + WF_W3 + (long)r*64 + c0);
    #pragma unroll
    for (int q=0;q<4;q++){
      float4 v = src[q];
      wb[(c0+4*q+0)*65 + r] = v.x; wb[(c0+4*q+1)*65 + r] = v.y;
      wb[(c0+4*q+2)*65 + r] = v.z; wb[(c0+4*q+3)*65 + r] = v.w;
    }
  }
  __syncthreads();

  int pr = t & 15, og = t >> 4;
  float acc[4][4] = {};
  #pragma unroll 8
  for (int k=0;k<64;k++){
    float4 a = *(const float4*)&Hs[k*65 + pr*4];
    float4 c = *(const float4*)&wb[k*65 + og*4];
    float av[4] = {a.x,a.y,a.z,a.w}, cv[4] = {c.x,c.y,c.z,c.w};
    #pragma unroll
    for (int i=0;i<4;i++)
      #pragma unroll
      for (int j=0;j<4;j++) acc[i][j] += av[i]*cv[j];
  }
  __syncthreads();

  #pragma unroll
  for (int j=0;j<4;j++){
    int o = og*4 + j;
    float g3 = wf[WF_G3+o], b3 = wf[WF_B3+o];
    #pragma unroll
    for (int i=0;i<4;i++)
      Hs[o*65 + pr*4 + i] = lrelu(g3*acc[i][j] + b3);
  }
  {
    int r = t >> 1, c0 = (t & 1)*32;
    const float4* src = (const float4*)(wf + WF_W4 + (long)r*64 + c0);
    #pragma unroll
    for (int q=0;q<8;q++){
      float4 v = src[q];
      wb[(c0+4*q+0)*130 + r] = v.x; wb[(c0+4*q+1)*130 + r] = v.y;
      wb[(c0+4*q+2)*130 + r] = v.z; wb[(c0+4*q+3)*130 + r] = v.w;
    }
  }
  __syncthreads();

  float a2[4][8] = {};
  #pragma unroll 8
  for (int k=0;k<64;k++){
    float4 a = *(const float4*)&Hs[k*65 + pr*4];
    float4 c0 = *(const float4*)&wb[k*130 + og*8];
    float4 c1 = *(const float4*)&wb[k*130 + og*8 + 4];
    float av[4] = {a.x,a.y,a.z,a.w};
    float cv[8] = {c0.x,c0.y,c0.z,c0.w,c1.x,c1.y,c1.z,c1.w};
    #pragma unroll
    for (int i=0;i<4;i++)
      #pragma unroll
      for (int j=0;j<8;j++) a2[i][j] += av[i]*cv[j];
  }
  #pragma unroll
  for (int j=0;j<8;j++){
    int o = og*8 + j;
    float g4 = wf[WF_G4+o], b4 = wf[WF_B4+o];
    #pragma unroll
    for (int i=0;i<4;i++)
      h4g[(long)o*NP + p0 + pr*4 + i] = lrelu(g4*a2[i][j] + b4);
  }
}

// ---------------- K6b: conv5 GEMM [512 x 128] . [128 x NP] ------------------
#define KC 32
__global__ __launch_bounds__(256) void k_conv5(const float* __restrict__ ws, void* __restrict__ outv){
  __shared__ float As[KC*128];   // [k][o]
  __shared__ float Bs[KC*128];   // [k][pt]
  const float* wf = ws + OFF_WF;
  int f = ((const int*)(ws + OFF_FLAG))[0];
  int t = threadIdx.x;
  int p0 = blockIdx.x*128;
  int o0 = blockIdx.y*128;
  const float* H4 = ws + OFF_H4;
  float acc[8][8] = {};

  for (int kc = 0; kc < 128; kc += KC){
    {
      int r = t >> 1, c0 = (t & 1)*16;
      const float4* src = (const float4*)(wf + WF_W5 + (long)(o0 + r)*128 + kc + c0);
      #pragma unroll
      for (int q=0;q<4;q++){
        float4 v = src[q];
        As[(c0+4*q+0)*128 + r] = v.x; As[(c0+4*q+1)*128 + r] = v.y;
        As[(c0+4*q+2)*128 + r] = v.z; As[(c0+4*q+3)*128 + r] = v.w;
      }
    }
    {
      int kr = t >> 3, pc = (t & 7)*16;
      const float4* src = (const float4*)(H4 + (long)(kc + kr)*NP + p0 + pc);
      float4 v0 = src[0], v1 = src[1], v2 = src[2], v3 = src[3];
      *(float4*)&Bs[kr*128 + pc     ] = v0;
      *(float4*)&Bs[kr*128 + pc + 4 ] = v1;
      *(float4*)&Bs[kr*128 + pc + 8 ] = v2;
      *(float4*)&Bs[kr*128 + pc + 12] = v3;
    }
    __syncthreads();
    int tr = t/16, tc = t%16;
    #pragma unroll 8
    for (int k=0;k<KC;k++){
      const float4* ap = (const float4*)&As[k*128 + tr*8];
      const float4* bp = (const float4*)&Bs[k*128 + tc*8];
      float4 a0 = ap[0], a1 = ap[1], b0 = bp[0], b1 = bp[1];
      float a[8] = {a0.x,a0.y,a0.z,a0.w,a1.x,a1.y,a1.z,a1.w};
      float b[8] = {b0.x,b0.y,b0.z,b0.w,b1.x,b1.y,b1.z,b1.w};
      #pragma unroll
      for (int i=0;i<8;i++)
        #pragma unroll
        for (int j=0;j<8;j++) acc[i][j] += a[i]*b[j];
    }
    __syncthreads();
  }

  int tr = t/16, tc = t%16;
  int b = p0 >> 12, nn = (p0 & 4095) + tc*8;
  #pragma unroll
  for (int i=0;i<8;i++){
    int oo = o0 + tr*8 + i;
    float g5 = wf[WF_G5+oo], b5 = wf[WF_B5+oo];
    long base = ((long)(b*512 + oo) << 12) + nn;
    if (f){
      float4 v0 = make_float4(lrelu(g5*acc[i][0]+b5), lrelu(g5*acc[i][1]+b5),
                              lrelu(g5*acc[i][2]+b5), lrelu(g5*acc[i][3]+b5));
      float4 v1 = make_float4(lrelu(g5*acc[i][4]+b5), lrelu(g5*acc[i][5]+b5),
                              lrelu(g5*acc[i][6]+b5), lrelu(g5*acc[i][7]+b5));
      *(float4*)((float*)outv + base)     = v0;
      *(float4*)((float*)outv + base + 4) = v1;
    } else {
      #pragma unroll
      for (int j=0;j<8;j++)
        ((bf16*)outv)[base + j] = __float2bfloat16(lrelu(g5*acc[i][j] + b5));
    }
  }
}

// ---------------- host ------------------------------------------------------
extern "C" void kernel_launch(void* const* d_in, const int* in_sizes, int n_in,
                              void* d_out, int out_size, void* d_ws, size_t ws_size,
                              hipStream_t stream) {
  const void* X = d_in[0];
  float* ws = (float*)d_ws;
  int* flagp = (int*)(ws + OFF_FLAG);

  WPack pk;
  static const int wsz[27] = {192,64,64, 4096,64,64, 8192,64,64, 4096,64,64, 4096,64,64,
                              4096,64,64, 4096,64,64, 8192,128,128, 65536,512,512};
  int off = 0;
  for (int i=0;i<27;i++){ pk.p[i] = d_in[i+1]; pk.off[i] = off; off += wsz[i]; }
  pk.off[27] = off;

  k_detect<<<dim3(1), dim3(64), 0, stream>>>(X, flagp);
  k_wcvt<<<dim3((WF_END+255)/256), dim3(256), 0, stream>>>(pk, ws + OFF_WF, flagp);
  k_point<<<dim3(NP/256), dim3(256), 0, stream>>>(X, ws);
  k_knn2<<<dim3(NP/8), dim3(512), 0, stream>>>(ws, (int*)(ws + OFF_IDX2));

  long availf = (long)(ws_size/4) - OFF_PAIR;
  int chunk = 4096;
  if (availf < (long)N_*N_){
    long c = (availf / N_) & ~127L;
    chunk = (int)(c < 128 ? 128 : c);
    if (chunk > 4096) chunk = 4096;
  }
  for (int b=0;b<8;b++){
    for (int n0=0;n0<N_; n0+=chunk){
      int rows = (N_ - n0 < chunk) ? (N_ - n0) : chunk;
      k_pair<<<dim3(32, rows/128), dim3(256), 0, stream>>>(ws, ws + OFF_PAIR, b, n0);
      k_topk_pair<<<dim3(rows/4), dim3(256), 0, stream>>>(ws + OFF_PAIR, (int*)(ws + OFF_IDX1), b, n0);
    }
  }
  k_wt<<<dim3(2), dim3(256), 0, stream>>>(ws);   // OFF_XX dead now; w2T for k_edge
  k_uv<<<dim3(NP/32), dim3(256), 0, stream>>>(ws);
  k_edge<1><<<dim3(NP/64), dim3(512), 0, stream>>>(ws, (const int*)(ws + OFF_IDX1),
        OFF_U, OFF_V, OFF_W2T, WF_GDG1, WF_BDG1, WF_GDG2, WF_BDG2, OFF_HDG);
  k_w<<<dim3(NP/32), dim3(256), 0, stream>>>(ws);
  k_edge<0><<<dim3(NP/64), dim3(512), 0, stream>>>(ws, (const int*)(ws + OFF_IDX2),
        0, OFF_U, OFF_W2T + 4096, WF_GSN1, WF_BSN1, WF_GSN2, WF_BSN2, OFF_H2);
  k_h4<<<dim3(NP/64), dim3(256), 0, stream>>>(ws, ws + OFF_H4);
  k_conv5<<<dim3(NP/128, 4), dim3(256), 0, stream>>>(ws, d_out);
}